// Round 12
// baseline (844.171 us; speedup 1.0000x reference)
//
#include <hip/hip_runtime.h>
#include <math.h>

#define D_MODEL 1024
#define D_SAE   16384
#define BATCH   4096
#define NTOT    (1ull * BATCH * D_SAE)
#define LN_EPS  1e-8
#define EPS_M   3e-4f        // |split-bf16 score - fp64 score| safe band half-width (>=6x margin)
#define ROW_CAP 256
#define CAND_CAP  (4 * 1024 * 1024)
#define CAND2_CAP 65536

using bf16x8 = __attribute__((ext_vector_type(8))) short;
using f32x4  = __attribute__((ext_vector_type(4))) float;

__device__ inline unsigned short f2bf(float f) {   // RNE fp32->bf16
  unsigned u = __float_as_uint(f);
  return (unsigned short)((u + 0x7fffu + ((u >> 16) & 1u)) >> 16);
}
__device__ inline float bf2f(unsigned short h) {
  return __uint_as_float((unsigned)h << 16);
}

// ---------- block (256-thread) reductions ----------
__device__ inline double blockReduceSum256(double v, double* lds) {
#pragma unroll
  for (int off = 32; off > 0; off >>= 1) v += __shfl_down(v, off, 64);
  int lane = threadIdx.x & 63, wid = threadIdx.x >> 6;
  __syncthreads();
  if (lane == 0) lds[wid] = v;
  __syncthreads();
  return lds[0] + lds[1] + lds[2] + lds[3];
}
__device__ inline int blockReduceSumInt256(int v, int* lds) {
#pragma unroll
  for (int off = 32; off > 0; off >>= 1) v += __shfl_down(v, off, 64);
  int lane = threadIdx.x & 63, wid = threadIdx.x >> 6;
  __syncthreads();
  if (lane == 0) lds[wid] = v;
  __syncthreads();
  return lds[0] + lds[1] + lds[2] + lds[3];
}

__device__ inline int wave_append(bool pred, int* counter) {
  unsigned long long m = __ballot(pred);
  int lane = threadIdx.x & 63;
  int pos = -1;
  if (m) {
    int ldr = __ffsll((long long)m) - 1;
    int base = 0;
    if (lane == ldr) base = atomicAdd(counter, __popcll(m));
    base = __shfl(base, ldr, 64);
    if (pred) pos = base + __popcll(m & ((1ull << lane) - 1ull));
  }
  return pos;
}

// ---------- 64-lane parallel descending histogram scan ----------
__device__ inline void hist_scan_desc(const int* __restrict__ hist, int nbins, int need,
                                      int& bsel, int& cumsel) {
  int t = threadIdx.x;          // 0..63
  int chunk = nbins >> 6;
  int topbase = nbins - t * chunk;
  int psum = 0;
  for (int i = 1; i <= chunk; ++i) psum += hist[topbase - i];
  int incl = psum;
#pragma unroll
  for (int off = 1; off < 64; off <<= 1) {
    int v = __shfl_up(incl, off, 64);
    if (t >= off) incl += v;
  }
  int excl = incl - psum;
  bool hit = (excl < need) && (excl + psum >= need);
  unsigned long long m = __ballot(hit);
  int tb = m ? (__ffsll((long long)m) - 1) : 63;
  int exb = __shfl(excl, tb, 64);
  int res_b = 0, res_c = 0;
  if (t == tb) {
    int c = exb;
    int b = nbins - tb * chunk - 1;
    int bend = b - chunk;
    for (; b > 0 && b > bend; --b) {
      int cc = hist[b];
      if (c + cc >= need) break;
      c += cc;
    }
    res_b = b; res_c = c;
  }
  bsel = __shfl(res_b, tb, 64);
  cumsel = __shfl(res_c, tb, 64);
}

// ---------- per-thread fp64 LN chain: thread t owns elements t*4..t*4+3 ----------
__device__ inline void ln_row_fp64(const float* __restrict__ row, double* lds, double d[4]) {
  int t = threadIdx.x;
  float4 s4 = *(const float4*)(row + t * 4);
  float4 t4 = *(const float4*)(row + D_MODEL + t * 4);
  double s[4] = {s4.x, s4.y, s4.z, s4.w};
  double tt[4] = {t4.x, t4.y, t4.z, t4.w};
  double ms = blockReduceSum256(s[0] + s[1] + s[2] + s[3], lds) / D_MODEL;
  double mt = blockReduceSum256(tt[0] + tt[1] + tt[2] + tt[3], lds) / D_MODEL;
  double vs = 0, vt = 0;
#pragma unroll
  for (int i = 0; i < 4; i++) { double a = s[i] - ms; vs += a * a; a = tt[i] - mt; vt += a * a; }
  vs = blockReduceSum256(vs, lds) / D_MODEL;
  vt = blockReduceSum256(vt, lds) / D_MODEL;
  double rs = sqrt(vs + LN_EPS), rt = sqrt(vt + LN_EPS);
  double u[4];
#pragma unroll
  for (int i = 0; i < 4; i++) u[i] = (tt[i] - mt) / rt - (s[i] - ms) / rs;
  double mu = blockReduceSum256(u[0] + u[1] + u[2] + u[3], lds) / D_MODEL;
  double vu = 0;
#pragma unroll
  for (int i = 0; i < 4; i++) { double a = u[i] - mu; vu += a * a; }
  vu = blockReduceSum256(vu, lds) / D_MODEL;
  double ru = sqrt(vu + LN_EPS);
#pragma unroll
  for (int i = 0; i < 4; i++) d[i] = (u[i] - mu) / ru;
}

// ---------- LN -> split-bf16 A in GEMM-tiled layout [mt][ks][kc][ml][e] ----------
__global__ __launch_bounds__(256) void ln_kernel(const float* __restrict__ x,
                                                 short* __restrict__ Ahi, short* __restrict__ Alo) {
  __shared__ double lds[4];
  int b = blockIdx.x, t = threadIdx.x;
  double d[4];
  ln_row_fp64(x + (size_t)b * (2 * D_MODEL), lds, d);
  int mt = b >> 7, ml = b & 127;
  int ks = t >> 3, kc = (t >> 1) & 3, e0 = (t & 1) * 4;
  size_t base = ((((size_t)mt * 32 + ks) * 4 + kc) * 128 + ml) * 8 + e0;
  short h[4], l[4];
#pragma unroll
  for (int i = 0; i < 4; i++) {
    float f = (float)d[i];
    unsigned short hh = f2bf(f);
    h[i] = (short)hh;
    l[i] = (short)f2bf(f - bf2f(hh));
  }
  *(short4*)&Ahi[base] = make_short4(h[0], h[1], h[2], h[3]);
  *(short4*)&Alo[base] = make_short4(l[0], l[1], l[2], l[3]);
}

// ---------- dec_norms in fp64 (wave-per-feature, no block syncs) ----------
__global__ __launch_bounds__(256) void norm_kernel(const float* __restrict__ Wdec,
                                                   double* __restrict__ g64, float* __restrict__ g32) {
  int wv = threadIdx.x >> 6, lane = threadIdx.x & 63;
  int j = (blockIdx.x << 2) | wv;
  const float4* rowp = (const float4*)(Wdec + (size_t)j * D_MODEL);
  double a = 0;
#pragma unroll
  for (int q = 0; q < 4; ++q) {
    float4 w = rowp[lane + q * 64];
    a += (double)w.x * w.x + (double)w.y * w.y + (double)w.z * w.z + (double)w.w * w.w;
  }
#pragma unroll
  for (int off = 32; off > 0; off >>= 1) a += __shfl_down(a, off, 64);
  if (lane == 0) { double g = sqrt(a); g64[j] = g; g32[j] = (float)g; }
}

// ---------- pre-split W_enc fp32 -> tiled bf16 hi/lo [nt][ks][kc][c][e] ----------
__global__ __launch_bounds__(256) void wsplit_kernel(const float* __restrict__ Wenc,
                                                     short* __restrict__ Whi, short* __restrict__ Wlo) {
  __shared__ short sh[4096];
  __shared__ short sl[4096];
  int blk = blockIdx.x;            // 4096 = 128 nt * 32 ks
  int nt = blk >> 5, ks = blk & 31;
  int t = threadIdx.x;
  int r = t >> 3;
  int cg = t & 7;
  int kc = r >> 3, e = r & 7;
  const float* src = Wenc + (size_t)(ks * 32 + r) * D_SAE + nt * 128 + cg;
#pragma unroll
  for (int j = 0; j < 16; ++j) {
    float f = src[j * 8];
    unsigned short hh = f2bf(f);
    short ll = (short)f2bf(f - bf2f(hh));
    int c = j * 8 + cg;
    sh[kc * 1024 + c * 8 + e] = (short)hh;
    sl[kc * 1024 + c * 8 + e] = ll;
  }
  __syncthreads();
  size_t obase = ((size_t)nt * 32 + ks) * 4096;
  *(float4*)&Whi[obase + t * 16]     = *(const float4*)&sh[t * 16];
  *(float4*)&Whi[obase + t * 16 + 8] = *(const float4*)&sh[t * 16 + 8];
  *(float4*)&Wlo[obase + t * 16]     = *(const float4*)&sl[t * 16];
  *(float4*)&Wlo[obase + t * 16 + 8] = *(const float4*)&sl[t * 16 + 8];
}

// ---------- hi-only subsampled hist GEMM (big path): per-wave privatized hist ----------
__global__ __launch_bounds__(256) void hist_gemm(
    const short* __restrict__ Whi, const short* __restrict__ Ahi,
    const float* __restrict__ benc, const float* __restrict__ g32,
    int* __restrict__ ghist) {
  __shared__ short sA[4096];
  __shared__ short sB[4096];
  __shared__ int h[4][2048];
  const int tid = threadIdx.x;
  const int lane = tid & 63;
  const int w = tid >> 6;
  const int wm = (w >> 1) * 64, wn = (w & 1) * 64;
  int lin = blockIdx.x;            // 512 = 4 mt * 128 nt
  int mt = lin >> 7, nt = lin & 127;
  const int col0 = nt * 128;
  for (int i = tid; i < 8192; i += 256) ((int*)h)[i] = 0;
  const size_t atile = (size_t)mt * 131072;
  const size_t btile = (size_t)nt * 131072;
  f32x4 acc[4][4] = {};
  const int kcl = lane >> 4, l15 = lane & 15;

  float4 a0, a1, b0, b1;
  {
    const float4* ah4 = (const float4*)(Ahi + atile);
    const float4* bh4 = (const float4*)(Whi + btile);
    a0 = ah4[tid]; a1 = ah4[tid + 256];
    b0 = bh4[tid]; b1 = bh4[tid + 256];
  }
  for (int ks = 0; ks < 32; ++ks) {
    __syncthreads();
    *(float4*)&sA[(size_t)tid * 8] = a0;
    *(float4*)&sA[(size_t)(tid + 256) * 8] = a1;
    *(float4*)&sB[(size_t)tid * 8] = b0;
    *(float4*)&sB[(size_t)(tid + 256) * 8] = b1;
    __syncthreads();
    if (ks < 31) {
      const float4* ah4 = (const float4*)(Ahi + atile + (ks + 1) * 4096);
      const float4* bh4 = (const float4*)(Whi + btile + (ks + 1) * 4096);
      a0 = ah4[tid]; a1 = ah4[tid + 256];
      b0 = bh4[tid]; b1 = bh4[tid + 256];
    }
    bf16x8 ahf[4];
#pragma unroll
    for (int fm = 0; fm < 4; ++fm)
      ahf[fm] = *(const bf16x8*)&sA[(kcl * 128 + wm + fm * 16 + l15) * 8];
#pragma unroll
    for (int fn = 0; fn < 4; ++fn) {
      bf16x8 bh = *(const bf16x8*)&sB[(kcl * 128 + wn + fn * 16 + l15) * 8];
#pragma unroll
      for (int fm = 0; fm < 4; ++fm)
        acc[fm][fn] = __builtin_amdgcn_mfma_f32_16x16x32_bf16(ahf[fm], bh, acc[fm][fn], 0, 0, 0);
    }
  }
#pragma unroll
  for (int fn = 0; fn < 4; ++fn) {
    int col = col0 + wn + fn * 16 + l15;
    float g = g32[col], be = benc[col];
#pragma unroll
    for (int fm = 0; fm < 4; ++fm) {
#pragma unroll
      for (int r = 0; r < 4; ++r) {
        float z = acc[fm][fn][r] + be;
        float s = z > 0.f ? z * g : 0.f;
        unsigned bits = __float_as_uint(s);
        if (bits) atomicAdd(&h[w][bits >> 21], 1);
      }
    }
  }
  __syncthreads();
  for (int i = tid; i < 2048; i += 256) {
    int v = h[0][i] + h[1][i] + h[2][i] + h[3][i];
    if (v) atomicAdd(&ghist[i], v);
  }
}

// ---------- 128x128 split-bf16 MFMA extract GEMM (round-6-proven structure) ----------
// Pre-split B, reg-prefetch pipeline, L2-locality block map, fused pass-0 hist,
// block-aggregated append. Grid 4096 x 256 thr, ~3 blocks/CU.
__global__ __launch_bounds__(256) void extract_gemm128(
    const short* __restrict__ Whi, const short* __restrict__ Wlo,
    const short* __restrict__ Ahi, const short* __restrict__ Alo,
    const float* __restrict__ benc, const float* __restrict__ g32,
    int* __restrict__ ctrl, int* __restrict__ cand_idx, float* __restrict__ cand_sc,
    int* __restrict__ ghist) {
  __shared__ short sA[8192];   // hi [4][128][8] | lo at +4096
  __shared__ short sB[8192];
  __shared__ int hh[2050];     // [0..2047] hist, [2048] count, [2049] base

  const int tid = threadIdx.x;
  const int lane = tid & 63;
  const int w = tid >> 6;
  const int wm = (w >> 1) * 64, wn = (w & 1) * 64;

  // L2-locality: XCD owns 16 nt panels; 32 consecutive blocks share a panel
  int lin = blockIdx.x;
  int xcd = lin & 7, j = lin >> 3;
  int mt = j & 31;
  int nt = (xcd << 4) | (j >> 5);
  const int row0 = mt * 128, col0 = nt * 128;

  const size_t atile = (size_t)mt * 131072;
  const size_t btile = (size_t)nt * 131072;

  f32x4 acc[4][4] = {};
  const int kcl = lane >> 4, l15 = lane & 15;

  float4 a0, a1, a2, a3, b0, b1, b2, b3;
  {
    const float4* ah4 = (const float4*)(Ahi + atile);
    const float4* al4 = (const float4*)(Alo + atile);
    const float4* bh4 = (const float4*)(Whi + btile);
    const float4* bl4 = (const float4*)(Wlo + btile);
    a0 = ah4[tid]; a1 = ah4[tid + 256];
    a2 = al4[tid]; a3 = al4[tid + 256];
    b0 = bh4[tid]; b1 = bh4[tid + 256];
    b2 = bl4[tid]; b3 = bl4[tid + 256];
  }

  for (int ks = 0; ks < 32; ++ks) {
    __syncthreads();   // previous tile fully consumed
    *(float4*)&sA[(size_t)tid * 8] = a0;
    *(float4*)&sA[(size_t)(tid + 256) * 8] = a1;
    *(float4*)&sA[(size_t)(512 + tid) * 8] = a2;
    *(float4*)&sA[(size_t)(512 + tid + 256) * 8] = a3;
    *(float4*)&sB[(size_t)tid * 8] = b0;
    *(float4*)&sB[(size_t)(tid + 256) * 8] = b1;
    *(float4*)&sB[(size_t)(512 + tid) * 8] = b2;
    *(float4*)&sB[(size_t)(512 + tid + 256) * 8] = b3;
    __syncthreads();   // tile visible
    if (ks < 31) {
      const int o = (ks + 1) * 4096;
      const float4* ah4 = (const float4*)(Ahi + atile + o);
      const float4* al4 = (const float4*)(Alo + atile + o);
      const float4* bh4 = (const float4*)(Whi + btile + o);
      const float4* bl4 = (const float4*)(Wlo + btile + o);
      a0 = ah4[tid]; a1 = ah4[tid + 256];
      a2 = al4[tid]; a3 = al4[tid + 256];
      b0 = bh4[tid]; b1 = bh4[tid + 256];
      b2 = bl4[tid]; b3 = bl4[tid + 256];
    }
    bf16x8 ahf[4], alf[4];
#pragma unroll
    for (int fm = 0; fm < 4; ++fm) {
      int off = (kcl * 128 + wm + fm * 16 + l15) * 8;
      ahf[fm] = *(const bf16x8*)&sA[off];
      alf[fm] = *(const bf16x8*)&sA[4096 + off];
    }
#pragma unroll
    for (int fn = 0; fn < 4; ++fn) {
      int boff = (kcl * 128 + wn + fn * 16 + l15) * 8;
      bf16x8 bh = *(const bf16x8*)&sB[boff];
      bf16x8 bl = *(const bf16x8*)&sB[4096 + boff];
#pragma unroll
      for (int fm = 0; fm < 4; ++fm) {
        acc[fm][fn] = __builtin_amdgcn_mfma_f32_16x16x32_bf16(ahf[fm], bh, acc[fm][fn], 0, 0, 0);
        acc[fm][fn] = __builtin_amdgcn_mfma_f32_16x16x32_bf16(alf[fm], bh, acc[fm][fn], 0, 0, 0);
        acc[fm][fn] = __builtin_amdgcn_mfma_f32_16x16x32_bf16(ahf[fm], bl, acc[fm][fn], 0, 0, 0);
      }
    }
  }

  // epilogue: count + fused pass-0 LDS histogram, then block-aggregated append
  const int l4r = lane >> 4;
  unsigned thrBits = (unsigned)ctrl[1];
  __syncthreads();
  for (int i = tid; i < 2050; i += 256) hh[i] = 0;
  __syncthreads();
  int cnt = 0;
#pragma unroll
  for (int fn = 0; fn < 4; ++fn) {
    int col = col0 + wn + fn * 16 + l15;
    float g = g32[col], be = benc[col];
#pragma unroll
    for (int fm = 0; fm < 4; ++fm) {
#pragma unroll
      for (int r = 0; r < 4; ++r) {
        float z = acc[fm][fn][r] + be;
        float s = z > 0.f ? z * g : 0.f;
        unsigned bits = __float_as_uint(s);
        if (bits >= thrBits) { cnt++; atomicAdd(&hh[bits >> 21], 1); }
      }
    }
  }
  int my = 0;
  if (cnt) my = atomicAdd(&hh[2048], cnt);
  __syncthreads();
  if (tid == 0) hh[2049] = atomicAdd(&ctrl[2], hh[2048]);
  for (int i = tid; i < 2048; i += 256)
    if (hh[i]) atomicAdd(&ghist[i], hh[i]);
  __syncthreads();
  int pos = hh[2049] + my;
#pragma unroll
  for (int fn = 0; fn < 4; ++fn) {
    int col = col0 + wn + fn * 16 + l15;
    float g = g32[col], be = benc[col];
#pragma unroll
    for (int fm = 0; fm < 4; ++fm) {
      int rowb = row0 + wm + fm * 16 + l4r * 4;
#pragma unroll
      for (int r = 0; r < 4; ++r) {
        float z = acc[fm][fn][r] + be;
        float s = z > 0.f ? z * g : 0.f;
        if (__float_as_uint(s) >= thrBits) {
          if (pos < CAND_CAP) { cand_idx[pos] = (rowb + r) * D_SAE + col; cand_sc[pos] = s; }
          pos++;
        }
      }
    }
  }
}

// ---------- fallback 128^2 GEMM (small ws): MODE 0 = hist (1/16), MODE 1 = extract ----------
template <int MODE>
__global__ __launch_bounds__(256) void mfma_gemm(
    const float* __restrict__ Wenc,
    const short* __restrict__ Ahi, const short* __restrict__ Alo,
    const float* __restrict__ benc, const float* __restrict__ g32,
    int* __restrict__ ghist, int* __restrict__ ctrl,
    int* __restrict__ cand_idx, float* __restrict__ cand_sc) {
  __shared__ short sA[8192];
  __shared__ short sB[8192];
  __shared__ int h[(MODE == 0) ? 2048 : 2];
  const int tid = threadIdx.x;
  const int lane = tid & 63;
  const int w = tid >> 6;
  const int wm = (w >> 1) * 64, wn = (w & 1) * 64;
  int lin = blockIdx.x;
  int mt, nt;
  if (MODE == 0) { mt = lin >> 7; nt = lin & 127; }
  else { int xcd = lin & 7, j = lin >> 3; mt = j & 31; nt = (xcd << 4) | (j >> 5); }
  const int row0 = mt * 128, col0 = nt * 128;
  if (MODE == 0) { for (int i = tid; i < 2048; i += 256) h[i] = 0; }
  else if (tid == 0) h[0] = 0;
  const int nl = tid & 127;
  const int half = tid >> 7;
  const float* wbase = Wenc + (size_t)col0 + nl;
  const size_t atile = (size_t)mt * 131072;
  f32x4 acc[4][4] = {};
  const int kcl = lane >> 4, l15 = lane & 15;
  float4 a0, a1, a2, a3;
  float bfv[16];
  {
    const float4* ah4 = (const float4*)(Ahi + atile);
    const float4* al4 = (const float4*)(Alo + atile);
    a0 = ah4[tid]; a1 = ah4[tid + 256];
    a2 = al4[tid]; a3 = al4[tid + 256];
#pragma unroll
    for (int p = 0; p < 4; ++p)
#pragma unroll
      for (int i = 0; i < 4; ++i)
        bfv[p * 4 + i] = wbase[(size_t)(p * 8 + half * 4 + i) * D_SAE];
  }
  for (int ks = 0; ks < 32; ++ks) {
    short hb[16], lb[16];
#pragma unroll
    for (int q = 0; q < 16; ++q) {
      unsigned short hh = f2bf(bfv[q]);
      hb[q] = (short)hh;
      lb[q] = (short)f2bf(bfv[q] - bf2f(hh));
    }
    __syncthreads();
    *(float4*)&sA[(size_t)tid * 8] = a0;
    *(float4*)&sA[(size_t)(tid + 256) * 8] = a1;
    *(float4*)&sA[(size_t)(512 + tid) * 8] = a2;
    *(float4*)&sA[(size_t)(512 + tid + 256) * 8] = a3;
#pragma unroll
    for (int p = 0; p < 4; ++p) {
      int boff = p * 1024 + nl * 8 + half * 4;
      *(short4*)&sB[boff] = make_short4(hb[p * 4], hb[p * 4 + 1], hb[p * 4 + 2], hb[p * 4 + 3]);
      *(short4*)&sB[4096 + boff] = make_short4(lb[p * 4], lb[p * 4 + 1], lb[p * 4 + 2], lb[p * 4 + 3]);
    }
    __syncthreads();
    if (ks < 31) {
      const float4* ah4 = (const float4*)(Ahi + atile + (ks + 1) * 4096);
      const float4* al4 = (const float4*)(Alo + atile + (ks + 1) * 4096);
      a0 = ah4[tid]; a1 = ah4[tid + 256];
      a2 = al4[tid]; a3 = al4[tid + 256];
      const int k0n = (ks + 1) * 32;
#pragma unroll
      for (int p = 0; p < 4; ++p)
#pragma unroll
        for (int i = 0; i < 4; ++i)
          bfv[p * 4 + i] = wbase[(size_t)(k0n + p * 8 + half * 4 + i) * D_SAE];
    }
    bf16x8 ahf[4], alf[4];
#pragma unroll
    for (int fm = 0; fm < 4; ++fm) {
      int off = (kcl * 128 + wm + fm * 16 + l15) * 8;
      ahf[fm] = *(const bf16x8*)&sA[off];
      alf[fm] = *(const bf16x8*)&sA[4096 + off];
    }
#pragma unroll
    for (int fn = 0; fn < 4; ++fn) {
      int boff = (kcl * 128 + wn + fn * 16 + l15) * 8;
      bf16x8 bh = *(const bf16x8*)&sB[boff];
      bf16x8 bl = *(const bf16x8*)&sB[4096 + boff];
#pragma unroll
      for (int fm = 0; fm < 4; ++fm) {
        acc[fm][fn] = __builtin_amdgcn_mfma_f32_16x16x32_bf16(ahf[fm], bh, acc[fm][fn], 0, 0, 0);
        acc[fm][fn] = __builtin_amdgcn_mfma_f32_16x16x32_bf16(alf[fm], bh, acc[fm][fn], 0, 0, 0);
        acc[fm][fn] = __builtin_amdgcn_mfma_f32_16x16x32_bf16(ahf[fm], bl, acc[fm][fn], 0, 0, 0);
      }
    }
  }
  const int l4r = lane >> 4;
  if (MODE == 0) {
#pragma unroll
    for (int fn = 0; fn < 4; ++fn) {
      int col = col0 + wn + fn * 16 + l15;
      float g = g32[col], be = benc[col];
#pragma unroll
      for (int fm = 0; fm < 4; ++fm) {
#pragma unroll
        for (int r = 0; r < 4; ++r) {
          float z = acc[fm][fn][r] + be;
          float s = z > 0.f ? z * g : 0.f;
          unsigned bits = __float_as_uint(s);
          if (bits) atomicAdd(&h[bits >> 21], 1);
        }
      }
    }
    __syncthreads();
    for (int i = tid; i < 2048; i += 256)
      if (h[i]) atomicAdd(&ghist[i], h[i]);
  } else {
    unsigned thrBits = (unsigned)ctrl[1];
    int cnt = 0;
#pragma unroll
    for (int fn = 0; fn < 4; ++fn) {
      int col = col0 + wn + fn * 16 + l15;
      float g = g32[col], be = benc[col];
#pragma unroll
      for (int fm = 0; fm < 4; ++fm) {
#pragma unroll
        for (int r = 0; r < 4; ++r) {
          float z = acc[fm][fn][r] + be;
          float s = z > 0.f ? z * g : 0.f;
          cnt += (__float_as_uint(s) >= thrBits) ? 1 : 0;
        }
      }
    }
    int my = 0;
    if (cnt) my = atomicAdd(&h[0], cnt);
    __syncthreads();
    if (tid == 0) h[1] = atomicAdd(&ctrl[2], h[0]);
    __syncthreads();
    int pos = h[1] + my;
#pragma unroll
    for (int fn = 0; fn < 4; ++fn) {
      int col = col0 + wn + fn * 16 + l15;
      float g = g32[col], be = benc[col];
#pragma unroll
      for (int fm = 0; fm < 4; ++fm) {
        int rowb = row0 + wm + fm * 16 + l4r * 4;
#pragma unroll
        for (int r = 0; r < 4; ++r) {
          float z = acc[fm][fn][r] + be;
          float s = z > 0.f ? z * g : 0.f;
          if (__float_as_uint(s) >= thrBits) {
            if (pos < CAND_CAP) { cand_idx[pos] = (rowb + r) * D_SAE + col; cand_sc[pos] = s; }
            pos++;
          }
        }
      }
    }
  }
}

// ---------- coarse threshold (64-thread parallel scan) ----------
__global__ void find_coarse_kernel(const int* __restrict__ gh, int* ctrl,
                                   const int* __restrict__ kptr, int sub) {
  long long kB = (long long)kptr[0] * BATCH;
  long long needl = (kB + 500000 + sub - 1) / sub;
  long long fl = 720000 / sub;
  if (needl < fl) needl = fl;
  int b, cum;
  hist_scan_desc(gh, 2048, (int)needl, b, cum);
  if (threadIdx.x == 0) {
    long long est_incl = (long long)sub * (cum + gh[b]);
    if (est_incl > 3500000LL && (long long)sub * cum >= kB + 120000LL) b = b + 1;
    ctrl[1] = (int)(((unsigned)b) << 21);
  }
}

// ---------- radix histograms over candidate scores (passes 1,2) ----------
__global__ __launch_bounds__(256) void chist_kernel(const float* __restrict__ cand_sc,
                                                    const int* __restrict__ ctrl,
                                                    int* __restrict__ ghist, int pass) {
  __shared__ int h[2048];
  int nb = (pass == 2) ? 1024 : 2048;
  for (int i = threadIdx.x; i < nb; i += 256) h[i] = 0;
  __syncthreads();
  int n = ctrl[2]; if (n > CAND_CAP) n = CAND_CAP;
  unsigned sel1 = 0, sel22 = 0;
  if (pass == 1) sel1 = (unsigned)ctrl[3];
  if (pass == 2) sel22 = ((unsigned)ctrl[3] << 11) | (unsigned)ctrl[5];
  for (int i = blockIdx.x * 256 + threadIdx.x; i < n; i += gridDim.x * 256) {
    unsigned bits = __float_as_uint(cand_sc[i]);
    if (pass == 0) atomicAdd(&h[bits >> 21], 1);
    else if (pass == 1) { if ((bits >> 21) == sel1) atomicAdd(&h[(bits >> 10) & 0x7FFu], 1); }
    else { if ((bits >> 10) == sel22) atomicAdd(&h[bits & 0x3FFu], 1); }
  }
  __syncthreads();
  for (int i = threadIdx.x; i < nb; i += 256)
    if (h[i]) atomicAdd(&ghist[i], h[i]);
}

// ---------- radix select step (64-thread parallel scan) ----------
__global__ void cfind_kernel(const int* __restrict__ hist, int* ctrl,
                             const int* __restrict__ kptr, int pass) {
  int kB = kptr[0] * BATCH;
  int need, nbins;
  if (pass == 0)      { need = kB;                       nbins = 2048; }
  else if (pass == 1) { need = kB - ctrl[4];             nbins = 2048; }
  else                { need = kB - ctrl[4] - ctrl[6];   nbins = 1024; }
  int b, cum;
  hist_scan_desc(hist, nbins, need, b, cum);
  if (threadIdx.x == 0) {
    if (pass == 0)      { ctrl[3] = b; ctrl[4] = cum; }
    else if (pass == 1) { ctrl[5] = b; ctrl[6] = cum; }
    else {
      unsigned vbits = ((unsigned)ctrl[3] << 21) | ((unsigned)ctrl[5] << 10) | (unsigned)b;
      float V = __uint_as_float(vbits);
      float* cf = (float*)ctrl;
      cf[8] = V; cf[9] = V + EPS_M; cf[10] = V - EPS_M;
    }
  }
}

// ---------- band partition ----------
__global__ __launch_bounds__(256) void band_kernel(const int* __restrict__ cand_idx,
    const float* __restrict__ cand_sc, const float* __restrict__ g32,
    int* ctrl, int* row_cnt, int* row_feat, float* row_act, int* cand2_idx) {
  const float* cf = (const float*)ctrl;
  float hi = cf[9], lo = cf[10];
  int n = ctrl[2]; if (n > CAND_CAP) n = CAND_CAP;
  int lane = threadIdx.x & 63;
  int defc = 0;
  for (int i = blockIdx.x * 256 + threadIdx.x; i < n; i += gridDim.x * 256) {
    float s = cand_sc[i];
    int flat = cand_idx[i];
    if (s > hi) {
      int b = flat >> 14, j = flat & (D_SAE - 1);
      int p = atomicAdd(&row_cnt[b], 1);
      if (p < ROW_CAP) { row_feat[b * ROW_CAP + p] = j; row_act[b * ROW_CAP + p] = s / g32[j]; }
      defc++;
    }
    bool isc = (s <= hi) && (s >= lo);
    int pos = wave_append(isc, &ctrl[12]);
    if (isc && pos >= 0 && pos < CAND2_CAP) cand2_idx[pos] = flat;
  }
#pragma unroll
  for (int off = 32; off > 0; off >>= 1) defc += __shfl_down(defc, off, 64);
  if (lane == 0 && defc) atomicAdd(&ctrl[11], defc);
}

// ---------- fp64 rescore of band candidates ----------
__global__ __launch_bounds__(256) void cand2_score_kernel(const int* __restrict__ ctrl,
    const int* __restrict__ cand2_idx, const float* __restrict__ x,
    const float* __restrict__ Wdec, const float* __restrict__ benc,
    const double* __restrict__ g64, double* __restrict__ cand2_sc) {
  __shared__ double lds[4];
  int n2 = ctrl[12]; if (n2 > CAND2_CAP) n2 = CAND2_CAP;
  int t = threadIdx.x;
  for (int c = blockIdx.x; c < n2; c += gridDim.x) {
    int flat = cand2_idx[c];
    int b = flat >> 14, j = flat & (D_SAE - 1);
    double d[4];
    ln_row_fp64(x + (size_t)b * (2 * D_MODEL), lds, d);
    float4 w4 = *(const float4*)(Wdec + (size_t)j * D_MODEL + t * 4);
    double a = d[0] * (double)w4.x + d[1] * (double)w4.y + d[2] * (double)w4.z + d[3] * (double)w4.w;
    double z = blockReduceSum256(a, lds) + (double)benc[j];
    double sc = z > 0 ? z * g64[j] : 0.0;
    if (t == 0) cand2_sc[c] = sc;
  }
}

// ---------- rank band candidates (fp64, index-stable), accept fill ----------
__global__ __launch_bounds__(256) void cand2_rank_kernel(const int* __restrict__ ctrl,
    const int* __restrict__ cand2_idx, const double* __restrict__ cand2_sc,
    const double* __restrict__ g64, const int* __restrict__ kptr,
    int* row_cnt, int* row_feat, float* row_act) {
  __shared__ int lds[4];
  int n2 = ctrl[12]; if (n2 > CAND2_CAP) n2 = CAND2_CAP;
  int kB = kptr[0] * BATCH;
  int fill = kB - ctrl[11];
  int t = threadIdx.x;
  for (int c = blockIdx.x; c < n2; c += gridDim.x) {
    double sc = cand2_sc[c];
    int fc = cand2_idx[c];
    int cnt = 0;
    for (int y = t; y < n2; y += 256) {
      double sy = cand2_sc[y];
      if (sy > sc || (sy == sc && cand2_idx[y] < fc)) cnt++;
    }
    cnt = blockReduceSumInt256(cnt, lds);
    if (t == 0 && cnt < fill) {
      int b = fc >> 14, j = fc & (D_SAE - 1);
      int p = atomicAdd(&row_cnt[b], 1);
      if (p < ROW_CAP) { row_feat[b * ROW_CAP + p] = j; row_act[b * ROW_CAP + p] = (float)(sc / g64[j]); }
    }
  }
}

// ---------- sparse recon (float4, 2-way ILP) ----------
__global__ __launch_bounds__(256) void recon_kernel(const int* __restrict__ row_cnt,
    const int* __restrict__ row_feat, const float* __restrict__ row_act,
    const float* __restrict__ Wdec, const float* __restrict__ bdec, float* __restrict__ out) {
  int b = blockIdx.x, t = threadIdx.x;
  float4 acc0 = *(const float4*)&bdec[t * 4];
  float4 acc1 = make_float4(0.f, 0.f, 0.f, 0.f);
  int n = row_cnt[b]; if (n > ROW_CAP) n = ROW_CAP;
  const int* rf = row_feat + (size_t)b * ROW_CAP;
  const float* ra = row_act + (size_t)b * ROW_CAP;
  int p = 0;
  for (; p + 2 <= n; p += 2) {
    int j0 = rf[p], j1 = rf[p + 1];
    float v0 = ra[p], v1 = ra[p + 1];
    float4 w0 = *(const float4*)(Wdec + (size_t)j0 * D_MODEL + t * 4);
    float4 w1 = *(const float4*)(Wdec + (size_t)j1 * D_MODEL + t * 4);
    acc0.x += v0 * w0.x; acc0.y += v0 * w0.y; acc0.z += v0 * w0.z; acc0.w += v0 * w0.w;
    acc1.x += v1 * w1.x; acc1.y += v1 * w1.y; acc1.z += v1 * w1.z; acc1.w += v1 * w1.w;
  }
  if (p < n) {
    int j0 = rf[p]; float v0 = ra[p];
    float4 w0 = *(const float4*)(Wdec + (size_t)j0 * D_MODEL + t * 4);
    acc0.x += v0 * w0.x; acc0.y += v0 * w0.y; acc0.z += v0 * w0.z; acc0.w += v0 * w0.w;
  }
  acc0.x += acc1.x; acc0.y += acc1.y; acc0.z += acc1.z; acc0.w += acc1.w;
  *(float4*)(out + (size_t)b * D_MODEL + t * 4) = acc0;
}

extern "C" void kernel_launch(void* const* d_in, const int* in_sizes, int n_in,
                              void* d_out, int out_size, void* d_ws, size_t ws_size,
                              hipStream_t stream) {
  const float* x    = (const float*)d_in[0];
  const float* Wenc = (const float*)d_in[1];
  const float* benc = (const float*)d_in[2];
  const float* Wdec = (const float*)d_in[3];
  const float* bdec = (const float*)d_in[4];
  const int*   kptr = (const int*)d_in[5];
  float* out = (float*)d_out;

  char* ws = (char*)d_ws;
  size_t off = 0;
  short*  Ahi       = (short*)(ws + off);  off += (size_t)BATCH * D_MODEL * 2;
  short*  Alo       = (short*)(ws + off);  off += (size_t)BATCH * D_MODEL * 2;
  int*    cand_idx  = (int*)(ws + off);    off += (size_t)CAND_CAP * 4;
  float*  cand_sc   = (float*)(ws + off);  off += (size_t)CAND_CAP * 4;
  int*    row_feat  = (int*)(ws + off);    off += (size_t)BATCH * ROW_CAP * 4;
  float*  row_act   = (float*)(ws + off);  off += (size_t)BATCH * ROW_CAP * 4;
  int*    cand2_idx = (int*)(ws + off);    off += (size_t)CAND2_CAP * 4;
  double* cand2_sc  = (double*)(ws + off); off += (size_t)CAND2_CAP * 8;
  double* g64       = (double*)(ws + off); off += (size_t)D_SAE * 8;
  float*  g32       = (float*)(ws + off);  off += (size_t)D_SAE * 4;
  char*   zbase     = ws + off;
  int* ghist   = (int*)(zbase);
  int* h1      = (int*)(zbase + 8192);
  int* h2      = (int*)(zbase + 16384);
  int* h3      = (int*)(zbase + 24576);
  int* ctrl    = (int*)(zbase + 28672);
  int* row_cnt = (int*)(zbase + 28928);
  size_t zbytes = 28928 + (size_t)BATCH * 4;
  size_t small_need = off + zbytes;
  if (small_need > ws_size) return;  // ~60 MB floor

  size_t big_off = (small_need + 255) & ~(size_t)255;
  short* Whi = (short*)(ws + big_off);
  short* Wlo = Whi + (size_t)D_MODEL * D_SAE;
  size_t big_need = big_off + (size_t)D_MODEL * D_SAE * 4;
  const bool big = (big_need <= ws_size);   // round-6/8/9-proven to fit

  hipMemsetAsync(zbase, 0, zbytes, stream);

  ln_kernel<<<BATCH, 256, 0, stream>>>(x, Ahi, Alo);
  norm_kernel<<<D_SAE / 4, 256, 0, stream>>>(Wdec, g64, g32);
  if (big) {
    wsplit_kernel<<<4096, 256, 0, stream>>>(Wenc, Whi, Wlo);
    hist_gemm<<<512, 256, 0, stream>>>(Whi, Ahi, benc, g32, ghist);
    find_coarse_kernel<<<1, 64, 0, stream>>>(ghist, ctrl, kptr, 8);
    extract_gemm128<<<4096, 256, 0, stream>>>(Whi, Wlo, Ahi, Alo, benc, g32, ctrl, cand_idx, cand_sc, h1);
  } else {
    mfma_gemm<0><<<256, 256, 0, stream>>>(Wenc, Ahi, Alo, benc, g32, ghist, ctrl, nullptr, nullptr);
    find_coarse_kernel<<<1, 64, 0, stream>>>(ghist, ctrl, kptr, 16);
    mfma_gemm<1><<<4096, 256, 0, stream>>>(Wenc, Ahi, Alo, benc, g32, nullptr, ctrl, cand_idx, cand_sc);
    chist_kernel<<<1024, 256, 0, stream>>>(cand_sc, ctrl, h1, 0);
  }
  cfind_kernel<<<1, 64, 0, stream>>>(h1, ctrl, kptr, 0);
  chist_kernel<<<1024, 256, 0, stream>>>(cand_sc, ctrl, h2, 1);
  cfind_kernel<<<1, 64, 0, stream>>>(h2, ctrl, kptr, 1);
  chist_kernel<<<1024, 256, 0, stream>>>(cand_sc, ctrl, h3, 2);
  cfind_kernel<<<1, 64, 0, stream>>>(h3, ctrl, kptr, 2);
  band_kernel<<<1024, 256, 0, stream>>>(cand_idx, cand_sc, g32, ctrl, row_cnt, row_feat, row_act, cand2_idx);
  cand2_score_kernel<<<4096, 256, 0, stream>>>(ctrl, cand2_idx, x, Wdec, benc, g64, cand2_sc);
  cand2_rank_kernel<<<2048, 256, 0, stream>>>(ctrl, cand2_idx, cand2_sc, g64, kptr, row_cnt, row_feat, row_act);
  recon_kernel<<<BATCH, 256, 0, stream>>>(row_cnt, row_feat, row_act, Wdec, bdec, out);
}

// Round 13
// 837.538 us; speedup vs baseline: 1.0079x; 1.0079x over previous
//
#include <hip/hip_runtime.h>
#include <math.h>

#define D_MODEL 1024
#define D_SAE   16384
#define BATCH   4096
#define NTOT    (1ull * BATCH * D_SAE)
#define LN_EPS  1e-8
#define EPS_M   3e-4f        // |split-bf16 score - fp64 score| safe band half-width (>=6x margin)
#define ROW_CAP 256
#define CAND_CAP  (4 * 1024 * 1024)
#define CAND2_CAP 65536

using bf16x8 = __attribute__((ext_vector_type(8))) short;
using f32x4  = __attribute__((ext_vector_type(4))) float;

__device__ inline unsigned short f2bf(float f) {   // RNE fp32->bf16
  unsigned u = __float_as_uint(f);
  return (unsigned short)((u + 0x7fffu + ((u >> 16) & 1u)) >> 16);
}
__device__ inline float bf2f(unsigned short h) {
  return __uint_as_float((unsigned)h << 16);
}

// ---------- block (256-thread) reductions ----------
__device__ inline double blockReduceSum256(double v, double* lds) {
#pragma unroll
  for (int off = 32; off > 0; off >>= 1) v += __shfl_down(v, off, 64);
  int lane = threadIdx.x & 63, wid = threadIdx.x >> 6;
  __syncthreads();
  if (lane == 0) lds[wid] = v;
  __syncthreads();
  return lds[0] + lds[1] + lds[2] + lds[3];
}
__device__ inline int blockReduceSumInt256(int v, int* lds) {
#pragma unroll
  for (int off = 32; off > 0; off >>= 1) v += __shfl_down(v, off, 64);
  int lane = threadIdx.x & 63, wid = threadIdx.x >> 6;
  __syncthreads();
  if (lane == 0) lds[wid] = v;
  __syncthreads();
  return lds[0] + lds[1] + lds[2] + lds[3];
}

__device__ inline int wave_append(bool pred, int* counter) {
  unsigned long long m = __ballot(pred);
  int lane = threadIdx.x & 63;
  int pos = -1;
  if (m) {
    int ldr = __ffsll((long long)m) - 1;
    int base = 0;
    if (lane == ldr) base = atomicAdd(counter, __popcll(m));
    base = __shfl(base, ldr, 64);
    if (pred) pos = base + __popcll(m & ((1ull << lane) - 1ull));
  }
  return pos;
}

// ---------- 64-lane parallel descending histogram scan ----------
__device__ inline void hist_scan_desc(const int* __restrict__ hist, int nbins, int need,
                                      int& bsel, int& cumsel) {
  int t = threadIdx.x;          // 0..63
  int chunk = nbins >> 6;
  int topbase = nbins - t * chunk;
  int psum = 0;
  for (int i = 1; i <= chunk; ++i) psum += hist[topbase - i];
  int incl = psum;
#pragma unroll
  for (int off = 1; off < 64; off <<= 1) {
    int v = __shfl_up(incl, off, 64);
    if (t >= off) incl += v;
  }
  int excl = incl - psum;
  bool hit = (excl < need) && (excl + psum >= need);
  unsigned long long m = __ballot(hit);
  int tb = m ? (__ffsll((long long)m) - 1) : 63;
  int exb = __shfl(excl, tb, 64);
  int res_b = 0, res_c = 0;
  if (t == tb) {
    int c = exb;
    int b = nbins - tb * chunk - 1;
    int bend = b - chunk;
    for (; b > 0 && b > bend; --b) {
      int cc = hist[b];
      if (c + cc >= need) break;
      c += cc;
    }
    res_b = b; res_c = c;
  }
  bsel = __shfl(res_b, tb, 64);
  cumsel = __shfl(res_c, tb, 64);
}

// ---------- per-thread fp64 LN chain: thread t owns elements t*4..t*4+3 ----------
__device__ inline void ln_row_fp64(const float* __restrict__ row, double* lds, double d[4]) {
  int t = threadIdx.x;
  float4 s4 = *(const float4*)(row + t * 4);
  float4 t4 = *(const float4*)(row + D_MODEL + t * 4);
  double s[4] = {s4.x, s4.y, s4.z, s4.w};
  double tt[4] = {t4.x, t4.y, t4.z, t4.w};
  double ms = blockReduceSum256(s[0] + s[1] + s[2] + s[3], lds) / D_MODEL;
  double mt = blockReduceSum256(tt[0] + tt[1] + tt[2] + tt[3], lds) / D_MODEL;
  double vs = 0, vt = 0;
#pragma unroll
  for (int i = 0; i < 4; i++) { double a = s[i] - ms; vs += a * a; a = tt[i] - mt; vt += a * a; }
  vs = blockReduceSum256(vs, lds) / D_MODEL;
  vt = blockReduceSum256(vt, lds) / D_MODEL;
  double rs = sqrt(vs + LN_EPS), rt = sqrt(vt + LN_EPS);
  double u[4];
#pragma unroll
  for (int i = 0; i < 4; i++) u[i] = (tt[i] - mt) / rt - (s[i] - ms) / rs;
  double mu = blockReduceSum256(u[0] + u[1] + u[2] + u[3], lds) / D_MODEL;
  double vu = 0;
#pragma unroll
  for (int i = 0; i < 4; i++) { double a = u[i] - mu; vu += a * a; }
  vu = blockReduceSum256(vu, lds) / D_MODEL;
  double ru = sqrt(vu + LN_EPS);
#pragma unroll
  for (int i = 0; i < 4; i++) d[i] = (u[i] - mu) / ru;
}

// ---------- LN -> split-bf16 A in GEMM-tiled layout [mt][ks][kc][ml][e] ----------
__global__ __launch_bounds__(256) void ln_kernel(const float* __restrict__ x,
                                                 short* __restrict__ Ahi, short* __restrict__ Alo) {
  __shared__ double lds[4];
  int b = blockIdx.x, t = threadIdx.x;
  double d[4];
  ln_row_fp64(x + (size_t)b * (2 * D_MODEL), lds, d);
  int mt = b >> 7, ml = b & 127;
  int ks = t >> 3, kc = (t >> 1) & 3, e0 = (t & 1) * 4;
  size_t base = ((((size_t)mt * 32 + ks) * 4 + kc) * 128 + ml) * 8 + e0;
  short h[4], l[4];
#pragma unroll
  for (int i = 0; i < 4; i++) {
    float f = (float)d[i];
    unsigned short hh = f2bf(f);
    h[i] = (short)hh;
    l[i] = (short)f2bf(f - bf2f(hh));
  }
  *(short4*)&Ahi[base] = make_short4(h[0], h[1], h[2], h[3]);
  *(short4*)&Alo[base] = make_short4(l[0], l[1], l[2], l[3]);
}

// ---------- dec_norms in fp64 (wave-per-feature, no block syncs) ----------
__global__ __launch_bounds__(256) void norm_kernel(const float* __restrict__ Wdec,
                                                   double* __restrict__ g64, float* __restrict__ g32) {
  int wv = threadIdx.x >> 6, lane = threadIdx.x & 63;
  int j = (blockIdx.x << 2) | wv;
  const float4* rowp = (const float4*)(Wdec + (size_t)j * D_MODEL);
  double a = 0;
#pragma unroll
  for (int q = 0; q < 4; ++q) {
    float4 w = rowp[lane + q * 64];
    a += (double)w.x * w.x + (double)w.y * w.y + (double)w.z * w.z + (double)w.w * w.w;
  }
#pragma unroll
  for (int off = 32; off > 0; off >>= 1) a += __shfl_down(a, off, 64);
  if (lane == 0) { double g = sqrt(a); g64[j] = g; g32[j] = (float)g; }
}

// ---------- pre-split W_enc fp32 -> tiled bf16 hi/lo [nt][ks][kc][c][e] ----------
__global__ __launch_bounds__(256) void wsplit_kernel(const float* __restrict__ Wenc,
                                                     short* __restrict__ Whi, short* __restrict__ Wlo) {
  __shared__ short sh[4096];
  __shared__ short sl[4096];
  int blk = blockIdx.x;            // 4096 = 128 nt * 32 ks
  int nt = blk >> 5, ks = blk & 31;
  int t = threadIdx.x;
  int r = t >> 3;
  int cg = t & 7;
  int kc = r >> 3, e = r & 7;
  const float* src = Wenc + (size_t)(ks * 32 + r) * D_SAE + nt * 128 + cg;
#pragma unroll
  for (int j = 0; j < 16; ++j) {
    float f = src[j * 8];
    unsigned short hh = f2bf(f);
    short ll = (short)f2bf(f - bf2f(hh));
    int c = j * 8 + cg;
    sh[kc * 1024 + c * 8 + e] = (short)hh;
    sl[kc * 1024 + c * 8 + e] = ll;
  }
  __syncthreads();
  size_t obase = ((size_t)nt * 32 + ks) * 4096;
  *(float4*)&Whi[obase + t * 16]     = *(const float4*)&sh[t * 16];
  *(float4*)&Whi[obase + t * 16 + 8] = *(const float4*)&sh[t * 16 + 8];
  *(float4*)&Wlo[obase + t * 16]     = *(const float4*)&sl[t * 16];
  *(float4*)&Wlo[obase + t * 16 + 8] = *(const float4*)&sl[t * 16 + 8];
}

// ---------- hi-only subsampled hist GEMM (big path): per-wave privatized hist ----------
__global__ __launch_bounds__(256) void hist_gemm(
    const short* __restrict__ Whi, const short* __restrict__ Ahi,
    const float* __restrict__ benc, const float* __restrict__ g32,
    int* __restrict__ ghist) {
  __shared__ short sA[4096];
  __shared__ short sB[4096];
  __shared__ int h[4][2048];
  const int tid = threadIdx.x;
  const int lane = tid & 63;
  const int w = tid >> 6;
  const int wm = (w >> 1) * 64, wn = (w & 1) * 64;
  int lin = blockIdx.x;            // 512 = 4 mt * 128 nt
  int mt = lin >> 7, nt = lin & 127;
  const int col0 = nt * 128;
  for (int i = tid; i < 8192; i += 256) ((int*)h)[i] = 0;
  const size_t atile = (size_t)mt * 131072;
  const size_t btile = (size_t)nt * 131072;
  f32x4 acc[4][4] = {};
  const int kcl = lane >> 4, l15 = lane & 15;

  float4 a0, a1, b0, b1;
  {
    const float4* ah4 = (const float4*)(Ahi + atile);
    const float4* bh4 = (const float4*)(Whi + btile);
    a0 = ah4[tid]; a1 = ah4[tid + 256];
    b0 = bh4[tid]; b1 = bh4[tid + 256];
  }
  for (int ks = 0; ks < 32; ++ks) {
    __syncthreads();
    *(float4*)&sA[(size_t)tid * 8] = a0;
    *(float4*)&sA[(size_t)(tid + 256) * 8] = a1;
    *(float4*)&sB[(size_t)tid * 8] = b0;
    *(float4*)&sB[(size_t)(tid + 256) * 8] = b1;
    __syncthreads();
    if (ks < 31) {
      const float4* ah4 = (const float4*)(Ahi + atile + (ks + 1) * 4096);
      const float4* bh4 = (const float4*)(Whi + btile + (ks + 1) * 4096);
      a0 = ah4[tid]; a1 = ah4[tid + 256];
      b0 = bh4[tid]; b1 = bh4[tid + 256];
    }
    bf16x8 ahf[4];
#pragma unroll
    for (int fm = 0; fm < 4; ++fm)
      ahf[fm] = *(const bf16x8*)&sA[(kcl * 128 + wm + fm * 16 + l15) * 8];
#pragma unroll
    for (int fn = 0; fn < 4; ++fn) {
      bf16x8 bh = *(const bf16x8*)&sB[(kcl * 128 + wn + fn * 16 + l15) * 8];
#pragma unroll
      for (int fm = 0; fm < 4; ++fm)
        acc[fm][fn] = __builtin_amdgcn_mfma_f32_16x16x32_bf16(ahf[fm], bh, acc[fm][fn], 0, 0, 0);
    }
  }
#pragma unroll
  for (int fn = 0; fn < 4; ++fn) {
    int col = col0 + wn + fn * 16 + l15;
    float g = g32[col], be = benc[col];
#pragma unroll
    for (int fm = 0; fm < 4; ++fm) {
#pragma unroll
      for (int r = 0; r < 4; ++r) {
        float z = acc[fm][fn][r] + be;
        float s = z > 0.f ? z * g : 0.f;
        unsigned bits = __float_as_uint(s);
        if (bits) atomicAdd(&h[w][bits >> 21], 1);
      }
    }
  }
  __syncthreads();
  for (int i = tid; i < 2048; i += 256) {
    int v = h[0][i] + h[1][i] + h[2][i] + h[3][i];
    if (v) atomicAdd(&ghist[i], v);
  }
}

// ---------- 128x128 split-bf16 MFMA extract GEMM ----------
// Round-6-proven structure; pass-0 histogram ALIASED into sA after the K-loop
// so total LDS stays exactly 32768 B (sA+sB) -> max blocks/CU.
__global__ __launch_bounds__(256) void extract_gemm128(
    const short* __restrict__ Whi, const short* __restrict__ Wlo,
    const short* __restrict__ Ahi, const short* __restrict__ Alo,
    const float* __restrict__ benc, const float* __restrict__ g32,
    int* __restrict__ ctrl, int* __restrict__ cand_idx, float* __restrict__ cand_sc,
    int* __restrict__ ghist) {
  __shared__ short sA[8192];   // hi [4][128][8] | lo at +4096 ; reused as hist after K-loop
  __shared__ short sB[8192];

  const int tid = threadIdx.x;
  const int lane = tid & 63;
  const int w = tid >> 6;
  const int wm = (w >> 1) * 64, wn = (w & 1) * 64;

  // L2-locality: XCD owns 16 nt panels; 32 consecutive blocks share a panel
  int lin = blockIdx.x;
  int xcd = lin & 7, j = lin >> 3;
  int mt = j & 31;
  int nt = (xcd << 4) | (j >> 5);
  const int row0 = mt * 128, col0 = nt * 128;

  const size_t atile = (size_t)mt * 131072;
  const size_t btile = (size_t)nt * 131072;

  f32x4 acc[4][4] = {};
  const int kcl = lane >> 4, l15 = lane & 15;

  float4 a0, a1, a2, a3, b0, b1, b2, b3;
  {
    const float4* ah4 = (const float4*)(Ahi + atile);
    const float4* al4 = (const float4*)(Alo + atile);
    const float4* bh4 = (const float4*)(Whi + btile);
    const float4* bl4 = (const float4*)(Wlo + btile);
    a0 = ah4[tid]; a1 = ah4[tid + 256];
    a2 = al4[tid]; a3 = al4[tid + 256];
    b0 = bh4[tid]; b1 = bh4[tid + 256];
    b2 = bl4[tid]; b3 = bl4[tid + 256];
  }

  for (int ks = 0; ks < 32; ++ks) {
    __syncthreads();   // previous tile fully consumed
    *(float4*)&sA[(size_t)tid * 8] = a0;
    *(float4*)&sA[(size_t)(tid + 256) * 8] = a1;
    *(float4*)&sA[(size_t)(512 + tid) * 8] = a2;
    *(float4*)&sA[(size_t)(512 + tid + 256) * 8] = a3;
    *(float4*)&sB[(size_t)tid * 8] = b0;
    *(float4*)&sB[(size_t)(tid + 256) * 8] = b1;
    *(float4*)&sB[(size_t)(512 + tid) * 8] = b2;
    *(float4*)&sB[(size_t)(512 + tid + 256) * 8] = b3;
    __syncthreads();   // tile visible
    if (ks < 31) {
      const int o = (ks + 1) * 4096;
      const float4* ah4 = (const float4*)(Ahi + atile + o);
      const float4* al4 = (const float4*)(Alo + atile + o);
      const float4* bh4 = (const float4*)(Whi + btile + o);
      const float4* bl4 = (const float4*)(Wlo + btile + o);
      a0 = ah4[tid]; a1 = ah4[tid + 256];
      a2 = al4[tid]; a3 = al4[tid + 256];
      b0 = bh4[tid]; b1 = bh4[tid + 256];
      b2 = bl4[tid]; b3 = bl4[tid + 256];
    }
    bf16x8 ahf[4], alf[4];
#pragma unroll
    for (int fm = 0; fm < 4; ++fm) {
      int off = (kcl * 128 + wm + fm * 16 + l15) * 8;
      ahf[fm] = *(const bf16x8*)&sA[off];
      alf[fm] = *(const bf16x8*)&sA[4096 + off];
    }
#pragma unroll
    for (int fn = 0; fn < 4; ++fn) {
      int boff = (kcl * 128 + wn + fn * 16 + l15) * 8;
      bf16x8 bh = *(const bf16x8*)&sB[boff];
      bf16x8 bl = *(const bf16x8*)&sB[4096 + boff];
#pragma unroll
      for (int fm = 0; fm < 4; ++fm) {
        acc[fm][fn] = __builtin_amdgcn_mfma_f32_16x16x32_bf16(ahf[fm], bh, acc[fm][fn], 0, 0, 0);
        acc[fm][fn] = __builtin_amdgcn_mfma_f32_16x16x32_bf16(alf[fm], bh, acc[fm][fn], 0, 0, 0);
        acc[fm][fn] = __builtin_amdgcn_mfma_f32_16x16x32_bf16(ahf[fm], bl, acc[fm][fn], 0, 0, 0);
      }
    }
  }

  // epilogue: alias hist into sA (dead after K-loop). hh[0..2047]=hist,
  // hh[2048]=block count, hh[2049]=global base.
  int* hh = (int*)sA;
  const int l4r = lane >> 4;
  unsigned thrBits = (unsigned)ctrl[1];
  __syncthreads();                         // all sA fragment reads done
  for (int i = tid; i < 2050; i += 256) hh[i] = 0;
  __syncthreads();
  int cnt = 0;
#pragma unroll
  for (int fn = 0; fn < 4; ++fn) {
    int col = col0 + wn + fn * 16 + l15;
    float g = g32[col], be = benc[col];
#pragma unroll
    for (int fm = 0; fm < 4; ++fm) {
#pragma unroll
      for (int r = 0; r < 4; ++r) {
        float z = acc[fm][fn][r] + be;
        float s = z > 0.f ? z * g : 0.f;
        unsigned bits = __float_as_uint(s);
        if (bits >= thrBits) { cnt++; atomicAdd(&hh[bits >> 21], 1); }
      }
    }
  }
  int my = 0;
  if (cnt) my = atomicAdd(&hh[2048], cnt);
  __syncthreads();
  if (tid == 0) hh[2049] = atomicAdd(&ctrl[2], hh[2048]);
  for (int i = tid; i < 2048; i += 256)
    if (hh[i]) atomicAdd(&ghist[i], hh[i]);
  __syncthreads();
  int pos = hh[2049] + my;
#pragma unroll
  for (int fn = 0; fn < 4; ++fn) {
    int col = col0 + wn + fn * 16 + l15;
    float g = g32[col], be = benc[col];
#pragma unroll
    for (int fm = 0; fm < 4; ++fm) {
      int rowb = row0 + wm + fm * 16 + l4r * 4;
#pragma unroll
      for (int r = 0; r < 4; ++r) {
        float z = acc[fm][fn][r] + be;
        float s = z > 0.f ? z * g : 0.f;
        if (__float_as_uint(s) >= thrBits) {
          if (pos < CAND_CAP) { cand_idx[pos] = (rowb + r) * D_SAE + col; cand_sc[pos] = s; }
          pos++;
        }
      }
    }
  }
}

// ---------- fallback 128^2 GEMM (small ws): MODE 0 = hist (1/16), MODE 1 = extract ----------
template <int MODE>
__global__ __launch_bounds__(256) void mfma_gemm(
    const float* __restrict__ Wenc,
    const short* __restrict__ Ahi, const short* __restrict__ Alo,
    const float* __restrict__ benc, const float* __restrict__ g32,
    int* __restrict__ ghist, int* __restrict__ ctrl,
    int* __restrict__ cand_idx, float* __restrict__ cand_sc) {
  __shared__ short sA[8192];
  __shared__ short sB[8192];
  __shared__ int h[(MODE == 0) ? 2048 : 2];
  const int tid = threadIdx.x;
  const int lane = tid & 63;
  const int w = tid >> 6;
  const int wm = (w >> 1) * 64, wn = (w & 1) * 64;
  int lin = blockIdx.x;
  int mt, nt;
  if (MODE == 0) { mt = lin >> 7; nt = lin & 127; }
  else { int xcd = lin & 7, j = lin >> 3; mt = j & 31; nt = (xcd << 4) | (j >> 5); }
  const int row0 = mt * 128, col0 = nt * 128;
  if (MODE == 0) { for (int i = tid; i < 2048; i += 256) h[i] = 0; }
  else if (tid == 0) h[0] = 0;
  const int nl = tid & 127;
  const int half = tid >> 7;
  const float* wbase = Wenc + (size_t)col0 + nl;
  const size_t atile = (size_t)mt * 131072;
  f32x4 acc[4][4] = {};
  const int kcl = lane >> 4, l15 = lane & 15;
  float4 a0, a1, a2, a3;
  float bfv[16];
  {
    const float4* ah4 = (const float4*)(Ahi + atile);
    const float4* al4 = (const float4*)(Alo + atile);
    a0 = ah4[tid]; a1 = ah4[tid + 256];
    a2 = al4[tid]; a3 = al4[tid + 256];
#pragma unroll
    for (int p = 0; p < 4; ++p)
#pragma unroll
      for (int i = 0; i < 4; ++i)
        bfv[p * 4 + i] = wbase[(size_t)(p * 8 + half * 4 + i) * D_SAE];
  }
  for (int ks = 0; ks < 32; ++ks) {
    short hb[16], lb[16];
#pragma unroll
    for (int q = 0; q < 16; ++q) {
      unsigned short hh = f2bf(bfv[q]);
      hb[q] = (short)hh;
      lb[q] = (short)f2bf(bfv[q] - bf2f(hh));
    }
    __syncthreads();
    *(float4*)&sA[(size_t)tid * 8] = a0;
    *(float4*)&sA[(size_t)(tid + 256) * 8] = a1;
    *(float4*)&sA[(size_t)(512 + tid) * 8] = a2;
    *(float4*)&sA[(size_t)(512 + tid + 256) * 8] = a3;
#pragma unroll
    for (int p = 0; p < 4; ++p) {
      int boff = p * 1024 + nl * 8 + half * 4;
      *(short4*)&sB[boff] = make_short4(hb[p * 4], hb[p * 4 + 1], hb[p * 4 + 2], hb[p * 4 + 3]);
      *(short4*)&sB[4096 + boff] = make_short4(lb[p * 4], lb[p * 4 + 1], lb[p * 4 + 2], lb[p * 4 + 3]);
    }
    __syncthreads();
    if (ks < 31) {
      const float4* ah4 = (const float4*)(Ahi + atile + (ks + 1) * 4096);
      const float4* al4 = (const float4*)(Alo + atile + (ks + 1) * 4096);
      a0 = ah4[tid]; a1 = ah4[tid + 256];
      a2 = al4[tid]; a3 = al4[tid + 256];
      const int k0n = (ks + 1) * 32;
#pragma unroll
      for (int p = 0; p < 4; ++p)
#pragma unroll
        for (int i = 0; i < 4; ++i)
          bfv[p * 4 + i] = wbase[(size_t)(k0n + p * 8 + half * 4 + i) * D_SAE];
    }
    bf16x8 ahf[4], alf[4];
#pragma unroll
    for (int fm = 0; fm < 4; ++fm) {
      int off = (kcl * 128 + wm + fm * 16 + l15) * 8;
      ahf[fm] = *(const bf16x8*)&sA[off];
      alf[fm] = *(const bf16x8*)&sA[4096 + off];
    }
#pragma unroll
    for (int fn = 0; fn < 4; ++fn) {
      int boff = (kcl * 128 + wn + fn * 16 + l15) * 8;
      bf16x8 bh = *(const bf16x8*)&sB[boff];
      bf16x8 bl = *(const bf16x8*)&sB[4096 + boff];
#pragma unroll
      for (int fm = 0; fm < 4; ++fm) {
        acc[fm][fn] = __builtin_amdgcn_mfma_f32_16x16x32_bf16(ahf[fm], bh, acc[fm][fn], 0, 0, 0);
        acc[fm][fn] = __builtin_amdgcn_mfma_f32_16x16x32_bf16(alf[fm], bh, acc[fm][fn], 0, 0, 0);
        acc[fm][fn] = __builtin_amdgcn_mfma_f32_16x16x32_bf16(ahf[fm], bl, acc[fm][fn], 0, 0, 0);
      }
    }
  }
  const int l4r = lane >> 4;
  if (MODE == 0) {
#pragma unroll
    for (int fn = 0; fn < 4; ++fn) {
      int col = col0 + wn + fn * 16 + l15;
      float g = g32[col], be = benc[col];
#pragma unroll
      for (int fm = 0; fm < 4; ++fm) {
#pragma unroll
        for (int r = 0; r < 4; ++r) {
          float z = acc[fm][fn][r] + be;
          float s = z > 0.f ? z * g : 0.f;
          unsigned bits = __float_as_uint(s);
          if (bits) atomicAdd(&h[bits >> 21], 1);
        }
      }
    }
    __syncthreads();
    for (int i = tid; i < 2048; i += 256)
      if (h[i]) atomicAdd(&ghist[i], h[i]);
  } else {
    unsigned thrBits = (unsigned)ctrl[1];
    int cnt = 0;
#pragma unroll
    for (int fn = 0; fn < 4; ++fn) {
      int col = col0 + wn + fn * 16 + l15;
      float g = g32[col], be = benc[col];
#pragma unroll
      for (int fm = 0; fm < 4; ++fm) {
#pragma unroll
        for (int r = 0; r < 4; ++r) {
          float z = acc[fm][fn][r] + be;
          float s = z > 0.f ? z * g : 0.f;
          cnt += (__float_as_uint(s) >= thrBits) ? 1 : 0;
        }
      }
    }
    int my = 0;
    if (cnt) my = atomicAdd(&h[0], cnt);
    __syncthreads();
    if (tid == 0) h[1] = atomicAdd(&ctrl[2], h[0]);
    __syncthreads();
    int pos = h[1] + my;
#pragma unroll
    for (int fn = 0; fn < 4; ++fn) {
      int col = col0 + wn + fn * 16 + l15;
      float g = g32[col], be = benc[col];
#pragma unroll
      for (int fm = 0; fm < 4; ++fm) {
        int rowb = row0 + wm + fm * 16 + l4r * 4;
#pragma unroll
        for (int r = 0; r < 4; ++r) {
          float z = acc[fm][fn][r] + be;
          float s = z > 0.f ? z * g : 0.f;
          if (__float_as_uint(s) >= thrBits) {
            if (pos < CAND_CAP) { cand_idx[pos] = (rowb + r) * D_SAE + col; cand_sc[pos] = s; }
            pos++;
          }
        }
      }
    }
  }
}

// ---------- coarse threshold (64-thread parallel scan) ----------
__global__ void find_coarse_kernel(const int* __restrict__ gh, int* ctrl,
                                   const int* __restrict__ kptr, int sub) {
  long long kB = (long long)kptr[0] * BATCH;
  long long needl = (kB + 500000 + sub - 1) / sub;
  long long fl = 720000 / sub;
  if (needl < fl) needl = fl;
  int b, cum;
  hist_scan_desc(gh, 2048, (int)needl, b, cum);
  if (threadIdx.x == 0) {
    long long est_incl = (long long)sub * (cum + gh[b]);
    if (est_incl > 3500000LL && (long long)sub * cum >= kB + 120000LL) b = b + 1;
    ctrl[1] = (int)(((unsigned)b) << 21);
  }
}

// ---------- radix histograms over candidate scores (passes 1,2) ----------
__global__ __launch_bounds__(256) void chist_kernel(const float* __restrict__ cand_sc,
                                                    const int* __restrict__ ctrl,
                                                    int* __restrict__ ghist, int pass) {
  __shared__ int h[2048];
  int nb = (pass == 2) ? 1024 : 2048;
  for (int i = threadIdx.x; i < nb; i += 256) h[i] = 0;
  __syncthreads();
  int n = ctrl[2]; if (n > CAND_CAP) n = CAND_CAP;
  unsigned sel1 = 0, sel22 = 0;
  if (pass == 1) sel1 = (unsigned)ctrl[3];
  if (pass == 2) sel22 = ((unsigned)ctrl[3] << 11) | (unsigned)ctrl[5];
  for (int i = blockIdx.x * 256 + threadIdx.x; i < n; i += gridDim.x * 256) {
    unsigned bits = __float_as_uint(cand_sc[i]);
    if (pass == 0) atomicAdd(&h[bits >> 21], 1);
    else if (pass == 1) { if ((bits >> 21) == sel1) atomicAdd(&h[(bits >> 10) & 0x7FFu], 1); }
    else { if ((bits >> 10) == sel22) atomicAdd(&h[bits & 0x3FFu], 1); }
  }
  __syncthreads();
  for (int i = threadIdx.x; i < nb; i += 256)
    if (h[i]) atomicAdd(&ghist[i], h[i]);
}

// ---------- radix select step (64-thread parallel scan) ----------
__global__ void cfind_kernel(const int* __restrict__ hist, int* ctrl,
                             const int* __restrict__ kptr, int pass) {
  int kB = kptr[0] * BATCH;
  int need, nbins;
  if (pass == 0)      { need = kB;                       nbins = 2048; }
  else if (pass == 1) { need = kB - ctrl[4];             nbins = 2048; }
  else                { need = kB - ctrl[4] - ctrl[6];   nbins = 1024; }
  int b, cum;
  hist_scan_desc(hist, nbins, need, b, cum);
  if (threadIdx.x == 0) {
    if (pass == 0)      { ctrl[3] = b; ctrl[4] = cum; }
    else if (pass == 1) { ctrl[5] = b; ctrl[6] = cum; }
    else {
      unsigned vbits = ((unsigned)ctrl[3] << 21) | ((unsigned)ctrl[5] << 10) | (unsigned)b;
      float V = __uint_as_float(vbits);
      float* cf = (float*)ctrl;
      cf[8] = V; cf[9] = V + EPS_M; cf[10] = V - EPS_M;
    }
  }
}

// ---------- band partition ----------
__global__ __launch_bounds__(256) void band_kernel(const int* __restrict__ cand_idx,
    const float* __restrict__ cand_sc, const float* __restrict__ g32,
    int* ctrl, int* row_cnt, int* row_feat, float* row_act, int* cand2_idx) {
  const float* cf = (const float*)ctrl;
  float hi = cf[9], lo = cf[10];
  int n = ctrl[2]; if (n > CAND_CAP) n = CAND_CAP;
  int lane = threadIdx.x & 63;
  int defc = 0;
  for (int i = blockIdx.x * 256 + threadIdx.x; i < n; i += gridDim.x * 256) {
    float s = cand_sc[i];
    int flat = cand_idx[i];
    if (s > hi) {
      int b = flat >> 14, j = flat & (D_SAE - 1);
      int p = atomicAdd(&row_cnt[b], 1);
      if (p < ROW_CAP) { row_feat[b * ROW_CAP + p] = j; row_act[b * ROW_CAP + p] = s / g32[j]; }
      defc++;
    }
    bool isc = (s <= hi) && (s >= lo);
    int pos = wave_append(isc, &ctrl[12]);
    if (isc && pos >= 0 && pos < CAND2_CAP) cand2_idx[pos] = flat;
  }
#pragma unroll
  for (int off = 32; off > 0; off >>= 1) defc += __shfl_down(defc, off, 64);
  if (lane == 0 && defc) atomicAdd(&ctrl[11], defc);
}

// ---------- fp64 rescore of band candidates ----------
__global__ __launch_bounds__(256) void cand2_score_kernel(const int* __restrict__ ctrl,
    const int* __restrict__ cand2_idx, const float* __restrict__ x,
    const float* __restrict__ Wdec, const float* __restrict__ benc,
    const double* __restrict__ g64, double* __restrict__ cand2_sc) {
  __shared__ double lds[4];
  int n2 = ctrl[12]; if (n2 > CAND2_CAP) n2 = CAND2_CAP;
  int t = threadIdx.x;
  for (int c = blockIdx.x; c < n2; c += gridDim.x) {
    int flat = cand2_idx[c];
    int b = flat >> 14, j = flat & (D_SAE - 1);
    double d[4];
    ln_row_fp64(x + (size_t)b * (2 * D_MODEL), lds, d);
    float4 w4 = *(const float4*)(Wdec + (size_t)j * D_MODEL + t * 4);
    double a = d[0] * (double)w4.x + d[1] * (double)w4.y + d[2] * (double)w4.z + d[3] * (double)w4.w;
    double z = blockReduceSum256(a, lds) + (double)benc[j];
    double sc = z > 0 ? z * g64[j] : 0.0;
    if (t == 0) cand2_sc[c] = sc;
  }
}

// ---------- rank band candidates (fp64, index-stable), accept fill ----------
__global__ __launch_bounds__(256) void cand2_rank_kernel(const int* __restrict__ ctrl,
    const int* __restrict__ cand2_idx, const double* __restrict__ cand2_sc,
    const double* __restrict__ g64, const int* __restrict__ kptr,
    int* row_cnt, int* row_feat, float* row_act) {
  __shared__ int lds[4];
  int n2 = ctrl[12]; if (n2 > CAND2_CAP) n2 = CAND2_CAP;
  int kB = kptr[0] * BATCH;
  int fill = kB - ctrl[11];
  int t = threadIdx.x;
  for (int c = blockIdx.x; c < n2; c += gridDim.x) {
    double sc = cand2_sc[c];
    int fc = cand2_idx[c];
    int cnt = 0;
    for (int y = t; y < n2; y += 256) {
      double sy = cand2_sc[y];
      if (sy > sc || (sy == sc && cand2_idx[y] < fc)) cnt++;
    }
    cnt = blockReduceSumInt256(cnt, lds);
    if (t == 0 && cnt < fill) {
      int b = fc >> 14, j = fc & (D_SAE - 1);
      int p = atomicAdd(&row_cnt[b], 1);
      if (p < ROW_CAP) { row_feat[b * ROW_CAP + p] = j; row_act[b * ROW_CAP + p] = (float)(sc / g64[j]); }
    }
  }
}

// ---------- sparse recon (float4, 2-way ILP) ----------
__global__ __launch_bounds__(256) void recon_kernel(const int* __restrict__ row_cnt,
    const int* __restrict__ row_feat, const float* __restrict__ row_act,
    const float* __restrict__ Wdec, const float* __restrict__ bdec, float* __restrict__ out) {
  int b = blockIdx.x, t = threadIdx.x;
  float4 acc0 = *(const float4*)&bdec[t * 4];
  float4 acc1 = make_float4(0.f, 0.f, 0.f, 0.f);
  int n = row_cnt[b]; if (n > ROW_CAP) n = ROW_CAP;
  const int* rf = row_feat + (size_t)b * ROW_CAP;
  const float* ra = row_act + (size_t)b * ROW_CAP;
  int p = 0;
  for (; p + 2 <= n; p += 2) {
    int j0 = rf[p], j1 = rf[p + 1];
    float v0 = ra[p], v1 = ra[p + 1];
    float4 w0 = *(const float4*)(Wdec + (size_t)j0 * D_MODEL + t * 4);
    float4 w1 = *(const float4*)(Wdec + (size_t)j1 * D_MODEL + t * 4);
    acc0.x += v0 * w0.x; acc0.y += v0 * w0.y; acc0.z += v0 * w0.z; acc0.w += v0 * w0.w;
    acc1.x += v1 * w1.x; acc1.y += v1 * w1.y; acc1.z += v1 * w1.z; acc1.w += v1 * w1.w;
  }
  if (p < n) {
    int j0 = rf[p]; float v0 = ra[p];
    float4 w0 = *(const float4*)(Wdec + (size_t)j0 * D_MODEL + t * 4);
    acc0.x += v0 * w0.x; acc0.y += v0 * w0.y; acc0.z += v0 * w0.z; acc0.w += v0 * w0.w;
  }
  acc0.x += acc1.x; acc0.y += acc1.y; acc0.z += acc1.z; acc0.w += acc1.w;
  *(float4*)(out + (size_t)b * D_MODEL + t * 4) = acc0;
}

extern "C" void kernel_launch(void* const* d_in, const int* in_sizes, int n_in,
                              void* d_out, int out_size, void* d_ws, size_t ws_size,
                              hipStream_t stream) {
  const float* x    = (const float*)d_in[0];
  const float* Wenc = (const float*)d_in[1];
  const float* benc = (const float*)d_in[2];
  const float* Wdec = (const float*)d_in[3];
  const float* bdec = (const float*)d_in[4];
  const int*   kptr = (const int*)d_in[5];
  float* out = (float*)d_out;

  char* ws = (char*)d_ws;
  size_t off = 0;
  short*  Ahi       = (short*)(ws + off);  off += (size_t)BATCH * D_MODEL * 2;
  short*  Alo       = (short*)(ws + off);  off += (size_t)BATCH * D_MODEL * 2;
  int*    cand_idx  = (int*)(ws + off);    off += (size_t)CAND_CAP * 4;
  float*  cand_sc   = (float*)(ws + off);  off += (size_t)CAND_CAP * 4;
  int*    row_feat  = (int*)(ws + off);    off += (size_t)BATCH * ROW_CAP * 4;
  float*  row_act   = (float*)(ws + off);  off += (size_t)BATCH * ROW_CAP * 4;
  int*    cand2_idx = (int*)(ws + off);    off += (size_t)CAND2_CAP * 4;
  double* cand2_sc  = (double*)(ws + off); off += (size_t)CAND2_CAP * 8;
  double* g64       = (double*)(ws + off); off += (size_t)D_SAE * 8;
  float*  g32       = (float*)(ws + off);  off += (size_t)D_SAE * 4;
  char*   zbase     = ws + off;
  int* ghist   = (int*)(zbase);
  int* h1      = (int*)(zbase + 8192);
  int* h2      = (int*)(zbase + 16384);
  int* h3      = (int*)(zbase + 24576);
  int* ctrl    = (int*)(zbase + 28672);
  int* row_cnt = (int*)(zbase + 28928);
  size_t zbytes = 28928 + (size_t)BATCH * 4;
  size_t small_need = off + zbytes;
  if (small_need > ws_size) return;  // ~60 MB floor

  size_t big_off = (small_need + 255) & ~(size_t)255;
  short* Whi = (short*)(ws + big_off);
  short* Wlo = Whi + (size_t)D_MODEL * D_SAE;
  size_t big_need = big_off + (size_t)D_MODEL * D_SAE * 4;
  const bool big = (big_need <= ws_size);   // round-6/8/9-proven to fit

  hipMemsetAsync(zbase, 0, zbytes, stream);

  ln_kernel<<<BATCH, 256, 0, stream>>>(x, Ahi, Alo);
  norm_kernel<<<D_SAE / 4, 256, 0, stream>>>(Wdec, g64, g32);
  if (big) {
    wsplit_kernel<<<4096, 256, 0, stream>>>(Wenc, Whi, Wlo);
    hist_gemm<<<512, 256, 0, stream>>>(Whi, Ahi, benc, g32, ghist);
    find_coarse_kernel<<<1, 64, 0, stream>>>(ghist, ctrl, kptr, 8);
    extract_gemm128<<<4096, 256, 0, stream>>>(Whi, Wlo, Ahi, Alo, benc, g32, ctrl, cand_idx, cand_sc, h1);
  } else {
    mfma_gemm<0><<<256, 256, 0, stream>>>(Wenc, Ahi, Alo, benc, g32, ghist, ctrl, nullptr, nullptr);
    find_coarse_kernel<<<1, 64, 0, stream>>>(ghist, ctrl, kptr, 16);
    mfma_gemm<1><<<4096, 256, 0, stream>>>(Wenc, Ahi, Alo, benc, g32, nullptr, ctrl, cand_idx, cand_sc);
    chist_kernel<<<1024, 256, 0, stream>>>(cand_sc, ctrl, h1, 0);
  }
  cfind_kernel<<<1, 64, 0, stream>>>(h1, ctrl, kptr, 0);
  chist_kernel<<<1024, 256, 0, stream>>>(cand_sc, ctrl, h2, 1);
  cfind_kernel<<<1, 64, 0, stream>>>(h2, ctrl, kptr, 1);
  chist_kernel<<<1024, 256, 0, stream>>>(cand_sc, ctrl, h3, 2);
  cfind_kernel<<<1, 64, 0, stream>>>(h3, ctrl, kptr, 2);
  band_kernel<<<1024, 256, 0, stream>>>(cand_idx, cand_sc, g32, ctrl, row_cnt, row_feat, row_act, cand2_idx);
  cand2_score_kernel<<<4096, 256, 0, stream>>>(ctrl, cand2_idx, x, Wdec, benc, g64, cand2_sc);
  cand2_rank_kernel<<<2048, 256, 0, stream>>>(ctrl, cand2_idx, cand2_sc, g64, kptr, row_cnt, row_feat, row_act);
  recon_kernel<<<BATCH, 256, 0, stream>>>(row_cnt, row_feat, row_act, Wdec, bdec, out);
}

// Round 15
// 762.680 us; speedup vs baseline: 1.1068x; 1.0982x over previous
//
#include <hip/hip_runtime.h>
#include <math.h>

#define D_MODEL 1024
#define D_SAE   16384
#define BATCH   4096
#define NTOT    (1ull * BATCH * D_SAE)
#define LN_EPS  1e-8
#define EPS_M   3e-4f        // |split-bf16 score - fp64 score| safe band half-width (>=6x margin)
#define ROW_CAP 256
#define CAND_CAP  (4 * 1024 * 1024)
#define CAND2_CAP 65536

using bf16x8 = __attribute__((ext_vector_type(8))) short;
using f32x4  = __attribute__((ext_vector_type(4))) float;

__device__ inline unsigned short f2bf(float f) {   // RNE fp32->bf16
  unsigned u = __float_as_uint(f);
  return (unsigned short)((u + 0x7fffu + ((u >> 16) & 1u)) >> 16);
}
__device__ inline float bf2f(unsigned short h) {
  return __uint_as_float((unsigned)h << 16);
}

// ---------- block (256-thread) reductions ----------
__device__ inline double blockReduceSum256(double v, double* lds) {
#pragma unroll
  for (int off = 32; off > 0; off >>= 1) v += __shfl_down(v, off, 64);
  int lane = threadIdx.x & 63, wid = threadIdx.x >> 6;
  __syncthreads();
  if (lane == 0) lds[wid] = v;
  __syncthreads();
  return lds[0] + lds[1] + lds[2] + lds[3];
}
__device__ inline int blockReduceSumInt256(int v, int* lds) {
#pragma unroll
  for (int off = 32; off > 0; off >>= 1) v += __shfl_down(v, off, 64);
  int lane = threadIdx.x & 63, wid = threadIdx.x >> 6;
  __syncthreads();
  if (lane == 0) lds[wid] = v;
  __syncthreads();
  return lds[0] + lds[1] + lds[2] + lds[3];
}

__device__ inline int wave_append(bool pred, int* counter) {
  unsigned long long m = __ballot(pred);
  int lane = threadIdx.x & 63;
  int pos = -1;
  if (m) {
    int ldr = __ffsll((long long)m) - 1;
    int base = 0;
    if (lane == ldr) base = atomicAdd(counter, __popcll(m));
    base = __shfl(base, ldr, 64);
    if (pred) pos = base + __popcll(m & ((1ull << lane) - 1ull));
  }
  return pos;
}

// ---------- 64-lane parallel descending histogram scan ----------
__device__ inline void hist_scan_desc(const int* __restrict__ hist, int nbins, int need,
                                      int& bsel, int& cumsel) {
  int t = threadIdx.x;          // 0..63
  int chunk = nbins >> 6;
  int topbase = nbins - t * chunk;
  int psum = 0;
  for (int i = 1; i <= chunk; ++i) psum += hist[topbase - i];
  int incl = psum;
#pragma unroll
  for (int off = 1; off < 64; off <<= 1) {
    int v = __shfl_up(incl, off, 64);
    if (t >= off) incl += v;
  }
  int excl = incl - psum;
  bool hit = (excl < need) && (excl + psum >= need);
  unsigned long long m = __ballot(hit);
  int tb = m ? (__ffsll((long long)m) - 1) : 63;
  int exb = __shfl(excl, tb, 64);
  int res_b = 0, res_c = 0;
  if (t == tb) {
    int c = exb;
    int b = nbins - tb * chunk - 1;
    int bend = b - chunk;
    for (; b > 0 && b > bend; --b) {
      int cc = hist[b];
      if (c + cc >= need) break;
      c += cc;
    }
    res_b = b; res_c = c;
  }
  bsel = __shfl(res_b, tb, 64);
  cumsel = __shfl(res_c, tb, 64);
}

// ---------- per-thread fp64 LN chain: thread t owns elements t*4..t*4+3 ----------
__device__ inline void ln_row_fp64(const float* __restrict__ row, double* lds, double d[4]) {
  int t = threadIdx.x;
  float4 s4 = *(const float4*)(row + t * 4);
  float4 t4 = *(const float4*)(row + D_MODEL + t * 4);
  double s[4] = {s4.x, s4.y, s4.z, s4.w};
  double tt[4] = {t4.x, t4.y, t4.z, t4.w};
  double ms = blockReduceSum256(s[0] + s[1] + s[2] + s[3], lds) / D_MODEL;
  double mt = blockReduceSum256(tt[0] + tt[1] + tt[2] + tt[3], lds) / D_MODEL;
  double vs = 0, vt = 0;
#pragma unroll
  for (int i = 0; i < 4; i++) { double a = s[i] - ms; vs += a * a; a = tt[i] - mt; vt += a * a; }
  vs = blockReduceSum256(vs, lds) / D_MODEL;
  vt = blockReduceSum256(vt, lds) / D_MODEL;
  double rs = sqrt(vs + LN_EPS), rt = sqrt(vt + LN_EPS);
  double u[4];
#pragma unroll
  for (int i = 0; i < 4; i++) u[i] = (tt[i] - mt) / rt - (s[i] - ms) / rs;
  double mu = blockReduceSum256(u[0] + u[1] + u[2] + u[3], lds) / D_MODEL;
  double vu = 0;
#pragma unroll
  for (int i = 0; i < 4; i++) { double a = u[i] - mu; vu += a * a; }
  vu = blockReduceSum256(vu, lds) / D_MODEL;
  double ru = sqrt(vu + LN_EPS);
#pragma unroll
  for (int i = 0; i < 4; i++) d[i] = (u[i] - mu) / ru;
}

// ---------- LN -> split-bf16 A in GEMM-tiled layout [mt][ks][kc][ml][e] ----------
__global__ __launch_bounds__(256) void ln_kernel(const float* __restrict__ x,
                                                 short* __restrict__ Ahi, short* __restrict__ Alo) {
  __shared__ double lds[4];
  int b = blockIdx.x, t = threadIdx.x;
  double d[4];
  ln_row_fp64(x + (size_t)b * (2 * D_MODEL), lds, d);
  int mt = b >> 7, ml = b & 127;
  int ks = t >> 3, kc = (t >> 1) & 3, e0 = (t & 1) * 4;
  size_t base = ((((size_t)mt * 32 + ks) * 4 + kc) * 128 + ml) * 8 + e0;
  short h[4], l[4];
#pragma unroll
  for (int i = 0; i < 4; i++) {
    float f = (float)d[i];
    unsigned short hh = f2bf(f);
    h[i] = (short)hh;
    l[i] = (short)f2bf(f - bf2f(hh));
  }
  *(short4*)&Ahi[base] = make_short4(h[0], h[1], h[2], h[3]);
  *(short4*)&Alo[base] = make_short4(l[0], l[1], l[2], l[3]);
}

// ---------- dec_norms in fp64 (wave-per-feature, no block syncs) ----------
__global__ __launch_bounds__(256) void norm_kernel(const float* __restrict__ Wdec,
                                                   double* __restrict__ g64, float* __restrict__ g32) {
  int wv = threadIdx.x >> 6, lane = threadIdx.x & 63;
  int j = (blockIdx.x << 2) | wv;
  const float4* rowp = (const float4*)(Wdec + (size_t)j * D_MODEL);
  double a = 0;
#pragma unroll
  for (int q = 0; q < 4; ++q) {
    float4 w = rowp[lane + q * 64];
    a += (double)w.x * w.x + (double)w.y * w.y + (double)w.z * w.z + (double)w.w * w.w;
  }
#pragma unroll
  for (int off = 32; off > 0; off >>= 1) a += __shfl_down(a, off, 64);
  if (lane == 0) { double g = sqrt(a); g64[j] = g; g32[j] = (float)g; }
}

// ---------- pre-split W_enc fp32 -> tiled bf16 hi/lo [nt][ks][kc][c][e] ----------
__global__ __launch_bounds__(256) void wsplit_kernel(const float* __restrict__ Wenc,
                                                     short* __restrict__ Whi, short* __restrict__ Wlo) {
  __shared__ short sh[4096];
  __shared__ short sl[4096];
  int blk = blockIdx.x;            // 4096 = 128 nt * 32 ks
  int nt = blk >> 5, ks = blk & 31;
  int t = threadIdx.x;
  int r = t >> 3;
  int cg = t & 7;
  int kc = r >> 3, e = r & 7;
  const float* src = Wenc + (size_t)(ks * 32 + r) * D_SAE + nt * 128 + cg;
#pragma unroll
  for (int j = 0; j < 16; ++j) {
    float f = src[j * 8];
    unsigned short hh = f2bf(f);
    short ll = (short)f2bf(f - bf2f(hh));
    int c = j * 8 + cg;
    sh[kc * 1024 + c * 8 + e] = (short)hh;
    sl[kc * 1024 + c * 8 + e] = ll;
  }
  __syncthreads();
  size_t obase = ((size_t)nt * 32 + ks) * 4096;
  *(float4*)&Whi[obase + t * 16]     = *(const float4*)&sh[t * 16];
  *(float4*)&Whi[obase + t * 16 + 8] = *(const float4*)&sh[t * 16 + 8];
  *(float4*)&Wlo[obase + t * 16]     = *(const float4*)&sl[t * 16];
  *(float4*)&Wlo[obase + t * 16 + 8] = *(const float4*)&sl[t * 16 + 8];
}

// ---------- hi-only subsampled hist GEMM (big path): per-wave privatized hist ----------
__global__ __launch_bounds__(256) void hist_gemm(
    const short* __restrict__ Whi, const short* __restrict__ Ahi,
    const float* __restrict__ benc, const float* __restrict__ g32,
    int* __restrict__ ghist) {
  __shared__ short sA[4096];
  __shared__ short sB[4096];
  __shared__ int h[4][2048];
  const int tid = threadIdx.x;
  const int lane = tid & 63;
  const int w = tid >> 6;
  const int wm = (w >> 1) * 64, wn = (w & 1) * 64;
  int lin = blockIdx.x;            // 512 = 4 mt * 128 nt
  int mt = lin >> 7, nt = lin & 127;
  const int col0 = nt * 128;
  for (int i = tid; i < 8192; i += 256) ((int*)h)[i] = 0;
  const size_t atile = (size_t)mt * 131072;
  const size_t btile = (size_t)nt * 131072;
  f32x4 acc[4][4] = {};
  const int kcl = lane >> 4, l15 = lane & 15;

  float4 a0, a1, b0, b1;
  {
    const float4* ah4 = (const float4*)(Ahi + atile);
    const float4* bh4 = (const float4*)(Whi + btile);
    a0 = ah4[tid]; a1 = ah4[tid + 256];
    b0 = bh4[tid]; b1 = bh4[tid + 256];
  }
  for (int ks = 0; ks < 32; ++ks) {
    __syncthreads();
    *(float4*)&sA[(size_t)tid * 8] = a0;
    *(float4*)&sA[(size_t)(tid + 256) * 8] = a1;
    *(float4*)&sB[(size_t)tid * 8] = b0;
    *(float4*)&sB[(size_t)(tid + 256) * 8] = b1;
    __syncthreads();
    if (ks < 31) {
      const float4* ah4 = (const float4*)(Ahi + atile + (ks + 1) * 4096);
      const float4* bh4 = (const float4*)(Whi + btile + (ks + 1) * 4096);
      a0 = ah4[tid]; a1 = ah4[tid + 256];
      b0 = bh4[tid]; b1 = bh4[tid + 256];
    }
    bf16x8 ahf[4];
#pragma unroll
    for (int fm = 0; fm < 4; ++fm)
      ahf[fm] = *(const bf16x8*)&sA[(kcl * 128 + wm + fm * 16 + l15) * 8];
#pragma unroll
    for (int fn = 0; fn < 4; ++fn) {
      bf16x8 bh = *(const bf16x8*)&sB[(kcl * 128 + wn + fn * 16 + l15) * 8];
#pragma unroll
      for (int fm = 0; fm < 4; ++fm)
        acc[fm][fn] = __builtin_amdgcn_mfma_f32_16x16x32_bf16(ahf[fm], bh, acc[fm][fn], 0, 0, 0);
    }
  }
#pragma unroll
  for (int fn = 0; fn < 4; ++fn) {
    int col = col0 + wn + fn * 16 + l15;
    float g = g32[col], be = benc[col];
#pragma unroll
    for (int fm = 0; fm < 4; ++fm) {
#pragma unroll
      for (int r = 0; r < 4; ++r) {
        float z = acc[fm][fn][r] + be;
        float s = z > 0.f ? z * g : 0.f;
        unsigned bits = __float_as_uint(s);
        if (bits) atomicAdd(&h[w][bits >> 21], 1);
      }
    }
  }
  __syncthreads();
  for (int i = tid; i < 2048; i += 256) {
    int v = h[0][i] + h[1][i] + h[2][i] + h[3][i];
    if (v) atomicAdd(&ghist[i], v);
  }
}

// ---------- 128x128 split-bf16 MFMA extract GEMM ----------
// Round-6-proven structure; pass-0 histogram aliased into sA; __launch_bounds__(256,3)
// pins 3 blocks/CU (total regs <= ~170) to restore round-6 occupancy.
__global__ __launch_bounds__(256, 3) void extract_gemm128(
    const short* __restrict__ Whi, const short* __restrict__ Wlo,
    const short* __restrict__ Ahi, const short* __restrict__ Alo,
    const float* __restrict__ benc, const float* __restrict__ g32,
    int* __restrict__ ctrl, int* __restrict__ cand_idx, float* __restrict__ cand_sc,
    int* __restrict__ ghist) {
  __shared__ short sA[8192];   // hi [4][128][8] | lo at +4096 ; reused as hist after K-loop
  __shared__ short sB[8192];

  const int tid = threadIdx.x;
  const int lane = tid & 63;
  const int w = tid >> 6;
  const int wm = (w >> 1) * 64, wn = (w & 1) * 64;

  // L2-locality: XCD owns 16 nt panels; 32 consecutive blocks share a panel
  int lin = blockIdx.x;
  int xcd = lin & 7, j = lin >> 3;
  int mt = j & 31;
  int nt = (xcd << 4) | (j >> 5);
  const int row0 = mt * 128, col0 = nt * 128;

  const size_t atile = (size_t)mt * 131072;
  const size_t btile = (size_t)nt * 131072;

  f32x4 acc[4][4] = {};
  const int kcl = lane >> 4, l15 = lane & 15;

  float4 a0, a1, a2, a3, b0, b1, b2, b3;
  {
    const float4* ah4 = (const float4*)(Ahi + atile);
    const float4* al4 = (const float4*)(Alo + atile);
    const float4* bh4 = (const float4*)(Whi + btile);
    const float4* bl4 = (const float4*)(Wlo + btile);
    a0 = ah4[tid]; a1 = ah4[tid + 256];
    a2 = al4[tid]; a3 = al4[tid + 256];
    b0 = bh4[tid]; b1 = bh4[tid + 256];
    b2 = bl4[tid]; b3 = bl4[tid + 256];
  }

  for (int ks = 0; ks < 32; ++ks) {
    __syncthreads();   // previous tile fully consumed
    *(float4*)&sA[(size_t)tid * 8] = a0;
    *(float4*)&sA[(size_t)(tid + 256) * 8] = a1;
    *(float4*)&sA[(size_t)(512 + tid) * 8] = a2;
    *(float4*)&sA[(size_t)(512 + tid + 256) * 8] = a3;
    *(float4*)&sB[(size_t)tid * 8] = b0;
    *(float4*)&sB[(size_t)(tid + 256) * 8] = b1;
    *(float4*)&sB[(size_t)(512 + tid) * 8] = b2;
    *(float4*)&sB[(size_t)(512 + tid + 256) * 8] = b3;
    __syncthreads();   // tile visible
    if (ks < 31) {
      const int o = (ks + 1) * 4096;
      const float4* ah4 = (const float4*)(Ahi + atile + o);
      const float4* al4 = (const float4*)(Alo + atile + o);
      const float4* bh4 = (const float4*)(Whi + btile + o);
      const float4* bl4 = (const float4*)(Wlo + btile + o);
      a0 = ah4[tid]; a1 = ah4[tid + 256];
      a2 = al4[tid]; a3 = al4[tid + 256];
      b0 = bh4[tid]; b1 = bh4[tid + 256];
      b2 = bl4[tid]; b3 = bl4[tid + 256];
    }
    bf16x8 ahf[4], alf[4];
#pragma unroll
    for (int fm = 0; fm < 4; ++fm) {
      int off = (kcl * 128 + wm + fm * 16 + l15) * 8;
      ahf[fm] = *(const bf16x8*)&sA[off];
      alf[fm] = *(const bf16x8*)&sA[4096 + off];
    }
#pragma unroll
    for (int fn = 0; fn < 4; ++fn) {
      int boff = (kcl * 128 + wn + fn * 16 + l15) * 8;
      bf16x8 bh = *(const bf16x8*)&sB[boff];
      bf16x8 bl = *(const bf16x8*)&sB[4096 + boff];
#pragma unroll
      for (int fm = 0; fm < 4; ++fm) {
        acc[fm][fn] = __builtin_amdgcn_mfma_f32_16x16x32_bf16(ahf[fm], bh, acc[fm][fn], 0, 0, 0);
        acc[fm][fn] = __builtin_amdgcn_mfma_f32_16x16x32_bf16(alf[fm], bh, acc[fm][fn], 0, 0, 0);
        acc[fm][fn] = __builtin_amdgcn_mfma_f32_16x16x32_bf16(ahf[fm], bl, acc[fm][fn], 0, 0, 0);
      }
    }
  }

  // epilogue: alias hist into sA (dead after K-loop). hh[0..2047]=hist,
  // hh[2048]=block count, hh[2049]=global base.
  int* hh = (int*)sA;
  const int l4r = lane >> 4;
  unsigned thrBits = (unsigned)ctrl[1];
  __syncthreads();                         // all sA fragment reads done
  for (int i = tid; i < 2050; i += 256) hh[i] = 0;
  __syncthreads();
  int cnt = 0;
#pragma unroll
  for (int fn = 0; fn < 4; ++fn) {
    int col = col0 + wn + fn * 16 + l15;
    float g = g32[col], be = benc[col];
#pragma unroll
    for (int fm = 0; fm < 4; ++fm) {
#pragma unroll
      for (int r = 0; r < 4; ++r) {
        float z = acc[fm][fn][r] + be;
        float s = z > 0.f ? z * g : 0.f;
        unsigned bits = __float_as_uint(s);
        if (bits >= thrBits) { cnt++; atomicAdd(&hh[bits >> 21], 1); }
      }
    }
  }
  int my = 0;
  if (cnt) my = atomicAdd(&hh[2048], cnt);
  __syncthreads();
  if (tid == 0) hh[2049] = atomicAdd(&ctrl[2], hh[2048]);
  for (int i = tid; i < 2048; i += 256)
    if (hh[i]) atomicAdd(&ghist[i], hh[i]);
  __syncthreads();
  int pos = hh[2049] + my;
#pragma unroll
  for (int fn = 0; fn < 4; ++fn) {
    int col = col0 + wn + fn * 16 + l15;
    float g = g32[col], be = benc[col];
#pragma unroll
    for (int fm = 0; fm < 4; ++fm) {
      int rowb = row0 + wm + fm * 16 + l4r * 4;
#pragma unroll
      for (int r = 0; r < 4; ++r) {
        float z = acc[fm][fn][r] + be;
        float s = z > 0.f ? z * g : 0.f;
        if (__float_as_uint(s) >= thrBits) {
          if (pos < CAND_CAP) { cand_idx[pos] = (rowb + r) * D_SAE + col; cand_sc[pos] = s; }
          pos++;
        }
      }
    }
  }
}

// ---------- fallback 128^2 GEMM (small ws): MODE 0 = hist (1/16), MODE 1 = extract ----------
template <int MODE>
__global__ __launch_bounds__(256) void mfma_gemm(
    const float* __restrict__ Wenc,
    const short* __restrict__ Ahi, const short* __restrict__ Alo,
    const float* __restrict__ benc, const float* __restrict__ g32,
    int* __restrict__ ghist, int* __restrict__ ctrl,
    int* __restrict__ cand_idx, float* __restrict__ cand_sc) {
  __shared__ short sA[8192];
  __shared__ short sB[8192];
  __shared__ int h[(MODE == 0) ? 2048 : 2];
  const int tid = threadIdx.x;
  const int lane = tid & 63;
  const int w = tid >> 6;
  const int wm = (w >> 1) * 64, wn = (w & 1) * 64;
  int lin = blockIdx.x;
  int mt, nt;
  if (MODE == 0) { mt = lin >> 7; nt = lin & 127; }
  else { int xcd = lin & 7, j = lin >> 3; mt = j & 31; nt = (xcd << 4) | (j >> 5); }
  const int row0 = mt * 128, col0 = nt * 128;
  if (MODE == 0) { for (int i = tid; i < 2048; i += 256) h[i] = 0; }
  else if (tid == 0) h[0] = 0;
  const int nl = tid & 127;
  const int half = tid >> 7;
  const float* wbase = Wenc + (size_t)col0 + nl;
  const size_t atile = (size_t)mt * 131072;
  f32x4 acc[4][4] = {};
  const int kcl = lane >> 4, l15 = lane & 15;
  float4 a0, a1, a2, a3;
  float bfv[16];
  {
    const float4* ah4 = (const float4*)(Ahi + atile);
    const float4* al4 = (const float4*)(Alo + atile);
    a0 = ah4[tid]; a1 = ah4[tid + 256];
    a2 = al4[tid]; a3 = al4[tid + 256];
#pragma unroll
    for (int p = 0; p < 4; ++p)
#pragma unroll
      for (int i = 0; i < 4; ++i)
        bfv[p * 4 + i] = wbase[(size_t)(p * 8 + half * 4 + i) * D_SAE];
  }
  for (int ks = 0; ks < 32; ++ks) {
    short hb[16], lb[16];
#pragma unroll
    for (int q = 0; q < 16; ++q) {
      unsigned short hh = f2bf(bfv[q]);
      hb[q] = (short)hh;
      lb[q] = (short)f2bf(bfv[q] - bf2f(hh));
    }
    __syncthreads();
    *(float4*)&sA[(size_t)tid * 8] = a0;
    *(float4*)&sA[(size_t)(tid + 256) * 8] = a1;
    *(float4*)&sA[(size_t)(512 + tid) * 8] = a2;
    *(float4*)&sA[(size_t)(512 + tid + 256) * 8] = a3;
#pragma unroll
    for (int p = 0; p < 4; ++p) {
      int boff = p * 1024 + nl * 8 + half * 4;
      *(short4*)&sB[boff] = make_short4(hb[p * 4], hb[p * 4 + 1], hb[p * 4 + 2], hb[p * 4 + 3]);
      *(short4*)&sB[4096 + boff] = make_short4(lb[p * 4], lb[p * 4 + 1], lb[p * 4 + 2], lb[p * 4 + 3]);
    }
    __syncthreads();
    if (ks < 31) {
      const float4* ah4 = (const float4*)(Ahi + atile + (ks + 1) * 4096);
      const float4* al4 = (const float4*)(Alo + atile + (ks + 1) * 4096);
      a0 = ah4[tid]; a1 = ah4[tid + 256];
      a2 = al4[tid]; a3 = al4[tid + 256];
      const int k0n = (ks + 1) * 32;
#pragma unroll
      for (int p = 0; p < 4; ++p)
#pragma unroll
        for (int i = 0; i < 4; ++i)
          bfv[p * 4 + i] = wbase[(size_t)(k0n + p * 8 + half * 4 + i) * D_SAE];
    }
    bf16x8 ahf[4], alf[4];
#pragma unroll
    for (int fm = 0; fm < 4; ++fm) {
      int off = (kcl * 128 + wm + fm * 16 + l15) * 8;
      ahf[fm] = *(const bf16x8*)&sA[off];
      alf[fm] = *(const bf16x8*)&sA[4096 + off];
    }
#pragma unroll
    for (int fn = 0; fn < 4; ++fn) {
      int boff = (kcl * 128 + wn + fn * 16 + l15) * 8;
      bf16x8 bh = *(const bf16x8*)&sB[boff];
      bf16x8 bl = *(const bf16x8*)&sB[4096 + boff];
#pragma unroll
      for (int fm = 0; fm < 4; ++fm) {
        acc[fm][fn] = __builtin_amdgcn_mfma_f32_16x16x32_bf16(ahf[fm], bh, acc[fm][fn], 0, 0, 0);
        acc[fm][fn] = __builtin_amdgcn_mfma_f32_16x16x32_bf16(alf[fm], bh, acc[fm][fn], 0, 0, 0);
        acc[fm][fn] = __builtin_amdgcn_mfma_f32_16x16x32_bf16(ahf[fm], bl, acc[fm][fn], 0, 0, 0);
      }
    }
  }
  const int l4r = lane >> 4;
  if (MODE == 0) {
#pragma unroll
    for (int fn = 0; fn < 4; ++fn) {
      int col = col0 + wn + fn * 16 + l15;
      float g = g32[col], be = benc[col];
#pragma unroll
      for (int fm = 0; fm < 4; ++fm) {
#pragma unroll
        for (int r = 0; r < 4; ++r) {
          float z = acc[fm][fn][r] + be;
          float s = z > 0.f ? z * g : 0.f;
          unsigned bits = __float_as_uint(s);
          if (bits) atomicAdd(&h[bits >> 21], 1);
        }
      }
    }
    __syncthreads();
    for (int i = tid; i < 2048; i += 256)
      if (h[i]) atomicAdd(&ghist[i], h[i]);
  } else {
    unsigned thrBits = (unsigned)ctrl[1];
    int cnt = 0;
#pragma unroll
    for (int fn = 0; fn < 4; ++fn) {
      int col = col0 + wn + fn * 16 + l15;
      float g = g32[col], be = benc[col];
#pragma unroll
      for (int fm = 0; fm < 4; ++fm) {
#pragma unroll
        for (int r = 0; r < 4; ++r) {
          float z = acc[fm][fn][r] + be;
          float s = z > 0.f ? z * g : 0.f;
          cnt += (__float_as_uint(s) >= thrBits) ? 1 : 0;
        }
      }
    }
    int my = 0;
    if (cnt) my = atomicAdd(&h[0], cnt);
    __syncthreads();
    if (tid == 0) h[1] = atomicAdd(&ctrl[2], h[0]);
    __syncthreads();
    int pos = h[1] + my;
#pragma unroll
    for (int fn = 0; fn < 4; ++fn) {
      int col = col0 + wn + fn * 16 + l15;
      float g = g32[col], be = benc[col];
#pragma unroll
      for (int fm = 0; fm < 4; ++fm) {
        int rowb = row0 + wm + fm * 16 + l4r * 4;
#pragma unroll
        for (int r = 0; r < 4; ++r) {
          float z = acc[fm][fn][r] + be;
          float s = z > 0.f ? z * g : 0.f;
          if (__float_as_uint(s) >= thrBits) {
            if (pos < CAND_CAP) { cand_idx[pos] = (rowb + r) * D_SAE + col; cand_sc[pos] = s; }
            pos++;
          }
        }
      }
    }
  }
}

// ---------- coarse threshold (64-thread parallel scan) ----------
__global__ void find_coarse_kernel(const int* __restrict__ gh, int* ctrl,
                                   const int* __restrict__ kptr, int sub) {
  long long kB = (long long)kptr[0] * BATCH;
  long long needl = (kB + 500000 + sub - 1) / sub;
  long long fl = 720000 / sub;
  if (needl < fl) needl = fl;
  int b, cum;
  hist_scan_desc(gh, 2048, (int)needl, b, cum);
  if (threadIdx.x == 0) {
    long long est_incl = (long long)sub * (cum + gh[b]);
    if (est_incl > 3500000LL && (long long)sub * cum >= kB + 120000LL) b = b + 1;
    ctrl[1] = (int)(((unsigned)b) << 21);
  }
}

// ---------- radix histograms over candidate scores (passes 1,2) ----------
__global__ __launch_bounds__(256) void chist_kernel(const float* __restrict__ cand_sc,
                                                    const int* __restrict__ ctrl,
                                                    int* __restrict__ ghist, int pass) {
  __shared__ int h[2048];
  int nb = (pass == 2) ? 1024 : 2048;
  for (int i = threadIdx.x; i < nb; i += 256) h[i] = 0;
  __syncthreads();
  int n = ctrl[2]; if (n > CAND_CAP) n = CAND_CAP;
  unsigned sel1 = 0, sel22 = 0;
  if (pass == 1) sel1 = (unsigned)ctrl[3];
  if (pass == 2) sel22 = ((unsigned)ctrl[3] << 11) | (unsigned)ctrl[5];
  for (int i = blockIdx.x * 256 + threadIdx.x; i < n; i += gridDim.x * 256) {
    unsigned bits = __float_as_uint(cand_sc[i]);
    if (pass == 0) atomicAdd(&h[bits >> 21], 1);
    else if (pass == 1) { if ((bits >> 21) == sel1) atomicAdd(&h[(bits >> 10) & 0x7FFu], 1); }
    else { if ((bits >> 10) == sel22) atomicAdd(&h[bits & 0x3FFu], 1); }
  }
  __syncthreads();
  for (int i = threadIdx.x; i < nb; i += 256)
    if (h[i]) atomicAdd(&ghist[i], h[i]);
}

// ---------- radix select step (64-thread parallel scan) ----------
__global__ void cfind_kernel(const int* __restrict__ hist, int* ctrl,
                             const int* __restrict__ kptr, int pass) {
  int kB = kptr[0] * BATCH;
  int need, nbins;
  if (pass == 0)      { need = kB;                       nbins = 2048; }
  else if (pass == 1) { need = kB - ctrl[4];             nbins = 2048; }
  else                { need = kB - ctrl[4] - ctrl[6];   nbins = 1024; }
  int b, cum;
  hist_scan_desc(hist, nbins, need, b, cum);
  if (threadIdx.x == 0) {
    if (pass == 0)      { ctrl[3] = b; ctrl[4] = cum; }
    else if (pass == 1) { ctrl[5] = b; ctrl[6] = cum; }
    else {
      unsigned vbits = ((unsigned)ctrl[3] << 21) | ((unsigned)ctrl[5] << 10) | (unsigned)b;
      float V = __uint_as_float(vbits);
      float* cf = (float*)ctrl;
      cf[8] = V; cf[9] = V + EPS_M; cf[10] = V - EPS_M;
    }
  }
}

// ---------- band partition ----------
__global__ __launch_bounds__(256) void band_kernel(const int* __restrict__ cand_idx,
    const float* __restrict__ cand_sc, const float* __restrict__ g32,
    int* ctrl, int* row_cnt, int* row_feat, float* row_act, int* cand2_idx) {
  const float* cf = (const float*)ctrl;
  float hi = cf[9], lo = cf[10];
  int n = ctrl[2]; if (n > CAND_CAP) n = CAND_CAP;
  int lane = threadIdx.x & 63;
  int defc = 0;
  for (int i = blockIdx.x * 256 + threadIdx.x; i < n; i += gridDim.x * 256) {
    float s = cand_sc[i];
    int flat = cand_idx[i];
    if (s > hi) {
      int b = flat >> 14, j = flat & (D_SAE - 1);
      int p = atomicAdd(&row_cnt[b], 1);
      if (p < ROW_CAP) { row_feat[b * ROW_CAP + p] = j; row_act[b * ROW_CAP + p] = s / g32[j]; }
      defc++;
    }
    bool isc = (s <= hi) && (s >= lo);
    int pos = wave_append(isc, &ctrl[12]);
    if (isc && pos >= 0 && pos < CAND2_CAP) cand2_idx[pos] = flat;
  }
#pragma unroll
  for (int off = 32; off > 0; off >>= 1) defc += __shfl_down(defc, off, 64);
  if (lane == 0 && defc) atomicAdd(&ctrl[11], defc);
}

// ---------- fp64 rescore of band candidates ----------
__global__ __launch_bounds__(256) void cand2_score_kernel(const int* __restrict__ ctrl,
    const int* __restrict__ cand2_idx, const float* __restrict__ x,
    const float* __restrict__ Wdec, const float* __restrict__ benc,
    const double* __restrict__ g64, double* __restrict__ cand2_sc) {
  __shared__ double lds[4];
  int n2 = ctrl[12]; if (n2 > CAND2_CAP) n2 = CAND2_CAP;
  int t = threadIdx.x;
  for (int c = blockIdx.x; c < n2; c += gridDim.x) {
    int flat = cand2_idx[c];
    int b = flat >> 14, j = flat & (D_SAE - 1);
    double d[4];
    ln_row_fp64(x + (size_t)b * (2 * D_MODEL), lds, d);
    float4 w4 = *(const float4*)(Wdec + (size_t)j * D_MODEL + t * 4);
    double a = d[0] * (double)w4.x + d[1] * (double)w4.y + d[2] * (double)w4.z + d[3] * (double)w4.w;
    double z = blockReduceSum256(a, lds) + (double)benc[j];
    double sc = z > 0 ? z * g64[j] : 0.0;
    if (t == 0) cand2_sc[c] = sc;
  }
}

// ---------- rank band candidates (fp64, index-stable), accept fill ----------
__global__ __launch_bounds__(256) void cand2_rank_kernel(const int* __restrict__ ctrl,
    const int* __restrict__ cand2_idx, const double* __restrict__ cand2_sc,
    const double* __restrict__ g64, const int* __restrict__ kptr,
    int* row_cnt, int* row_feat, float* row_act) {
  __shared__ int lds[4];
  int n2 = ctrl[12]; if (n2 > CAND2_CAP) n2 = CAND2_CAP;
  int kB = kptr[0] * BATCH;
  int fill = kB - ctrl[11];
  int t = threadIdx.x;
  for (int c = blockIdx.x; c < n2; c += gridDim.x) {
    double sc = cand2_sc[c];
    int fc = cand2_idx[c];
    int cnt = 0;
    for (int y = t; y < n2; y += 256) {
      double sy = cand2_sc[y];
      if (sy > sc || (sy == sc && cand2_idx[y] < fc)) cnt++;
    }
    cnt = blockReduceSumInt256(cnt, lds);
    if (t == 0 && cnt < fill) {
      int b = fc >> 14, j = fc & (D_SAE - 1);
      int p = atomicAdd(&row_cnt[b], 1);
      if (p < ROW_CAP) { row_feat[b * ROW_CAP + p] = j; row_act[b * ROW_CAP + p] = (float)(sc / g64[j]); }
    }
  }
}

// ---------- sparse recon (float4, 2-way ILP) ----------
__global__ __launch_bounds__(256) void recon_kernel(const int* __restrict__ row_cnt,
    const int* __restrict__ row_feat, const float* __restrict__ row_act,
    const float* __restrict__ Wdec, const float* __restrict__ bdec, float* __restrict__ out) {
  int b = blockIdx.x, t = threadIdx.x;
  float4 acc0 = *(const float4*)&bdec[t * 4];
  float4 acc1 = make_float4(0.f, 0.f, 0.f, 0.f);
  int n = row_cnt[b]; if (n > ROW_CAP) n = ROW_CAP;
  const int* rf = row_feat + (size_t)b * ROW_CAP;
  const float* ra = row_act + (size_t)b * ROW_CAP;
  int p = 0;
  for (; p + 2 <= n; p += 2) {
    int j0 = rf[p], j1 = rf[p + 1];
    float v0 = ra[p], v1 = ra[p + 1];
    float4 w0 = *(const float4*)(Wdec + (size_t)j0 * D_MODEL + t * 4);
    float4 w1 = *(const float4*)(Wdec + (size_t)j1 * D_MODEL + t * 4);
    acc0.x += v0 * w0.x; acc0.y += v0 * w0.y; acc0.z += v0 * w0.z; acc0.w += v0 * w0.w;
    acc1.x += v1 * w1.x; acc1.y += v1 * w1.y; acc1.z += v1 * w1.z; acc1.w += v1 * w1.w;
  }
  if (p < n) {
    int j0 = rf[p]; float v0 = ra[p];
    float4 w0 = *(const float4*)(Wdec + (size_t)j0 * D_MODEL + t * 4);
    acc0.x += v0 * w0.x; acc0.y += v0 * w0.y; acc0.z += v0 * w0.z; acc0.w += v0 * w0.w;
  }
  acc0.x += acc1.x; acc0.y += acc1.y; acc0.z += acc1.z; acc0.w += acc1.w;
  *(float4*)(out + (size_t)b * D_MODEL + t * 4) = acc0;
}

extern "C" void kernel_launch(void* const* d_in, const int* in_sizes, int n_in,
                              void* d_out, int out_size, void* d_ws, size_t ws_size,
                              hipStream_t stream) {
  const float* x    = (const float*)d_in[0];
  const float* Wenc = (const float*)d_in[1];
  const float* benc = (const float*)d_in[2];
  const float* Wdec = (const float*)d_in[3];
  const float* bdec = (const float*)d_in[4];
  const int*   kptr = (const int*)d_in[5];
  float* out = (float*)d_out;

  char* ws = (char*)d_ws;
  size_t off = 0;
  short*  Ahi       = (short*)(ws + off);  off += (size_t)BATCH * D_MODEL * 2;
  short*  Alo       = (short*)(ws + off);  off += (size_t)BATCH * D_MODEL * 2;
  int*    cand_idx  = (int*)(ws + off);    off += (size_t)CAND_CAP * 4;
  float*  cand_sc   = (float*)(ws + off);  off += (size_t)CAND_CAP * 4;
  int*    row_feat  = (int*)(ws + off);    off += (size_t)BATCH * ROW_CAP * 4;
  float*  row_act   = (float*)(ws + off);  off += (size_t)BATCH * ROW_CAP * 4;
  int*    cand2_idx = (int*)(ws + off);    off += (size_t)CAND2_CAP * 4;
  double* cand2_sc  = (double*)(ws + off); off += (size_t)CAND2_CAP * 8;
  double* g64       = (double*)(ws + off); off += (size_t)D_SAE * 8;
  float*  g32       = (float*)(ws + off);  off += (size_t)D_SAE * 4;
  char*   zbase     = ws + off;
  int* ghist   = (int*)(zbase);
  int* h1      = (int*)(zbase + 8192);
  int* h2      = (int*)(zbase + 16384);
  int* h3      = (int*)(zbase + 24576);
  int* ctrl    = (int*)(zbase + 28672);
  int* row_cnt = (int*)(zbase + 28928);
  size_t zbytes = 28928 + (size_t)BATCH * 4;
  size_t small_need = off + zbytes;
  if (small_need > ws_size) return;  // ~60 MB floor

  size_t big_off = (small_need + 255) & ~(size_t)255;
  short* Whi = (short*)(ws + big_off);
  short* Wlo = Whi + (size_t)D_MODEL * D_SAE;
  size_t big_need = big_off + (size_t)D_MODEL * D_SAE * 4;
  const bool big = (big_need <= ws_size);   // round-6/8/9-proven to fit

  hipMemsetAsync(zbase, 0, zbytes, stream);

  ln_kernel<<<BATCH, 256, 0, stream>>>(x, Ahi, Alo);
  norm_kernel<<<D_SAE / 4, 256, 0, stream>>>(Wdec, g64, g32);
  if (big) {
    wsplit_kernel<<<4096, 256, 0, stream>>>(Wenc, Whi, Wlo);
    hist_gemm<<<512, 256, 0, stream>>>(Whi, Ahi, benc, g32, ghist);
    find_coarse_kernel<<<1, 64, 0, stream>>>(ghist, ctrl, kptr, 8);
    extract_gemm128<<<4096, 256, 0, stream>>>(Whi, Wlo, Ahi, Alo, benc, g32, ctrl, cand_idx, cand_sc, h1);
  } else {
    mfma_gemm<0><<<256, 256, 0, stream>>>(Wenc, Ahi, Alo, benc, g32, ghist, ctrl, nullptr, nullptr);
    find_coarse_kernel<<<1, 64, 0, stream>>>(ghist, ctrl, kptr, 16);
    mfma_gemm<1><<<4096, 256, 0, stream>>>(Wenc, Ahi, Alo, benc, g32, nullptr, ctrl, cand_idx, cand_sc);
    chist_kernel<<<1024, 256, 0, stream>>>(cand_sc, ctrl, h1, 0);
  }
  cfind_kernel<<<1, 64, 0, stream>>>(h1, ctrl, kptr, 0);
  chist_kernel<<<1024, 256, 0, stream>>>(cand_sc, ctrl, h2, 1);
  cfind_kernel<<<1, 64, 0, stream>>>(h2, ctrl, kptr, 1);
  chist_kernel<<<1024, 256, 0, stream>>>(cand_sc, ctrl, h3, 2);
  cfind_kernel<<<1, 64, 0, stream>>>(h3, ctrl, kptr, 2);
  band_kernel<<<1024, 256, 0, stream>>>(cand_idx, cand_sc, g32, ctrl, row_cnt, row_feat, row_act, cand2_idx);
  cand2_score_kernel<<<4096, 256, 0, stream>>>(ctrl, cand2_idx, x, Wdec, benc, g64, cand2_sc);
  cand2_rank_kernel<<<2048, 256, 0, stream>>>(ctrl, cand2_idx, cand2_sc, g64, kptr, row_cnt, row_feat, row_act);
  recon_kernel<<<BATCH, 256, 0, stream>>>(row_cnt, row_feat, row_act, Wdec, bdec, out);
}

// Round 16
// 733.737 us; speedup vs baseline: 1.1505x; 1.0394x over previous
//
#include <hip/hip_runtime.h>
#include <math.h>

#define D_MODEL 1024
#define D_SAE   16384
#define BATCH   4096
#define NTOT    (1ull * BATCH * D_SAE)
#define LN_EPS  1e-8
#define EPS_M   3e-4f        // |split-bf16 score - fp64 score| safe band half-width (>=6x margin)
#define ROW_CAP 256
#define CAND_CAP  (4 * 1024 * 1024)
#define CAND2_CAP 65536

using bf16x8 = __attribute__((ext_vector_type(8))) short;
using f32x4  = __attribute__((ext_vector_type(4))) float;

__device__ inline unsigned short f2bf(float f) {   // RNE fp32->bf16
  unsigned u = __float_as_uint(f);
  return (unsigned short)((u + 0x7fffu + ((u >> 16) & 1u)) >> 16);
}
__device__ inline float bf2f(unsigned short h) {
  return __uint_as_float((unsigned)h << 16);
}

// ---------- block (256-thread) reductions ----------
__device__ inline double blockReduceSum256(double v, double* lds) {
#pragma unroll
  for (int off = 32; off > 0; off >>= 1) v += __shfl_down(v, off, 64);
  int lane = threadIdx.x & 63, wid = threadIdx.x >> 6;
  __syncthreads();
  if (lane == 0) lds[wid] = v;
  __syncthreads();
  return lds[0] + lds[1] + lds[2] + lds[3];
}
__device__ inline int blockReduceSumInt256(int v, int* lds) {
#pragma unroll
  for (int off = 32; off > 0; off >>= 1) v += __shfl_down(v, off, 64);
  int lane = threadIdx.x & 63, wid = threadIdx.x >> 6;
  __syncthreads();
  if (lane == 0) lds[wid] = v;
  __syncthreads();
  return lds[0] + lds[1] + lds[2] + lds[3];
}

__device__ inline int wave_append(bool pred, int* counter) {
  unsigned long long m = __ballot(pred);
  int lane = threadIdx.x & 63;
  int pos = -1;
  if (m) {
    int ldr = __ffsll((long long)m) - 1;
    int base = 0;
    if (lane == ldr) base = atomicAdd(counter, __popcll(m));
    base = __shfl(base, ldr, 64);
    if (pred) pos = base + __popcll(m & ((1ull << lane) - 1ull));
  }
  return pos;
}

// ---------- 64-lane parallel descending histogram scan ----------
__device__ inline void hist_scan_desc(const int* __restrict__ hist, int nbins, int need,
                                      int& bsel, int& cumsel) {
  int t = threadIdx.x;          // 0..63
  int chunk = nbins >> 6;
  int topbase = nbins - t * chunk;
  int psum = 0;
  for (int i = 1; i <= chunk; ++i) psum += hist[topbase - i];
  int incl = psum;
#pragma unroll
  for (int off = 1; off < 64; off <<= 1) {
    int v = __shfl_up(incl, off, 64);
    if (t >= off) incl += v;
  }
  int excl = incl - psum;
  bool hit = (excl < need) && (excl + psum >= need);
  unsigned long long m = __ballot(hit);
  int tb = m ? (__ffsll((long long)m) - 1) : 63;
  int exb = __shfl(excl, tb, 64);
  int res_b = 0, res_c = 0;
  if (t == tb) {
    int c = exb;
    int b = nbins - tb * chunk - 1;
    int bend = b - chunk;
    for (; b > 0 && b > bend; --b) {
      int cc = hist[b];
      if (c + cc >= need) break;
      c += cc;
    }
    res_b = b; res_c = c;
  }
  bsel = __shfl(res_b, tb, 64);
  cumsel = __shfl(res_c, tb, 64);
}

// ---------- per-thread fp64 LN chain (256-thr block version, used by cand2) ----------
__device__ inline void ln_row_fp64(const float* __restrict__ row, double* lds, double d[4]) {
  int t = threadIdx.x;
  float4 s4 = *(const float4*)(row + t * 4);
  float4 t4 = *(const float4*)(row + D_MODEL + t * 4);
  double s[4] = {s4.x, s4.y, s4.z, s4.w};
  double tt[4] = {t4.x, t4.y, t4.z, t4.w};
  double ms = blockReduceSum256(s[0] + s[1] + s[2] + s[3], lds) / D_MODEL;
  double mt = blockReduceSum256(tt[0] + tt[1] + tt[2] + tt[3], lds) / D_MODEL;
  double vs = 0, vt = 0;
#pragma unroll
  for (int i = 0; i < 4; i++) { double a = s[i] - ms; vs += a * a; a = tt[i] - mt; vt += a * a; }
  vs = blockReduceSum256(vs, lds) / D_MODEL;
  vt = blockReduceSum256(vt, lds) / D_MODEL;
  double rs = sqrt(vs + LN_EPS), rt = sqrt(vt + LN_EPS);
  double u[4];
#pragma unroll
  for (int i = 0; i < 4; i++) u[i] = (tt[i] - mt) / rt - (s[i] - ms) / rs;
  double mu = blockReduceSum256(u[0] + u[1] + u[2] + u[3], lds) / D_MODEL;
  double vu = 0;
#pragma unroll
  for (int i = 0; i < 4; i++) { double a = u[i] - mu; vu += a * a; }
  vu = blockReduceSum256(vu, lds) / D_MODEL;
  double ru = sqrt(vu + LN_EPS);
#pragma unroll
  for (int i = 0; i < 4; i++) d[i] = (u[i] - mu) / ru;
}

// ---------- LN -> split-bf16 A, wave-per-row (no barriers), tiled layout ----------
__global__ __launch_bounds__(256) void ln_kernel(const float* __restrict__ x,
                                                 short* __restrict__ Ahi, short* __restrict__ Alo) {
  int wv = threadIdx.x >> 6, lane = threadIdx.x & 63;
  int b = (blockIdx.x << 2) | wv;
  const float* row = x + (size_t)b * (2 * D_MODEL);
  // lane owns elements [lane*16, lane*16+16)
  float s[16], t[16];
  const float4* s4p = (const float4*)(row + lane * 16);
  const float4* t4p = (const float4*)(row + D_MODEL + lane * 16);
  double sum_s = 0, sum_t = 0;
#pragma unroll
  for (int q = 0; q < 4; ++q) {
    float4 a = s4p[q], c = t4p[q];
    s[q * 4 + 0] = a.x; s[q * 4 + 1] = a.y; s[q * 4 + 2] = a.z; s[q * 4 + 3] = a.w;
    t[q * 4 + 0] = c.x; t[q * 4 + 1] = c.y; t[q * 4 + 2] = c.z; t[q * 4 + 3] = c.w;
  }
#pragma unroll
  for (int i = 0; i < 16; ++i) { sum_s += s[i]; sum_t += t[i]; }
#pragma unroll
  for (int off = 1; off < 64; off <<= 1) {
    sum_s += __shfl_xor(sum_s, off, 64);
    sum_t += __shfl_xor(sum_t, off, 64);
  }
  double ms = sum_s / D_MODEL, mt_ = sum_t / D_MODEL;
  double vs = 0, vt = 0;
#pragma unroll
  for (int i = 0; i < 16; ++i) {
    double a = s[i] - ms; vs += a * a;
    double c = t[i] - mt_; vt += c * c;
  }
#pragma unroll
  for (int off = 1; off < 64; off <<= 1) {
    vs += __shfl_xor(vs, off, 64);
    vt += __shfl_xor(vt, off, 64);
  }
  double rs = sqrt(vs / D_MODEL + LN_EPS), rt = sqrt(vt / D_MODEL + LN_EPS);
  double u[16], su = 0;
#pragma unroll
  for (int i = 0; i < 16; ++i) { u[i] = (t[i] - mt_) / rt - (s[i] - ms) / rs; su += u[i]; }
#pragma unroll
  for (int off = 1; off < 64; off <<= 1) su += __shfl_xor(su, off, 64);
  double mu = su / D_MODEL, vu = 0;
#pragma unroll
  for (int i = 0; i < 16; ++i) { double a = u[i] - mu; vu += a * a; }
#pragma unroll
  for (int off = 1; off < 64; off <<= 1) vu += __shfl_xor(vu, off, 64);
  double ru = sqrt(vu / D_MODEL + LN_EPS);
  int mtb = b >> 7, ml = b & 127;
#pragma unroll
  for (int blk8 = 0; blk8 < 2; ++blk8) {
    short h8[8], l8[8];
#pragma unroll
    for (int e = 0; e < 8; ++e) {
      int i = blk8 * 8 + e;
      double dd = (u[i] - mu) / ru;
      float f = (float)dd;
      unsigned short hh = f2bf(f);
      h8[e] = (short)hh;
      l8[e] = (short)f2bf(f - bf2f(hh));
    }
    int gi = lane * 16 + blk8 * 8;     // first element index (multiple of 8)
    int ks = gi >> 5, kc = (gi >> 3) & 3;
    size_t base = ((((size_t)mtb * 32 + ks) * 4 + kc) * 128 + ml) * 8;
    *(float4*)&Ahi[base] = *(float4*)h8;
    *(float4*)&Alo[base] = *(float4*)l8;
  }
}

// ---------- dec_norms in fp64 (wave-per-feature, no block syncs) ----------
__global__ __launch_bounds__(256) void norm_kernel(const float* __restrict__ Wdec,
                                                   double* __restrict__ g64, float* __restrict__ g32) {
  int wv = threadIdx.x >> 6, lane = threadIdx.x & 63;
  int j = (blockIdx.x << 2) | wv;
  const float4* rowp = (const float4*)(Wdec + (size_t)j * D_MODEL);
  double a = 0;
#pragma unroll
  for (int q = 0; q < 4; ++q) {
    float4 w = rowp[lane + q * 64];
    a += (double)w.x * w.x + (double)w.y * w.y + (double)w.z * w.z + (double)w.w * w.w;
  }
#pragma unroll
  for (int off = 32; off > 0; off >>= 1) a += __shfl_down(a, off, 64);
  if (lane == 0) { double g = sqrt(a); g64[j] = g; g32[j] = (float)g; }
}

// ---------- pre-split W_enc fp32 -> tiled bf16 hi/lo [nt][ks][kc][c][e] ----------
__global__ __launch_bounds__(256) void wsplit_kernel(const float* __restrict__ Wenc,
                                                     short* __restrict__ Whi, short* __restrict__ Wlo) {
  __shared__ short sh[4096];
  __shared__ short sl[4096];
  int blk = blockIdx.x;            // 4096 = 128 nt * 32 ks
  int nt = blk >> 5, ks = blk & 31;
  int t = threadIdx.x;
  int r = t >> 3;
  int cg = t & 7;
  int kc = r >> 3, e = r & 7;
  const float* src = Wenc + (size_t)(ks * 32 + r) * D_SAE + nt * 128 + cg;
#pragma unroll
  for (int j = 0; j < 16; ++j) {
    float f = src[j * 8];
    unsigned short hh = f2bf(f);
    short ll = (short)f2bf(f - bf2f(hh));
    int c = j * 8 + cg;
    sh[kc * 1024 + c * 8 + e] = (short)hh;
    sl[kc * 1024 + c * 8 + e] = ll;
  }
  __syncthreads();
  size_t obase = ((size_t)nt * 32 + ks) * 4096;
  *(float4*)&Whi[obase + t * 16]     = *(const float4*)&sh[t * 16];
  *(float4*)&Whi[obase + t * 16 + 8] = *(const float4*)&sh[t * 16 + 8];
  *(float4*)&Wlo[obase + t * 16]     = *(const float4*)&sl[t * 16];
  *(float4*)&Wlo[obase + t * 16 + 8] = *(const float4*)&sl[t * 16 + 8];
}

// ---------- hi-only 1/16-subsampled hist GEMM: per-wave privatized hist ----------
__global__ __launch_bounds__(256) void hist_gemm(
    const short* __restrict__ Whi, const short* __restrict__ Ahi,
    const float* __restrict__ benc, const float* __restrict__ g32,
    int* __restrict__ ghist) {
  __shared__ short sA[4096];
  __shared__ short sB[4096];
  __shared__ int h[4][2048];
  const int tid = threadIdx.x;
  const int lane = tid & 63;
  const int w = tid >> 6;
  const int wm = (w >> 1) * 64, wn = (w & 1) * 64;
  int lin = blockIdx.x;            // 256 = 2 mt * 128 nt
  int mt = lin >> 7, nt = lin & 127;
  const int col0 = nt * 128;
  for (int i = tid; i < 8192; i += 256) ((int*)h)[i] = 0;
  const size_t atile = (size_t)mt * 131072;
  const size_t btile = (size_t)nt * 131072;
  f32x4 acc[4][4] = {};
  const int kcl = lane >> 4, l15 = lane & 15;

  float4 a0, a1, b0, b1;
  {
    const float4* ah4 = (const float4*)(Ahi + atile);
    const float4* bh4 = (const float4*)(Whi + btile);
    a0 = ah4[tid]; a1 = ah4[tid + 256];
    b0 = bh4[tid]; b1 = bh4[tid + 256];
  }
  for (int ks = 0; ks < 32; ++ks) {
    __syncthreads();
    *(float4*)&sA[(size_t)tid * 8] = a0;
    *(float4*)&sA[(size_t)(tid + 256) * 8] = a1;
    *(float4*)&sB[(size_t)tid * 8] = b0;
    *(float4*)&sB[(size_t)(tid + 256) * 8] = b1;
    __syncthreads();
    if (ks < 31) {
      const float4* ah4 = (const float4*)(Ahi + atile + (ks + 1) * 4096);
      const float4* bh4 = (const float4*)(Whi + btile + (ks + 1) * 4096);
      a0 = ah4[tid]; a1 = ah4[tid + 256];
      b0 = bh4[tid]; b1 = bh4[tid + 256];
    }
    bf16x8 ahf[4];
#pragma unroll
    for (int fm = 0; fm < 4; ++fm)
      ahf[fm] = *(const bf16x8*)&sA[(kcl * 128 + wm + fm * 16 + l15) * 8];
#pragma unroll
    for (int fn = 0; fn < 4; ++fn) {
      bf16x8 bh = *(const bf16x8*)&sB[(kcl * 128 + wn + fn * 16 + l15) * 8];
#pragma unroll
      for (int fm = 0; fm < 4; ++fm)
        acc[fm][fn] = __builtin_amdgcn_mfma_f32_16x16x32_bf16(ahf[fm], bh, acc[fm][fn], 0, 0, 0);
    }
  }
#pragma unroll
  for (int fn = 0; fn < 4; ++fn) {
    int col = col0 + wn + fn * 16 + l15;
    float g = g32[col], be = benc[col];
#pragma unroll
    for (int fm = 0; fm < 4; ++fm) {
#pragma unroll
      for (int r = 0; r < 4; ++r) {
        float z = acc[fm][fn][r] + be;
        float s = z > 0.f ? z * g : 0.f;
        unsigned bits = __float_as_uint(s);
        if (bits) atomicAdd(&h[w][bits >> 21], 1);
      }
    }
  }
  __syncthreads();
  for (int i = tid; i < 2048; i += 256) {
    int v = h[0][i] + h[1][i] + h[2][i] + h[3][i];
    if (v) atomicAdd(&ghist[i], v);
  }
}

// ---------- 128x128 split-bf16 MFMA extract GEMM ----------
// XCD owns 4 mt A-tiles (2MB, L2-resident); streams B panels in nt order.
// Pass-0 histogram aliased into sA; __launch_bounds__(256,3) pins 3 blocks/CU.
__global__ __launch_bounds__(256, 3) void extract_gemm128(
    const short* __restrict__ Whi, const short* __restrict__ Wlo,
    const short* __restrict__ Ahi, const short* __restrict__ Alo,
    const float* __restrict__ benc, const float* __restrict__ g32,
    int* __restrict__ ctrl, int* __restrict__ cand_idx, float* __restrict__ cand_sc,
    int* __restrict__ ghist) {
  __shared__ short sA[8192];   // hi [4][128][8] | lo at +4096 ; reused as hist after K-loop
  __shared__ short sB[8192];

  const int tid = threadIdx.x;
  const int lane = tid & 63;
  const int w = tid >> 6;
  const int wm = (w >> 1) * 64, wn = (w & 1) * 64;

  // A-resident partition: XCD owns mt in [4*xcd, 4*xcd+4); B streams in nt order.
  int lin = blockIdx.x;
  int xcd = lin & 7, j = lin >> 3;
  int mt = (xcd << 2) | (j & 3);
  int nt = j >> 2;
  const int row0 = mt * 128, col0 = nt * 128;

  const size_t atile = (size_t)mt * 131072;
  const size_t btile = (size_t)nt * 131072;

  f32x4 acc[4][4] = {};
  const int kcl = lane >> 4, l15 = lane & 15;

  float4 a0, a1, a2, a3, b0, b1, b2, b3;
  {
    const float4* ah4 = (const float4*)(Ahi + atile);
    const float4* al4 = (const float4*)(Alo + atile);
    const float4* bh4 = (const float4*)(Whi + btile);
    const float4* bl4 = (const float4*)(Wlo + btile);
    a0 = ah4[tid]; a1 = ah4[tid + 256];
    a2 = al4[tid]; a3 = al4[tid + 256];
    b0 = bh4[tid]; b1 = bh4[tid + 256];
    b2 = bl4[tid]; b3 = bl4[tid + 256];
  }

  for (int ks = 0; ks < 32; ++ks) {
    __syncthreads();   // previous tile fully consumed
    *(float4*)&sA[(size_t)tid * 8] = a0;
    *(float4*)&sA[(size_t)(tid + 256) * 8] = a1;
    *(float4*)&sA[(size_t)(512 + tid) * 8] = a2;
    *(float4*)&sA[(size_t)(512 + tid + 256) * 8] = a3;
    *(float4*)&sB[(size_t)tid * 8] = b0;
    *(float4*)&sB[(size_t)(tid + 256) * 8] = b1;
    *(float4*)&sB[(size_t)(512 + tid) * 8] = b2;
    *(float4*)&sB[(size_t)(512 + tid + 256) * 8] = b3;
    __syncthreads();   // tile visible
    if (ks < 31) {
      const int o = (ks + 1) * 4096;
      const float4* ah4 = (const float4*)(Ahi + atile + o);
      const float4* al4 = (const float4*)(Alo + atile + o);
      const float4* bh4 = (const float4*)(Whi + btile + o);
      const float4* bl4 = (const float4*)(Wlo + btile + o);
      a0 = ah4[tid]; a1 = ah4[tid + 256];
      a2 = al4[tid]; a3 = al4[tid + 256];
      b0 = bh4[tid]; b1 = bh4[tid + 256];
      b2 = bl4[tid]; b3 = bl4[tid + 256];
    }
    bf16x8 ahf[4], alf[4];
#pragma unroll
    for (int fm = 0; fm < 4; ++fm) {
      int off = (kcl * 128 + wm + fm * 16 + l15) * 8;
      ahf[fm] = *(const bf16x8*)&sA[off];
      alf[fm] = *(const bf16x8*)&sA[4096 + off];
    }
#pragma unroll
    for (int fn = 0; fn < 4; ++fn) {
      int boff = (kcl * 128 + wn + fn * 16 + l15) * 8;
      bf16x8 bh = *(const bf16x8*)&sB[boff];
      bf16x8 bl = *(const bf16x8*)&sB[4096 + boff];
#pragma unroll
      for (int fm = 0; fm < 4; ++fm) {
        acc[fm][fn] = __builtin_amdgcn_mfma_f32_16x16x32_bf16(ahf[fm], bh, acc[fm][fn], 0, 0, 0);
        acc[fm][fn] = __builtin_amdgcn_mfma_f32_16x16x32_bf16(alf[fm], bh, acc[fm][fn], 0, 0, 0);
        acc[fm][fn] = __builtin_amdgcn_mfma_f32_16x16x32_bf16(ahf[fm], bl, acc[fm][fn], 0, 0, 0);
      }
    }
  }

  // epilogue: alias hist into sA (dead after K-loop). hh[0..2047]=hist,
  // hh[2048]=block count, hh[2049]=global base.
  int* hh = (int*)sA;
  const int l4r = lane >> 4;
  unsigned thrBits = (unsigned)ctrl[1];
  __syncthreads();                         // all sA fragment reads done
  for (int i = tid; i < 2050; i += 256) hh[i] = 0;
  __syncthreads();
  int cnt = 0;
#pragma unroll
  for (int fn = 0; fn < 4; ++fn) {
    int col = col0 + wn + fn * 16 + l15;
    float g = g32[col], be = benc[col];
#pragma unroll
    for (int fm = 0; fm < 4; ++fm) {
#pragma unroll
      for (int r = 0; r < 4; ++r) {
        float z = acc[fm][fn][r] + be;
        float s = z > 0.f ? z * g : 0.f;
        unsigned bits = __float_as_uint(s);
        if (bits >= thrBits) { cnt++; atomicAdd(&hh[bits >> 21], 1); }
      }
    }
  }
  int my = 0;
  if (cnt) my = atomicAdd(&hh[2048], cnt);
  __syncthreads();
  if (tid == 0) hh[2049] = atomicAdd(&ctrl[2], hh[2048]);
  for (int i = tid; i < 2048; i += 256)
    if (hh[i]) atomicAdd(&ghist[i], hh[i]);
  __syncthreads();
  int pos = hh[2049] + my;
#pragma unroll
  for (int fn = 0; fn < 4; ++fn) {
    int col = col0 + wn + fn * 16 + l15;
    float g = g32[col], be = benc[col];
#pragma unroll
    for (int fm = 0; fm < 4; ++fm) {
      int rowb = row0 + wm + fm * 16 + l4r * 4;
#pragma unroll
      for (int r = 0; r < 4; ++r) {
        float z = acc[fm][fn][r] + be;
        float s = z > 0.f ? z * g : 0.f;
        if (__float_as_uint(s) >= thrBits) {
          if (pos < CAND_CAP) { cand_idx[pos] = (rowb + r) * D_SAE + col; cand_sc[pos] = s; }
          pos++;
        }
      }
    }
  }
}

// ---------- fallback 128^2 GEMM (small ws): MODE 0 = hist (1/16), MODE 1 = extract ----------
template <int MODE>
__global__ __launch_bounds__(256) void mfma_gemm(
    const float* __restrict__ Wenc,
    const short* __restrict__ Ahi, const short* __restrict__ Alo,
    const float* __restrict__ benc, const float* __restrict__ g32,
    int* __restrict__ ghist, int* __restrict__ ctrl,
    int* __restrict__ cand_idx, float* __restrict__ cand_sc) {
  __shared__ short sA[8192];
  __shared__ short sB[8192];
  __shared__ int h[(MODE == 0) ? 2048 : 2];
  const int tid = threadIdx.x;
  const int lane = tid & 63;
  const int w = tid >> 6;
  const int wm = (w >> 1) * 64, wn = (w & 1) * 64;
  int lin = blockIdx.x;
  int mt, nt;
  if (MODE == 0) { mt = lin >> 7; nt = lin & 127; }
  else { int xcd = lin & 7, j = lin >> 3; mt = j & 31; nt = (xcd << 4) | (j >> 5); }
  const int row0 = mt * 128, col0 = nt * 128;
  if (MODE == 0) { for (int i = tid; i < 2048; i += 256) h[i] = 0; }
  else if (tid == 0) h[0] = 0;
  const int nl = tid & 127;
  const int half = tid >> 7;
  const float* wbase = Wenc + (size_t)col0 + nl;
  const size_t atile = (size_t)mt * 131072;
  f32x4 acc[4][4] = {};
  const int kcl = lane >> 4, l15 = lane & 15;
  float4 a0, a1, a2, a3;
  float bfv[16];
  {
    const float4* ah4 = (const float4*)(Ahi + atile);
    const float4* al4 = (const float4*)(Alo + atile);
    a0 = ah4[tid]; a1 = ah4[tid + 256];
    a2 = al4[tid]; a3 = al4[tid + 256];
#pragma unroll
    for (int p = 0; p < 4; ++p)
#pragma unroll
      for (int i = 0; i < 4; ++i)
        bfv[p * 4 + i] = wbase[(size_t)(p * 8 + half * 4 + i) * D_SAE];
  }
  for (int ks = 0; ks < 32; ++ks) {
    short hb[16], lb[16];
#pragma unroll
    for (int q = 0; q < 16; ++q) {
      unsigned short hh = f2bf(bfv[q]);
      hb[q] = (short)hh;
      lb[q] = (short)f2bf(bfv[q] - bf2f(hh));
    }
    __syncthreads();
    *(float4*)&sA[(size_t)tid * 8] = a0;
    *(float4*)&sA[(size_t)(tid + 256) * 8] = a1;
    *(float4*)&sA[(size_t)(512 + tid) * 8] = a2;
    *(float4*)&sA[(size_t)(512 + tid + 256) * 8] = a3;
#pragma unroll
    for (int p = 0; p < 4; ++p) {
      int boff = p * 1024 + nl * 8 + half * 4;
      *(short4*)&sB[boff] = make_short4(hb[p * 4], hb[p * 4 + 1], hb[p * 4 + 2], hb[p * 4 + 3]);
      *(short4*)&sB[4096 + boff] = make_short4(lb[p * 4], lb[p * 4 + 1], lb[p * 4 + 2], lb[p * 4 + 3]);
    }
    __syncthreads();
    if (ks < 31) {
      const float4* ah4 = (const float4*)(Ahi + atile + (ks + 1) * 4096);
      const float4* al4 = (const float4*)(Alo + atile + (ks + 1) * 4096);
      a0 = ah4[tid]; a1 = ah4[tid + 256];
      a2 = al4[tid]; a3 = al4[tid + 256];
      const int k0n = (ks + 1) * 32;
#pragma unroll
      for (int p = 0; p < 4; ++p)
#pragma unroll
        for (int i = 0; i < 4; ++i)
          bfv[p * 4 + i] = wbase[(size_t)(k0n + p * 8 + half * 4 + i) * D_SAE];
    }
    bf16x8 ahf[4], alf[4];
#pragma unroll
    for (int fm = 0; fm < 4; ++fm) {
      int off = (kcl * 128 + wm + fm * 16 + l15) * 8;
      ahf[fm] = *(const bf16x8*)&sA[off];
      alf[fm] = *(const bf16x8*)&sA[4096 + off];
    }
#pragma unroll
    for (int fn = 0; fn < 4; ++fn) {
      int boff = (kcl * 128 + wn + fn * 16 + l15) * 8;
      bf16x8 bh = *(const bf16x8*)&sB[boff];
      bf16x8 bl = *(const bf16x8*)&sB[4096 + boff];
#pragma unroll
      for (int fm = 0; fm < 4; ++fm) {
        acc[fm][fn] = __builtin_amdgcn_mfma_f32_16x16x32_bf16(ahf[fm], bh, acc[fm][fn], 0, 0, 0);
        acc[fm][fn] = __builtin_amdgcn_mfma_f32_16x16x32_bf16(alf[fm], bh, acc[fm][fn], 0, 0, 0);
        acc[fm][fn] = __builtin_amdgcn_mfma_f32_16x16x32_bf16(ahf[fm], bl, acc[fm][fn], 0, 0, 0);
      }
    }
  }
  const int l4r = lane >> 4;
  if (MODE == 0) {
#pragma unroll
    for (int fn = 0; fn < 4; ++fn) {
      int col = col0 + wn + fn * 16 + l15;
      float g = g32[col], be = benc[col];
#pragma unroll
      for (int fm = 0; fm < 4; ++fm) {
#pragma unroll
        for (int r = 0; r < 4; ++r) {
          float z = acc[fm][fn][r] + be;
          float s = z > 0.f ? z * g : 0.f;
          unsigned bits = __float_as_uint(s);
          if (bits) atomicAdd(&h[bits >> 21], 1);
        }
      }
    }
    __syncthreads();
    for (int i = tid; i < 2048; i += 256)
      if (h[i]) atomicAdd(&ghist[i], h[i]);
  } else {
    unsigned thrBits = (unsigned)ctrl[1];
    int cnt = 0;
#pragma unroll
    for (int fn = 0; fn < 4; ++fn) {
      int col = col0 + wn + fn * 16 + l15;
      float g = g32[col], be = benc[col];
#pragma unroll
      for (int fm = 0; fm < 4; ++fm) {
#pragma unroll
        for (int r = 0; r < 4; ++r) {
          float z = acc[fm][fn][r] + be;
          float s = z > 0.f ? z * g : 0.f;
          cnt += (__float_as_uint(s) >= thrBits) ? 1 : 0;
        }
      }
    }
    int my = 0;
    if (cnt) my = atomicAdd(&h[0], cnt);
    __syncthreads();
    if (tid == 0) h[1] = atomicAdd(&ctrl[2], h[0]);
    __syncthreads();
    int pos = h[1] + my;
#pragma unroll
    for (int fn = 0; fn < 4; ++fn) {
      int col = col0 + wn + fn * 16 + l15;
      float g = g32[col], be = benc[col];
#pragma unroll
      for (int fm = 0; fm < 4; ++fm) {
        int rowb = row0 + wm + fm * 16 + l4r * 4;
#pragma unroll
        for (int r = 0; r < 4; ++r) {
          float z = acc[fm][fn][r] + be;
          float s = z > 0.f ? z * g : 0.f;
          if (__float_as_uint(s) >= thrBits) {
            if (pos < CAND_CAP) { cand_idx[pos] = (rowb + r) * D_SAE + col; cand_sc[pos] = s; }
            pos++;
          }
        }
      }
    }
  }
}

// ---------- coarse threshold (64-thread parallel scan) ----------
__global__ void find_coarse_kernel(const int* __restrict__ gh, int* ctrl,
                                   const int* __restrict__ kptr, int sub) {
  long long kB = (long long)kptr[0] * BATCH;
  long long needl = (kB + 500000 + sub - 1) / sub;
  long long fl = 720000 / sub;
  if (needl < fl) needl = fl;
  int b, cum;
  hist_scan_desc(gh, 2048, (int)needl, b, cum);
  if (threadIdx.x == 0) {
    long long est_incl = (long long)sub * (cum + gh[b]);
    if (est_incl > 3500000LL && (long long)sub * cum >= kB + 120000LL) b = b + 1;
    ctrl[1] = (int)(((unsigned)b) << 21);
  }
}

// ---------- radix histograms over candidate scores (passes 1,2) ----------
__global__ __launch_bounds__(256) void chist_kernel(const float* __restrict__ cand_sc,
                                                    const int* __restrict__ ctrl,
                                                    int* __restrict__ ghist, int pass) {
  __shared__ int h[2048];
  int nb = (pass == 2) ? 1024 : 2048;
  for (int i = threadIdx.x; i < nb; i += 256) h[i] = 0;
  __syncthreads();
  int n = ctrl[2]; if (n > CAND_CAP) n = CAND_CAP;
  unsigned sel1 = 0, sel22 = 0;
  if (pass == 1) sel1 = (unsigned)ctrl[3];
  if (pass == 2) sel22 = ((unsigned)ctrl[3] << 11) | (unsigned)ctrl[5];
  for (int i = blockIdx.x * 256 + threadIdx.x; i < n; i += gridDim.x * 256) {
    unsigned bits = __float_as_uint(cand_sc[i]);
    if (pass == 0) atomicAdd(&h[bits >> 21], 1);
    else if (pass == 1) { if ((bits >> 21) == sel1) atomicAdd(&h[(bits >> 10) & 0x7FFu], 1); }
    else { if ((bits >> 10) == sel22) atomicAdd(&h[bits & 0x3FFu], 1); }
  }
  __syncthreads();
  for (int i = threadIdx.x; i < nb; i += 256)
    if (h[i]) atomicAdd(&ghist[i], h[i]);
}

// ---------- radix select step (64-thread parallel scan) ----------
__global__ void cfind_kernel(const int* __restrict__ hist, int* ctrl,
                             const int* __restrict__ kptr, int pass) {
  int kB = kptr[0] * BATCH;
  int need, nbins;
  if (pass == 0)      { need = kB;                       nbins = 2048; }
  else if (pass == 1) { need = kB - ctrl[4];             nbins = 2048; }
  else                { need = kB - ctrl[4] - ctrl[6];   nbins = 1024; }
  int b, cum;
  hist_scan_desc(hist, nbins, need, b, cum);
  if (threadIdx.x == 0) {
    if (pass == 0)      { ctrl[3] = b; ctrl[4] = cum; }
    else if (pass == 1) { ctrl[5] = b; ctrl[6] = cum; }
    else {
      unsigned vbits = ((unsigned)ctrl[3] << 21) | ((unsigned)ctrl[5] << 10) | (unsigned)b;
      float V = __uint_as_float(vbits);
      float* cf = (float*)ctrl;
      cf[8] = V; cf[9] = V + EPS_M; cf[10] = V - EPS_M;
    }
  }
}

// ---------- band partition ----------
__global__ __launch_bounds__(256) void band_kernel(const int* __restrict__ cand_idx,
    const float* __restrict__ cand_sc, const float* __restrict__ g32,
    int* ctrl, int* row_cnt, int* row_feat, float* row_act, int* cand2_idx) {
  const float* cf = (const float*)ctrl;
  float hi = cf[9], lo = cf[10];
  int n = ctrl[2]; if (n > CAND_CAP) n = CAND_CAP;
  int lane = threadIdx.x & 63;
  int defc = 0;
  for (int i = blockIdx.x * 256 + threadIdx.x; i < n; i += gridDim.x * 256) {
    float s = cand_sc[i];
    int flat = cand_idx[i];
    if (s > hi) {
      int b = flat >> 14, j = flat & (D_SAE - 1);
      int p = atomicAdd(&row_cnt[b], 1);
      if (p < ROW_CAP) { row_feat[b * ROW_CAP + p] = j; row_act[b * ROW_CAP + p] = s / g32[j]; }
      defc++;
    }
    bool isc = (s <= hi) && (s >= lo);
    int pos = wave_append(isc, &ctrl[12]);
    if (isc && pos >= 0 && pos < CAND2_CAP) cand2_idx[pos] = flat;
  }
#pragma unroll
  for (int off = 32; off > 0; off >>= 1) defc += __shfl_down(defc, off, 64);
  if (lane == 0 && defc) atomicAdd(&ctrl[11], defc);
}

// ---------- fp64 rescore of band candidates ----------
__global__ __launch_bounds__(256) void cand2_score_kernel(const int* __restrict__ ctrl,
    const int* __restrict__ cand2_idx, const float* __restrict__ x,
    const float* __restrict__ Wdec, const float* __restrict__ benc,
    const double* __restrict__ g64, double* __restrict__ cand2_sc) {
  __shared__ double lds[4];
  int n2 = ctrl[12]; if (n2 > CAND2_CAP) n2 = CAND2_CAP;
  int t = threadIdx.x;
  for (int c = blockIdx.x; c < n2; c += gridDim.x) {
    int flat = cand2_idx[c];
    int b = flat >> 14, j = flat & (D_SAE - 1);
    double d[4];
    ln_row_fp64(x + (size_t)b * (2 * D_MODEL), lds, d);
    float4 w4 = *(const float4*)(Wdec + (size_t)j * D_MODEL + t * 4);
    double a = d[0] * (double)w4.x + d[1] * (double)w4.y + d[2] * (double)w4.z + d[3] * (double)w4.w;
    double z = blockReduceSum256(a, lds) + (double)benc[j];
    double sc = z > 0 ? z * g64[j] : 0.0;
    if (t == 0) cand2_sc[c] = sc;
  }
}

// ---------- rank band candidates (fp64, index-stable), accept fill ----------
__global__ __launch_bounds__(256) void cand2_rank_kernel(const int* __restrict__ ctrl,
    const int* __restrict__ cand2_idx, const double* __restrict__ cand2_sc,
    const double* __restrict__ g64, const int* __restrict__ kptr,
    int* row_cnt, int* row_feat, float* row_act) {
  __shared__ int lds[4];
  int n2 = ctrl[12]; if (n2 > CAND2_CAP) n2 = CAND2_CAP;
  int kB = kptr[0] * BATCH;
  int fill = kB - ctrl[11];
  int t = threadIdx.x;
  for (int c = blockIdx.x; c < n2; c += gridDim.x) {
    double sc = cand2_sc[c];
    int fc = cand2_idx[c];
    int cnt = 0;
    for (int y = t; y < n2; y += 256) {
      double sy = cand2_sc[y];
      if (sy > sc || (sy == sc && cand2_idx[y] < fc)) cnt++;
    }
    cnt = blockReduceSumInt256(cnt, lds);
    if (t == 0 && cnt < fill) {
      int b = fc >> 14, j = fc & (D_SAE - 1);
      int p = atomicAdd(&row_cnt[b], 1);
      if (p < ROW_CAP) { row_feat[b * ROW_CAP + p] = j; row_act[b * ROW_CAP + p] = (float)(sc / g64[j]); }
    }
  }
}

// ---------- sparse recon (float4, 2-way ILP) ----------
__global__ __launch_bounds__(256) void recon_kernel(const int* __restrict__ row_cnt,
    const int* __restrict__ row_feat, const float* __restrict__ row_act,
    const float* __restrict__ Wdec, const float* __restrict__ bdec, float* __restrict__ out) {
  int b = blockIdx.x, t = threadIdx.x;
  float4 acc0 = *(const float4*)&bdec[t * 4];
  float4 acc1 = make_float4(0.f, 0.f, 0.f, 0.f);
  int n = row_cnt[b]; if (n > ROW_CAP) n = ROW_CAP;
  const int* rf = row_feat + (size_t)b * ROW_CAP;
  const float* ra = row_act + (size_t)b * ROW_CAP;
  int p = 0;
  for (; p + 2 <= n; p += 2) {
    int j0 = rf[p], j1 = rf[p + 1];
    float v0 = ra[p], v1 = ra[p + 1];
    float4 w0 = *(const float4*)(Wdec + (size_t)j0 * D_MODEL + t * 4);
    float4 w1 = *(const float4*)(Wdec + (size_t)j1 * D_MODEL + t * 4);
    acc0.x += v0 * w0.x; acc0.y += v0 * w0.y; acc0.z += v0 * w0.z; acc0.w += v0 * w0.w;
    acc1.x += v1 * w1.x; acc1.y += v1 * w1.y; acc1.z += v1 * w1.z; acc1.w += v1 * w1.w;
  }
  if (p < n) {
    int j0 = rf[p]; float v0 = ra[p];
    float4 w0 = *(const float4*)(Wdec + (size_t)j0 * D_MODEL + t * 4);
    acc0.x += v0 * w0.x; acc0.y += v0 * w0.y; acc0.z += v0 * w0.z; acc0.w += v0 * w0.w;
  }
  acc0.x += acc1.x; acc0.y += acc1.y; acc0.z += acc1.z; acc0.w += acc1.w;
  *(float4*)(out + (size_t)b * D_MODEL + t * 4) = acc0;
}

extern "C" void kernel_launch(void* const* d_in, const int* in_sizes, int n_in,
                              void* d_out, int out_size, void* d_ws, size_t ws_size,
                              hipStream_t stream) {
  const float* x    = (const float*)d_in[0];
  const float* Wenc = (const float*)d_in[1];
  const float* benc = (const float*)d_in[2];
  const float* Wdec = (const float*)d_in[3];
  const float* bdec = (const float*)d_in[4];
  const int*   kptr = (const int*)d_in[5];
  float* out = (float*)d_out;

  char* ws = (char*)d_ws;
  size_t off = 0;
  short*  Ahi       = (short*)(ws + off);  off += (size_t)BATCH * D_MODEL * 2;
  short*  Alo       = (short*)(ws + off);  off += (size_t)BATCH * D_MODEL * 2;
  int*    cand_idx  = (int*)(ws + off);    off += (size_t)CAND_CAP * 4;
  float*  cand_sc   = (float*)(ws + off);  off += (size_t)CAND_CAP * 4;
  int*    row_feat  = (int*)(ws + off);    off += (size_t)BATCH * ROW_CAP * 4;
  float*  row_act   = (float*)(ws + off);  off += (size_t)BATCH * ROW_CAP * 4;
  int*    cand2_idx = (int*)(ws + off);    off += (size_t)CAND2_CAP * 4;
  double* cand2_sc  = (double*)(ws + off); off += (size_t)CAND2_CAP * 8;
  double* g64       = (double*)(ws + off); off += (size_t)D_SAE * 8;
  float*  g32       = (float*)(ws + off);  off += (size_t)D_SAE * 4;
  char*   zbase     = ws + off;
  int* ghist   = (int*)(zbase);
  int* h1      = (int*)(zbase + 8192);
  int* h2      = (int*)(zbase + 16384);
  int* h3      = (int*)(zbase + 24576);
  int* ctrl    = (int*)(zbase + 28672);
  int* row_cnt = (int*)(zbase + 28928);
  size_t zbytes = 28928 + (size_t)BATCH * 4;
  size_t small_need = off + zbytes;
  if (small_need > ws_size) return;  // ~60 MB floor

  size_t big_off = (small_need + 255) & ~(size_t)255;
  short* Whi = (short*)(ws + big_off);
  short* Wlo = Whi + (size_t)D_MODEL * D_SAE;
  size_t big_need = big_off + (size_t)D_MODEL * D_SAE * 4;
  const bool big = (big_need <= ws_size);   // round-6..15-proven to fit

  hipMemsetAsync(zbase, 0, zbytes, stream);

  ln_kernel<<<BATCH / 4, 256, 0, stream>>>(x, Ahi, Alo);
  norm_kernel<<<D_SAE / 4, 256, 0, stream>>>(Wdec, g64, g32);
  if (big) {
    wsplit_kernel<<<4096, 256, 0, stream>>>(Wenc, Whi, Wlo);
    hist_gemm<<<256, 256, 0, stream>>>(Whi, Ahi, benc, g32, ghist);
    find_coarse_kernel<<<1, 64, 0, stream>>>(ghist, ctrl, kptr, 16);
    extract_gemm128<<<4096, 256, 0, stream>>>(Whi, Wlo, Ahi, Alo, benc, g32, ctrl, cand_idx, cand_sc, h1);
  } else {
    mfma_gemm<0><<<256, 256, 0, stream>>>(Wenc, Ahi, Alo, benc, g32, ghist, ctrl, nullptr, nullptr);
    find_coarse_kernel<<<1, 64, 0, stream>>>(ghist, ctrl, kptr, 16);
    mfma_gemm<1><<<4096, 256, 0, stream>>>(Wenc, Ahi, Alo, benc, g32, nullptr, ctrl, cand_idx, cand_sc);
    chist_kernel<<<1024, 256, 0, stream>>>(cand_sc, ctrl, h1, 0);
  }
  cfind_kernel<<<1, 64, 0, stream>>>(h1, ctrl, kptr, 0);
  chist_kernel<<<1024, 256, 0, stream>>>(cand_sc, ctrl, h2, 1);
  cfind_kernel<<<1, 64, 0, stream>>>(h2, ctrl, kptr, 1);
  chist_kernel<<<1024, 256, 0, stream>>>(cand_sc, ctrl, h3, 2);
  cfind_kernel<<<1, 64, 0, stream>>>(h3, ctrl, kptr, 2);
  band_kernel<<<1024, 256, 0, stream>>>(cand_idx, cand_sc, g32, ctrl, row_cnt, row_feat, row_act, cand2_idx);
  cand2_score_kernel<<<4096, 256, 0, stream>>>(ctrl, cand2_idx, x, Wdec, benc, g64, cand2_sc);
  cand2_rank_kernel<<<2048, 256, 0, stream>>>(ctrl, cand2_idx, cand2_sc, g64, kptr, row_cnt, row_feat, row_act);
  recon_kernel<<<BATCH, 256, 0, stream>>>(row_cnt, row_feat, row_act, Wdec, bdec, out);
}

// Round 17
// 683.654 us; speedup vs baseline: 1.2348x; 1.0733x over previous
//
#include <hip/hip_runtime.h>
#include <math.h>

#define D_MODEL 1024
#define D_SAE   16384
#define BATCH   4096
#define NTOT    (1ull * BATCH * D_SAE)
#define LN_EPS  1e-8
#define EPS_M   3e-4f        // |split-bf16 score - fp64 score| safe band half-width (>=6x margin)
#define ROW_CAP 256
#define CAND_CAP  (4 * 1024 * 1024)
#define CAND2_CAP 65536

using bf16x8 = __attribute__((ext_vector_type(8))) short;
using f32x4  = __attribute__((ext_vector_type(4))) float;

__device__ inline unsigned short f2bf(float f) {   // RNE fp32->bf16
  unsigned u = __float_as_uint(f);
  return (unsigned short)((u + 0x7fffu + ((u >> 16) & 1u)) >> 16);
}
__device__ inline float bf2f(unsigned short h) {
  return __uint_as_float((unsigned)h << 16);
}

// ---------- block (256-thread) reductions ----------
__device__ inline double blockReduceSum256(double v, double* lds) {
#pragma unroll
  for (int off = 32; off > 0; off >>= 1) v += __shfl_down(v, off, 64);
  int lane = threadIdx.x & 63, wid = threadIdx.x >> 6;
  __syncthreads();
  if (lane == 0) lds[wid] = v;
  __syncthreads();
  return lds[0] + lds[1] + lds[2] + lds[3];
}
__device__ inline int blockReduceSumInt256(int v, int* lds) {
#pragma unroll
  for (int off = 32; off > 0; off >>= 1) v += __shfl_down(v, off, 64);
  int lane = threadIdx.x & 63, wid = threadIdx.x >> 6;
  __syncthreads();
  if (lane == 0) lds[wid] = v;
  __syncthreads();
  return lds[0] + lds[1] + lds[2] + lds[3];
}

__device__ inline int wave_append(bool pred, int* counter) {
  unsigned long long m = __ballot(pred);
  int lane = threadIdx.x & 63;
  int pos = -1;
  if (m) {
    int ldr = __ffsll((long long)m) - 1;
    int base = 0;
    if (lane == ldr) base = atomicAdd(counter, __popcll(m));
    base = __shfl(base, ldr, 64);
    if (pred) pos = base + __popcll(m & ((1ull << lane) - 1ull));
  }
  return pos;
}

// ---------- 64-lane parallel descending histogram scan ----------
__device__ inline void hist_scan_desc(const int* __restrict__ hist, int nbins, int need,
                                      int& bsel, int& cumsel) {
  int t = threadIdx.x;          // 0..63
  int chunk = nbins >> 6;
  int topbase = nbins - t * chunk;
  int psum = 0;
  for (int i = 1; i <= chunk; ++i) psum += hist[topbase - i];
  int incl = psum;
#pragma unroll
  for (int off = 1; off < 64; off <<= 1) {
    int v = __shfl_up(incl, off, 64);
    if (t >= off) incl += v;
  }
  int excl = incl - psum;
  bool hit = (excl < need) && (excl + psum >= need);
  unsigned long long m = __ballot(hit);
  int tb = m ? (__ffsll((long long)m) - 1) : 63;
  int exb = __shfl(excl, tb, 64);
  int res_b = 0, res_c = 0;
  if (t == tb) {
    int c = exb;
    int b = nbins - tb * chunk - 1;
    int bend = b - chunk;
    for (; b > 0 && b > bend; --b) {
      int cc = hist[b];
      if (c + cc >= need) break;
      c += cc;
    }
    res_b = b; res_c = c;
  }
  bsel = __shfl(res_b, tb, 64);
  cumsel = __shfl(res_c, tb, 64);
}

// ---------- per-thread fp64 LN chain (256-thr block version, used by cand2) ----------
__device__ inline void ln_row_fp64(const float* __restrict__ row, double* lds, double d[4]) {
  int t = threadIdx.x;
  float4 s4 = *(const float4*)(row + t * 4);
  float4 t4 = *(const float4*)(row + D_MODEL + t * 4);
  double s[4] = {s4.x, s4.y, s4.z, s4.w};
  double tt[4] = {t4.x, t4.y, t4.z, t4.w};
  double ms = blockReduceSum256(s[0] + s[1] + s[2] + s[3], lds) / D_MODEL;
  double mt = blockReduceSum256(tt[0] + tt[1] + tt[2] + tt[3], lds) / D_MODEL;
  double vs = 0, vt = 0;
#pragma unroll
  for (int i = 0; i < 4; i++) { double a = s[i] - ms; vs += a * a; a = tt[i] - mt; vt += a * a; }
  vs = blockReduceSum256(vs, lds) / D_MODEL;
  vt = blockReduceSum256(vt, lds) / D_MODEL;
  double rs = sqrt(vs + LN_EPS), rt = sqrt(vt + LN_EPS);
  double u[4];
#pragma unroll
  for (int i = 0; i < 4; i++) u[i] = (tt[i] - mt) / rt - (s[i] - ms) / rs;
  double mu = blockReduceSum256(u[0] + u[1] + u[2] + u[3], lds) / D_MODEL;
  double vu = 0;
#pragma unroll
  for (int i = 0; i < 4; i++) { double a = u[i] - mu; vu += a * a; }
  vu = blockReduceSum256(vu, lds) / D_MODEL;
  double ru = sqrt(vu + LN_EPS);
#pragma unroll
  for (int i = 0; i < 4; i++) d[i] = (u[i] - mu) / ru;
}

// ---------- LN -> split-bf16 A, wave-per-row (no barriers), tiled layout ----------
__global__ __launch_bounds__(256) void ln_kernel(const float* __restrict__ x,
                                                 short* __restrict__ Ahi, short* __restrict__ Alo) {
  int wv = threadIdx.x >> 6, lane = threadIdx.x & 63;
  int b = (blockIdx.x << 2) | wv;
  const float* row = x + (size_t)b * (2 * D_MODEL);
  float s[16], t[16];
  const float4* s4p = (const float4*)(row + lane * 16);
  const float4* t4p = (const float4*)(row + D_MODEL + lane * 16);
  double sum_s = 0, sum_t = 0;
#pragma unroll
  for (int q = 0; q < 4; ++q) {
    float4 a = s4p[q], c = t4p[q];
    s[q * 4 + 0] = a.x; s[q * 4 + 1] = a.y; s[q * 4 + 2] = a.z; s[q * 4 + 3] = a.w;
    t[q * 4 + 0] = c.x; t[q * 4 + 1] = c.y; t[q * 4 + 2] = c.z; t[q * 4 + 3] = c.w;
  }
#pragma unroll
  for (int i = 0; i < 16; ++i) { sum_s += s[i]; sum_t += t[i]; }
#pragma unroll
  for (int off = 1; off < 64; off <<= 1) {
    sum_s += __shfl_xor(sum_s, off, 64);
    sum_t += __shfl_xor(sum_t, off, 64);
  }
  double ms = sum_s / D_MODEL, mt_ = sum_t / D_MODEL;
  double vs = 0, vt = 0;
#pragma unroll
  for (int i = 0; i < 16; ++i) {
    double a = s[i] - ms; vs += a * a;
    double c = t[i] - mt_; vt += c * c;
  }
#pragma unroll
  for (int off = 1; off < 64; off <<= 1) {
    vs += __shfl_xor(vs, off, 64);
    vt += __shfl_xor(vt, off, 64);
  }
  double rs = sqrt(vs / D_MODEL + LN_EPS), rt = sqrt(vt / D_MODEL + LN_EPS);
  double u[16], su = 0;
#pragma unroll
  for (int i = 0; i < 16; ++i) { u[i] = (t[i] - mt_) / rt - (s[i] - ms) / rs; su += u[i]; }
#pragma unroll
  for (int off = 1; off < 64; off <<= 1) su += __shfl_xor(su, off, 64);
  double mu = su / D_MODEL, vu = 0;
#pragma unroll
  for (int i = 0; i < 16; ++i) { double a = u[i] - mu; vu += a * a; }
#pragma unroll
  for (int off = 1; off < 64; off <<= 1) vu += __shfl_xor(vu, off, 64);
  double ru = sqrt(vu / D_MODEL + LN_EPS);
  int mtb = b >> 7, ml = b & 127;
#pragma unroll
  for (int blk8 = 0; blk8 < 2; ++blk8) {
    short h8[8], l8[8];
#pragma unroll
    for (int e = 0; e < 8; ++e) {
      int i = blk8 * 8 + e;
      double dd = (u[i] - mu) / ru;
      float f = (float)dd;
      unsigned short hh = f2bf(f);
      h8[e] = (short)hh;
      l8[e] = (short)f2bf(f - bf2f(hh));
    }
    int gi = lane * 16 + blk8 * 8;
    int ks = gi >> 5, kc = (gi >> 3) & 3;
    size_t base = ((((size_t)mtb * 32 + ks) * 4 + kc) * 128 + ml) * 8;
    *(float4*)&Ahi[base] = *(float4*)h8;
    *(float4*)&Alo[base] = *(float4*)l8;
  }
}

// ---------- dec_norms in fp64 (wave-per-feature, no block syncs) ----------
__global__ __launch_bounds__(256) void norm_kernel(const float* __restrict__ Wdec,
                                                   double* __restrict__ g64, float* __restrict__ g32) {
  int wv = threadIdx.x >> 6, lane = threadIdx.x & 63;
  int j = (blockIdx.x << 2) | wv;
  const float4* rowp = (const float4*)(Wdec + (size_t)j * D_MODEL);
  double a = 0;
#pragma unroll
  for (int q = 0; q < 4; ++q) {
    float4 w = rowp[lane + q * 64];
    a += (double)w.x * w.x + (double)w.y * w.y + (double)w.z * w.z + (double)w.w * w.w;
  }
#pragma unroll
  for (int off = 32; off > 0; off >>= 1) a += __shfl_down(a, off, 64);
  if (lane == 0) { double g = sqrt(a); g64[j] = g; g32[j] = (float)g; }
}

// ---------- pre-split W_enc fp32 -> tiled bf16 hi/lo [nt][ks][kc][c][e] ----------
__global__ __launch_bounds__(256) void wsplit_kernel(const float* __restrict__ Wenc,
                                                     short* __restrict__ Whi, short* __restrict__ Wlo) {
  __shared__ short sh[4096];
  __shared__ short sl[4096];
  int blk = blockIdx.x;            // 4096 = 128 nt * 32 ks
  int nt = blk >> 5, ks = blk & 31;
  int t = threadIdx.x;
  int r = t >> 3;
  int cg = t & 7;
  int kc = r >> 3, e = r & 7;
  const float* src = Wenc + (size_t)(ks * 32 + r) * D_SAE + nt * 128 + cg;
#pragma unroll
  for (int j = 0; j < 16; ++j) {
    float f = src[j * 8];
    unsigned short hh = f2bf(f);
    short ll = (short)f2bf(f - bf2f(hh));
    int c = j * 8 + cg;
    sh[kc * 1024 + c * 8 + e] = (short)hh;
    sl[kc * 1024 + c * 8 + e] = ll;
  }
  __syncthreads();
  size_t obase = ((size_t)nt * 32 + ks) * 4096;
  *(float4*)&Whi[obase + t * 16]     = *(const float4*)&sh[t * 16];
  *(float4*)&Whi[obase + t * 16 + 8] = *(const float4*)&sh[t * 16 + 8];
  *(float4*)&Wlo[obase + t * 16]     = *(const float4*)&sl[t * 16];
  *(float4*)&Wlo[obase + t * 16 + 8] = *(const float4*)&sl[t * 16 + 8];
}

// ---------- Wdec fp32 -> row-major bf16 (for recon), into dead cand region ----------
__global__ __launch_bounds__(256) void wdecsplit_kernel(const float* __restrict__ Wdec,
                                                        short* __restrict__ wdech) {
  int j = blockIdx.x, t = threadIdx.x;
  float4 w = *(const float4*)(Wdec + (size_t)j * D_MODEL + t * 4);
  short4 h;
  h.x = (short)f2bf(w.x); h.y = (short)f2bf(w.y);
  h.z = (short)f2bf(w.z); h.w = (short)f2bf(w.w);
  *(short4*)&wdech[(size_t)j * D_MODEL + t * 4] = h;
}

// ---------- hi-only 1/16-subsampled hist GEMM: per-wave privatized hist ----------
__global__ __launch_bounds__(256) void hist_gemm(
    const short* __restrict__ Whi, const short* __restrict__ Ahi,
    const float* __restrict__ benc, const float* __restrict__ g32,
    int* __restrict__ ghist) {
  __shared__ short sA[4096];
  __shared__ short sB[4096];
  __shared__ int h[4][2048];
  const int tid = threadIdx.x;
  const int lane = tid & 63;
  const int w = tid >> 6;
  const int wm = (w >> 1) * 64, wn = (w & 1) * 64;
  int lin = blockIdx.x;            // 256 = 2 mt * 128 nt
  int mt = lin >> 7, nt = lin & 127;
  const int col0 = nt * 128;
  for (int i = tid; i < 8192; i += 256) ((int*)h)[i] = 0;
  const size_t atile = (size_t)mt * 131072;
  const size_t btile = (size_t)nt * 131072;
  f32x4 acc[4][4] = {};
  const int kcl = lane >> 4, l15 = lane & 15;

  float4 a0, a1, b0, b1;
  {
    const float4* ah4 = (const float4*)(Ahi + atile);
    const float4* bh4 = (const float4*)(Whi + btile);
    a0 = ah4[tid]; a1 = ah4[tid + 256];
    b0 = bh4[tid]; b1 = bh4[tid + 256];
  }
  for (int ks = 0; ks < 32; ++ks) {
    __syncthreads();
    *(float4*)&sA[(size_t)tid * 8] = a0;
    *(float4*)&sA[(size_t)(tid + 256) * 8] = a1;
    *(float4*)&sB[(size_t)tid * 8] = b0;
    *(float4*)&sB[(size_t)(tid + 256) * 8] = b1;
    __syncthreads();
    if (ks < 31) {
      const float4* ah4 = (const float4*)(Ahi + atile + (ks + 1) * 4096);
      const float4* bh4 = (const float4*)(Whi + btile + (ks + 1) * 4096);
      a0 = ah4[tid]; a1 = ah4[tid + 256];
      b0 = bh4[tid]; b1 = bh4[tid + 256];
    }
    bf16x8 ahf[4];
#pragma unroll
    for (int fm = 0; fm < 4; ++fm)
      ahf[fm] = *(const bf16x8*)&sA[(kcl * 128 + wm + fm * 16 + l15) * 8];
#pragma unroll
    for (int fn = 0; fn < 4; ++fn) {
      bf16x8 bh = *(const bf16x8*)&sB[(kcl * 128 + wn + fn * 16 + l15) * 8];
#pragma unroll
      for (int fm = 0; fm < 4; ++fm)
        acc[fm][fn] = __builtin_amdgcn_mfma_f32_16x16x32_bf16(ahf[fm], bh, acc[fm][fn], 0, 0, 0);
    }
  }
#pragma unroll
  for (int fn = 0; fn < 4; ++fn) {
    int col = col0 + wn + fn * 16 + l15;
    float g = g32[col], be = benc[col];
#pragma unroll
    for (int fm = 0; fm < 4; ++fm) {
#pragma unroll
      for (int r = 0; r < 4; ++r) {
        float z = acc[fm][fn][r] + be;
        float s = z > 0.f ? z * g : 0.f;
        unsigned bits = __float_as_uint(s);
        if (bits) atomicAdd(&h[w][bits >> 21], 1);
      }
    }
  }
  __syncthreads();
  for (int i = tid; i < 2048; i += 256) {
    int v = h[0][i] + h[1][i] + h[2][i] + h[3][i];
    if (v) atomicAdd(&ghist[i], v);
  }
}

// ---------- 128x128 split-bf16 MFMA extract GEMM ----------
// XCD owns 4 mt A-tiles (L2-resident); streams B panels in nt order.
// Pass-0 histogram aliased into sA; __launch_bounds__(256,3) pins 3 blocks/CU.
__global__ __launch_bounds__(256, 3) void extract_gemm128(
    const short* __restrict__ Whi, const short* __restrict__ Wlo,
    const short* __restrict__ Ahi, const short* __restrict__ Alo,
    const float* __restrict__ benc, const float* __restrict__ g32,
    int* __restrict__ ctrl, int* __restrict__ cand_idx, float* __restrict__ cand_sc,
    int* __restrict__ ghist) {
  __shared__ short sA[8192];   // hi [4][128][8] | lo at +4096 ; reused as hist after K-loop
  __shared__ short sB[8192];

  const int tid = threadIdx.x;
  const int lane = tid & 63;
  const int w = tid >> 6;
  const int wm = (w >> 1) * 64, wn = (w & 1) * 64;

  // A-resident partition: XCD owns mt in [4*xcd, 4*xcd+4); B streams in nt order.
  int lin = blockIdx.x;
  int xcd = lin & 7, j = lin >> 3;
  int mt = (xcd << 2) | (j & 3);
  int nt = j >> 2;
  const int row0 = mt * 128, col0 = nt * 128;

  const size_t atile = (size_t)mt * 131072;
  const size_t btile = (size_t)nt * 131072;

  f32x4 acc[4][4] = {};
  const int kcl = lane >> 4, l15 = lane & 15;

  float4 a0, a1, a2, a3, b0, b1, b2, b3;
  {
    const float4* ah4 = (const float4*)(Ahi + atile);
    const float4* al4 = (const float4*)(Alo + atile);
    const float4* bh4 = (const float4*)(Whi + btile);
    const float4* bl4 = (const float4*)(Wlo + btile);
    a0 = ah4[tid]; a1 = ah4[tid + 256];
    a2 = al4[tid]; a3 = al4[tid + 256];
    b0 = bh4[tid]; b1 = bh4[tid + 256];
    b2 = bl4[tid]; b3 = bl4[tid + 256];
  }

  for (int ks = 0; ks < 32; ++ks) {
    __syncthreads();   // previous tile fully consumed
    *(float4*)&sA[(size_t)tid * 8] = a0;
    *(float4*)&sA[(size_t)(tid + 256) * 8] = a1;
    *(float4*)&sA[(size_t)(512 + tid) * 8] = a2;
    *(float4*)&sA[(size_t)(512 + tid + 256) * 8] = a3;
    *(float4*)&sB[(size_t)tid * 8] = b0;
    *(float4*)&sB[(size_t)(tid + 256) * 8] = b1;
    *(float4*)&sB[(size_t)(512 + tid) * 8] = b2;
    *(float4*)&sB[(size_t)(512 + tid + 256) * 8] = b3;
    __syncthreads();   // tile visible
    if (ks < 31) {
      const int o = (ks + 1) * 4096;
      const float4* ah4 = (const float4*)(Ahi + atile + o);
      const float4* al4 = (const float4*)(Alo + atile + o);
      const float4* bh4 = (const float4*)(Whi + btile + o);
      const float4* bl4 = (const float4*)(Wlo + btile + o);
      a0 = ah4[tid]; a1 = ah4[tid + 256];
      a2 = al4[tid]; a3 = al4[tid + 256];
      b0 = bh4[tid]; b1 = bh4[tid + 256];
      b2 = bl4[tid]; b3 = bl4[tid + 256];
    }
    bf16x8 ahf[4], alf[4];
#pragma unroll
    for (int fm = 0; fm < 4; ++fm) {
      int off = (kcl * 128 + wm + fm * 16 + l15) * 8;
      ahf[fm] = *(const bf16x8*)&sA[off];
      alf[fm] = *(const bf16x8*)&sA[4096 + off];
    }
#pragma unroll
    for (int fn = 0; fn < 4; ++fn) {
      int boff = (kcl * 128 + wn + fn * 16 + l15) * 8;
      bf16x8 bh = *(const bf16x8*)&sB[boff];
      bf16x8 bl = *(const bf16x8*)&sB[4096 + boff];
#pragma unroll
      for (int fm = 0; fm < 4; ++fm) {
        acc[fm][fn] = __builtin_amdgcn_mfma_f32_16x16x32_bf16(ahf[fm], bh, acc[fm][fn], 0, 0, 0);
        acc[fm][fn] = __builtin_amdgcn_mfma_f32_16x16x32_bf16(alf[fm], bh, acc[fm][fn], 0, 0, 0);
        acc[fm][fn] = __builtin_amdgcn_mfma_f32_16x16x32_bf16(ahf[fm], bl, acc[fm][fn], 0, 0, 0);
      }
    }
  }

  // epilogue: alias hist into sA (dead after K-loop). hh[0..2047]=hist,
  // hh[2048]=block count, hh[2049]=global base.
  int* hh = (int*)sA;
  const int l4r = lane >> 4;
  unsigned thrBits = (unsigned)ctrl[1];
  __syncthreads();                         // all sA fragment reads done
  for (int i = tid; i < 2050; i += 256) hh[i] = 0;
  __syncthreads();
  int cnt = 0;
#pragma unroll
  for (int fn = 0; fn < 4; ++fn) {
    int col = col0 + wn + fn * 16 + l15;
    float g = g32[col], be = benc[col];
#pragma unroll
    for (int fm = 0; fm < 4; ++fm) {
#pragma unroll
      for (int r = 0; r < 4; ++r) {
        float z = acc[fm][fn][r] + be;
        float s = z > 0.f ? z * g : 0.f;
        unsigned bits = __float_as_uint(s);
        if (bits >= thrBits) { cnt++; atomicAdd(&hh[bits >> 21], 1); }
      }
    }
  }
  int my = 0;
  if (cnt) my = atomicAdd(&hh[2048], cnt);
  __syncthreads();
  if (tid == 0) hh[2049] = atomicAdd(&ctrl[2], hh[2048]);
  for (int i = tid; i < 2048; i += 256)
    if (hh[i]) atomicAdd(&ghist[i], hh[i]);
  __syncthreads();
  int pos = hh[2049] + my;
#pragma unroll
  for (int fn = 0; fn < 4; ++fn) {
    int col = col0 + wn + fn * 16 + l15;
    float g = g32[col], be = benc[col];
#pragma unroll
    for (int fm = 0; fm < 4; ++fm) {
      int rowb = row0 + wm + fm * 16 + l4r * 4;
#pragma unroll
      for (int r = 0; r < 4; ++r) {
        float z = acc[fm][fn][r] + be;
        float s = z > 0.f ? z * g : 0.f;
        if (__float_as_uint(s) >= thrBits) {
          if (pos < CAND_CAP) { cand_idx[pos] = (rowb + r) * D_SAE + col; cand_sc[pos] = s; }
          pos++;
        }
      }
    }
  }
}

// ---------- fallback 128^2 GEMM (small ws): MODE 0 = hist (1/16), MODE 1 = extract ----------
template <int MODE>
__global__ __launch_bounds__(256) void mfma_gemm(
    const float* __restrict__ Wenc,
    const short* __restrict__ Ahi, const short* __restrict__ Alo,
    const float* __restrict__ benc, const float* __restrict__ g32,
    int* __restrict__ ghist, int* __restrict__ ctrl,
    int* __restrict__ cand_idx, float* __restrict__ cand_sc) {
  __shared__ short sA[8192];
  __shared__ short sB[8192];
  __shared__ int h[(MODE == 0) ? 2048 : 2];
  const int tid = threadIdx.x;
  const int lane = tid & 63;
  const int w = tid >> 6;
  const int wm = (w >> 1) * 64, wn = (w & 1) * 64;
  int lin = blockIdx.x;
  int mt, nt;
  if (MODE == 0) { mt = lin >> 7; nt = lin & 127; }
  else { int xcd = lin & 7, j = lin >> 3; mt = j & 31; nt = (xcd << 4) | (j >> 5); }
  const int row0 = mt * 128, col0 = nt * 128;
  if (MODE == 0) { for (int i = tid; i < 2048; i += 256) h[i] = 0; }
  else if (tid == 0) h[0] = 0;
  const int nl = tid & 127;
  const int half = tid >> 7;
  const float* wbase = Wenc + (size_t)col0 + nl;
  const size_t atile = (size_t)mt * 131072;
  f32x4 acc[4][4] = {};
  const int kcl = lane >> 4, l15 = lane & 15;
  float4 a0, a1, a2, a3;
  float bfv[16];
  {
    const float4* ah4 = (const float4*)(Ahi + atile);
    const float4* al4 = (const float4*)(Alo + atile);
    a0 = ah4[tid]; a1 = ah4[tid + 256];
    a2 = al4[tid]; a3 = al4[tid + 256];
#pragma unroll
    for (int p = 0; p < 4; ++p)
#pragma unroll
      for (int i = 0; i < 4; ++i)
        bfv[p * 4 + i] = wbase[(size_t)(p * 8 + half * 4 + i) * D_SAE];
  }
  for (int ks = 0; ks < 32; ++ks) {
    short hb[16], lb[16];
#pragma unroll
    for (int q = 0; q < 16; ++q) {
      unsigned short hh = f2bf(bfv[q]);
      hb[q] = (short)hh;
      lb[q] = (short)f2bf(bfv[q] - bf2f(hh));
    }
    __syncthreads();
    *(float4*)&sA[(size_t)tid * 8] = a0;
    *(float4*)&sA[(size_t)(tid + 256) * 8] = a1;
    *(float4*)&sA[(size_t)(512 + tid) * 8] = a2;
    *(float4*)&sA[(size_t)(512 + tid + 256) * 8] = a3;
#pragma unroll
    for (int p = 0; p < 4; ++p) {
      int boff = p * 1024 + nl * 8 + half * 4;
      *(short4*)&sB[boff] = make_short4(hb[p * 4], hb[p * 4 + 1], hb[p * 4 + 2], hb[p * 4 + 3]);
      *(short4*)&sB[4096 + boff] = make_short4(lb[p * 4], lb[p * 4 + 1], lb[p * 4 + 2], lb[p * 4 + 3]);
    }
    __syncthreads();
    if (ks < 31) {
      const float4* ah4 = (const float4*)(Ahi + atile + (ks + 1) * 4096);
      const float4* al4 = (const float4*)(Alo + atile + (ks + 1) * 4096);
      a0 = ah4[tid]; a1 = ah4[tid + 256];
      a2 = al4[tid]; a3 = al4[tid + 256];
      const int k0n = (ks + 1) * 32;
#pragma unroll
      for (int p = 0; p < 4; ++p)
#pragma unroll
        for (int i = 0; i < 4; ++i)
          bfv[p * 4 + i] = wbase[(size_t)(k0n + p * 8 + half * 4 + i) * D_SAE];
    }
    bf16x8 ahf[4], alf[4];
#pragma unroll
    for (int fm = 0; fm < 4; ++fm) {
      int off = (kcl * 128 + wm + fm * 16 + l15) * 8;
      ahf[fm] = *(const bf16x8*)&sA[off];
      alf[fm] = *(const bf16x8*)&sA[4096 + off];
    }
#pragma unroll
    for (int fn = 0; fn < 4; ++fn) {
      int boff = (kcl * 128 + wn + fn * 16 + l15) * 8;
      bf16x8 bh = *(const bf16x8*)&sB[boff];
      bf16x8 bl = *(const bf16x8*)&sB[4096 + boff];
#pragma unroll
      for (int fm = 0; fm < 4; ++fm) {
        acc[fm][fn] = __builtin_amdgcn_mfma_f32_16x16x32_bf16(ahf[fm], bh, acc[fm][fn], 0, 0, 0);
        acc[fm][fn] = __builtin_amdgcn_mfma_f32_16x16x32_bf16(alf[fm], bh, acc[fm][fn], 0, 0, 0);
        acc[fm][fn] = __builtin_amdgcn_mfma_f32_16x16x32_bf16(ahf[fm], bl, acc[fm][fn], 0, 0, 0);
      }
    }
  }
  const int l4r = lane >> 4;
  if (MODE == 0) {
#pragma unroll
    for (int fn = 0; fn < 4; ++fn) {
      int col = col0 + wn + fn * 16 + l15;
      float g = g32[col], be = benc[col];
#pragma unroll
      for (int fm = 0; fm < 4; ++fm) {
#pragma unroll
        for (int r = 0; r < 4; ++r) {
          float z = acc[fm][fn][r] + be;
          float s = z > 0.f ? z * g : 0.f;
          unsigned bits = __float_as_uint(s);
          if (bits) atomicAdd(&h[bits >> 21], 1);
        }
      }
    }
    __syncthreads();
    for (int i = tid; i < 2048; i += 256)
      if (h[i]) atomicAdd(&ghist[i], h[i]);
  } else {
    unsigned thrBits = (unsigned)ctrl[1];
    int cnt = 0;
#pragma unroll
    for (int fn = 0; fn < 4; ++fn) {
      int col = col0 + wn + fn * 16 + l15;
      float g = g32[col], be = benc[col];
#pragma unroll
      for (int fm = 0; fm < 4; ++fm) {
#pragma unroll
        for (int r = 0; r < 4; ++r) {
          float z = acc[fm][fn][r] + be;
          float s = z > 0.f ? z * g : 0.f;
          cnt += (__float_as_uint(s) >= thrBits) ? 1 : 0;
        }
      }
    }
    int my = 0;
    if (cnt) my = atomicAdd(&h[0], cnt);
    __syncthreads();
    if (tid == 0) h[1] = atomicAdd(&ctrl[2], h[0]);
    __syncthreads();
    int pos = h[1] + my;
#pragma unroll
    for (int fn = 0; fn < 4; ++fn) {
      int col = col0 + wn + fn * 16 + l15;
      float g = g32[col], be = benc[col];
#pragma unroll
      for (int fm = 0; fm < 4; ++fm) {
        int rowb = row0 + wm + fm * 16 + l4r * 4;
#pragma unroll
        for (int r = 0; r < 4; ++r) {
          float z = acc[fm][fn][r] + be;
          float s = z > 0.f ? z * g : 0.f;
          if (__float_as_uint(s) >= thrBits) {
            if (pos < CAND_CAP) { cand_idx[pos] = (rowb + r) * D_SAE + col; cand_sc[pos] = s; }
            pos++;
          }
        }
      }
    }
  }
}

// ---------- coarse threshold (64-thread parallel scan) ----------
__global__ void find_coarse_kernel(const int* __restrict__ gh, int* ctrl,
                                   const int* __restrict__ kptr, int sub) {
  long long kB = (long long)kptr[0] * BATCH;
  long long needl = (kB + 500000 + sub - 1) / sub;
  long long fl = 720000 / sub;
  if (needl < fl) needl = fl;
  int b, cum;
  hist_scan_desc(gh, 2048, (int)needl, b, cum);
  if (threadIdx.x == 0) {
    long long est_incl = (long long)sub * (cum + gh[b]);
    if (est_incl > 3500000LL && (long long)sub * cum >= kB + 120000LL) b = b + 1;
    ctrl[1] = (int)(((unsigned)b) << 21);
  }
}

// ---------- radix histograms over candidate scores (passes 1,2) ----------
__global__ __launch_bounds__(256) void chist_kernel(const float* __restrict__ cand_sc,
                                                    const int* __restrict__ ctrl,
                                                    int* __restrict__ ghist, int pass) {
  __shared__ int h[2048];
  int nb = (pass == 2) ? 1024 : 2048;
  for (int i = threadIdx.x; i < nb; i += 256) h[i] = 0;
  __syncthreads();
  int n = ctrl[2]; if (n > CAND_CAP) n = CAND_CAP;
  unsigned sel1 = 0, sel22 = 0;
  if (pass == 1) sel1 = (unsigned)ctrl[3];
  if (pass == 2) sel22 = ((unsigned)ctrl[3] << 11) | (unsigned)ctrl[5];
  for (int i = blockIdx.x * 256 + threadIdx.x; i < n; i += gridDim.x * 256) {
    unsigned bits = __float_as_uint(cand_sc[i]);
    if (pass == 0) atomicAdd(&h[bits >> 21], 1);
    else if (pass == 1) { if ((bits >> 21) == sel1) atomicAdd(&h[(bits >> 10) & 0x7FFu], 1); }
    else { if ((bits >> 10) == sel22) atomicAdd(&h[bits & 0x3FFu], 1); }
  }
  __syncthreads();
  for (int i = threadIdx.x; i < nb; i += 256)
    if (h[i]) atomicAdd(&ghist[i], h[i]);
}

// ---------- radix select step (64-thread parallel scan) ----------
__global__ void cfind_kernel(const int* __restrict__ hist, int* ctrl,
                             const int* __restrict__ kptr, int pass) {
  int kB = kptr[0] * BATCH;
  int need, nbins;
  if (pass == 0)      { need = kB;                       nbins = 2048; }
  else if (pass == 1) { need = kB - ctrl[4];             nbins = 2048; }
  else                { need = kB - ctrl[4] - ctrl[6];   nbins = 1024; }
  int b, cum;
  hist_scan_desc(hist, nbins, need, b, cum);
  if (threadIdx.x == 0) {
    if (pass == 0)      { ctrl[3] = b; ctrl[4] = cum; }
    else if (pass == 1) { ctrl[5] = b; ctrl[6] = cum; }
    else {
      unsigned vbits = ((unsigned)ctrl[3] << 21) | ((unsigned)ctrl[5] << 10) | (unsigned)b;
      float V = __uint_as_float(vbits);
      float* cf = (float*)ctrl;
      cf[8] = V; cf[9] = V + EPS_M; cf[10] = V - EPS_M;
    }
  }
}

// ---------- band partition ----------
__global__ __launch_bounds__(256) void band_kernel(const int* __restrict__ cand_idx,
    const float* __restrict__ cand_sc, const float* __restrict__ g32,
    int* ctrl, int* row_cnt, int* row_feat, float* row_act, int* cand2_idx) {
  const float* cf = (const float*)ctrl;
  float hi = cf[9], lo = cf[10];
  int n = ctrl[2]; if (n > CAND_CAP) n = CAND_CAP;
  int lane = threadIdx.x & 63;
  int defc = 0;
  for (int i = blockIdx.x * 256 + threadIdx.x; i < n; i += gridDim.x * 256) {
    float s = cand_sc[i];
    int flat = cand_idx[i];
    if (s > hi) {
      int b = flat >> 14, j = flat & (D_SAE - 1);
      int p = atomicAdd(&row_cnt[b], 1);
      if (p < ROW_CAP) { row_feat[b * ROW_CAP + p] = j; row_act[b * ROW_CAP + p] = s / g32[j]; }
      defc++;
    }
    bool isc = (s <= hi) && (s >= lo);
    int pos = wave_append(isc, &ctrl[12]);
    if (isc && pos >= 0 && pos < CAND2_CAP) cand2_idx[pos] = flat;
  }
#pragma unroll
  for (int off = 32; off > 0; off >>= 1) defc += __shfl_down(defc, off, 64);
  if (lane == 0 && defc) atomicAdd(&ctrl[11], defc);
}

// ---------- fp64 rescore of band candidates ----------
__global__ __launch_bounds__(256) void cand2_score_kernel(const int* __restrict__ ctrl,
    const int* __restrict__ cand2_idx, const float* __restrict__ x,
    const float* __restrict__ Wdec, const float* __restrict__ benc,
    const double* __restrict__ g64, double* __restrict__ cand2_sc) {
  __shared__ double lds[4];
  int n2 = ctrl[12]; if (n2 > CAND2_CAP) n2 = CAND2_CAP;
  int t = threadIdx.x;
  for (int c = blockIdx.x; c < n2; c += gridDim.x) {
    int flat = cand2_idx[c];
    int b = flat >> 14, j = flat & (D_SAE - 1);
    double d[4];
    ln_row_fp64(x + (size_t)b * (2 * D_MODEL), lds, d);
    float4 w4 = *(const float4*)(Wdec + (size_t)j * D_MODEL + t * 4);
    double a = d[0] * (double)w4.x + d[1] * (double)w4.y + d[2] * (double)w4.z + d[3] * (double)w4.w;
    double z = blockReduceSum256(a, lds) + (double)benc[j];
    double sc = z > 0 ? z * g64[j] : 0.0;
    if (t == 0) cand2_sc[c] = sc;
  }
}

// ---------- rank band candidates (fp64, index-stable), accept fill ----------
__global__ __launch_bounds__(256) void cand2_rank_kernel(const int* __restrict__ ctrl,
    const int* __restrict__ cand2_idx, const double* __restrict__ cand2_sc,
    const double* __restrict__ g64, const int* __restrict__ kptr,
    int* row_cnt, int* row_feat, float* row_act) {
  __shared__ int lds[4];
  int n2 = ctrl[12]; if (n2 > CAND2_CAP) n2 = CAND2_CAP;
  int kB = kptr[0] * BATCH;
  int fill = kB - ctrl[11];
  int t = threadIdx.x;
  for (int c = blockIdx.x; c < n2; c += gridDim.x) {
    double sc = cand2_sc[c];
    int fc = cand2_idx[c];
    int cnt = 0;
    for (int y = t; y < n2; y += 256) {
      double sy = cand2_sc[y];
      if (sy > sc || (sy == sc && cand2_idx[y] < fc)) cnt++;
    }
    cnt = blockReduceSumInt256(cnt, lds);
    if (t == 0 && cnt < fill) {
      int b = fc >> 14, j = fc & (D_SAE - 1);
      int p = atomicAdd(&row_cnt[b], 1);
      if (p < ROW_CAP) { row_feat[b * ROW_CAP + p] = j; row_act[b * ROW_CAP + p] = (float)(sc / g64[j]); }
    }
  }
}

// ---------- sparse recon, bf16-hi Wdec (big path) ----------
__global__ __launch_bounds__(256) void recon_bf16_kernel(const int* __restrict__ row_cnt,
    const int* __restrict__ row_feat, const float* __restrict__ row_act,
    const short* __restrict__ wdech, const float* __restrict__ bdec, float* __restrict__ out) {
  int b = blockIdx.x, t = threadIdx.x;
  float4 acc0 = *(const float4*)&bdec[t * 4];
  float4 acc1 = make_float4(0.f, 0.f, 0.f, 0.f);
  int n = row_cnt[b]; if (n > ROW_CAP) n = ROW_CAP;
  const int* rf = row_feat + (size_t)b * ROW_CAP;
  const float* ra = row_act + (size_t)b * ROW_CAP;
  int p = 0;
  for (; p + 2 <= n; p += 2) {
    int j0 = rf[p], j1 = rf[p + 1];
    float v0 = ra[p], v1 = ra[p + 1];
    short4 h0 = *(const short4*)&wdech[(size_t)j0 * D_MODEL + t * 4];
    short4 h1 = *(const short4*)&wdech[(size_t)j1 * D_MODEL + t * 4];
    acc0.x += v0 * bf2f((unsigned short)h0.x); acc0.y += v0 * bf2f((unsigned short)h0.y);
    acc0.z += v0 * bf2f((unsigned short)h0.z); acc0.w += v0 * bf2f((unsigned short)h0.w);
    acc1.x += v1 * bf2f((unsigned short)h1.x); acc1.y += v1 * bf2f((unsigned short)h1.y);
    acc1.z += v1 * bf2f((unsigned short)h1.z); acc1.w += v1 * bf2f((unsigned short)h1.w);
  }
  if (p < n) {
    int j0 = rf[p]; float v0 = ra[p];
    short4 h0 = *(const short4*)&wdech[(size_t)j0 * D_MODEL + t * 4];
    acc0.x += v0 * bf2f((unsigned short)h0.x); acc0.y += v0 * bf2f((unsigned short)h0.y);
    acc0.z += v0 * bf2f((unsigned short)h0.z); acc0.w += v0 * bf2f((unsigned short)h0.w);
  }
  acc0.x += acc1.x; acc0.y += acc1.y; acc0.z += acc1.z; acc0.w += acc1.w;
  *(float4*)(out + (size_t)b * D_MODEL + t * 4) = acc0;
}

// ---------- sparse recon fp32 (fallback path) ----------
__global__ __launch_bounds__(256) void recon_kernel(const int* __restrict__ row_cnt,
    const int* __restrict__ row_feat, const float* __restrict__ row_act,
    const float* __restrict__ Wdec, const float* __restrict__ bdec, float* __restrict__ out) {
  int b = blockIdx.x, t = threadIdx.x;
  float4 acc0 = *(const float4*)&bdec[t * 4];
  float4 acc1 = make_float4(0.f, 0.f, 0.f, 0.f);
  int n = row_cnt[b]; if (n > ROW_CAP) n = ROW_CAP;
  const int* rf = row_feat + (size_t)b * ROW_CAP;
  const float* ra = row_act + (size_t)b * ROW_CAP;
  int p = 0;
  for (; p + 2 <= n; p += 2) {
    int j0 = rf[p], j1 = rf[p + 1];
    float v0 = ra[p], v1 = ra[p + 1];
    float4 w0 = *(const float4*)(Wdec + (size_t)j0 * D_MODEL + t * 4);
    float4 w1 = *(const float4*)(Wdec + (size_t)j1 * D_MODEL + t * 4);
    acc0.x += v0 * w0.x; acc0.y += v0 * w0.y; acc0.z += v0 * w0.z; acc0.w += v0 * w0.w;
    acc1.x += v1 * w1.x; acc1.y += v1 * w1.y; acc1.z += v1 * w1.z; acc1.w += v1 * w1.w;
  }
  if (p < n) {
    int j0 = rf[p]; float v0 = ra[p];
    float4 w0 = *(const float4*)(Wdec + (size_t)j0 * D_MODEL + t * 4);
    acc0.x += v0 * w0.x; acc0.y += v0 * w0.y; acc0.z += v0 * w0.z; acc0.w += v0 * w0.w;
  }
  acc0.x += acc1.x; acc0.y += acc1.y; acc0.z += acc1.z; acc0.w += acc1.w;
  *(float4*)(out + (size_t)b * D_MODEL + t * 4) = acc0;
}

extern "C" void kernel_launch(void* const* d_in, const int* in_sizes, int n_in,
                              void* d_out, int out_size, void* d_ws, size_t ws_size,
                              hipStream_t stream) {
  const float* x    = (const float*)d_in[0];
  const float* Wenc = (const float*)d_in[1];
  const float* benc = (const float*)d_in[2];
  const float* Wdec = (const float*)d_in[3];
  const float* bdec = (const float*)d_in[4];
  const int*   kptr = (const int*)d_in[5];
  float* out = (float*)d_out;

  char* ws = (char*)d_ws;
  size_t off = 0;
  short*  Ahi       = (short*)(ws + off);  off += (size_t)BATCH * D_MODEL * 2;
  short*  Alo       = (short*)(ws + off);  off += (size_t)BATCH * D_MODEL * 2;
  int*    cand_idx  = (int*)(ws + off);    off += (size_t)CAND_CAP * 4;
  float*  cand_sc   = (float*)(ws + off);  off += (size_t)CAND_CAP * 4;
  int*    row_feat  = (int*)(ws + off);    off += (size_t)BATCH * ROW_CAP * 4;
  float*  row_act   = (float*)(ws + off);  off += (size_t)BATCH * ROW_CAP * 4;
  int*    cand2_idx = (int*)(ws + off);    off += (size_t)CAND2_CAP * 4;
  double* cand2_sc  = (double*)(ws + off); off += (size_t)CAND2_CAP * 8;
  double* g64       = (double*)(ws + off); off += (size_t)D_SAE * 8;
  float*  g32       = (float*)(ws + off);  off += (size_t)D_SAE * 4;
  char*   zbase     = ws + off;
  int* ghist   = (int*)(zbase);
  int* h1      = (int*)(zbase + 8192);
  int* h2      = (int*)(zbase + 16384);
  int* h3      = (int*)(zbase + 24576);
  int* ctrl    = (int*)(zbase + 28672);
  int* row_cnt = (int*)(zbase + 28928);
  size_t zbytes = 28928 + (size_t)BATCH * 4;
  size_t small_need = off + zbytes;
  if (small_need > ws_size) return;  // ~60 MB floor

  size_t big_off = (small_need + 255) & ~(size_t)255;
  short* Whi = (short*)(ws + big_off);
  short* Wlo = Whi + (size_t)D_MODEL * D_SAE;
  size_t big_need = big_off + (size_t)D_MODEL * D_SAE * 4;
  const bool big = (big_need <= ws_size);   // round-6..16-proven to fit

  // bf16 Wdec for recon aliases the (dead-after-band) cand_idx+cand_sc region:
  // needs D_MODEL*D_SAE*2 = 33,554,432 B; region is CAND_CAP*8 = 33,554,432 B. Exact fit.
  short* wdech = (short*)cand_idx;

  hipMemsetAsync(zbase, 0, zbytes, stream);

  ln_kernel<<<BATCH / 4, 256, 0, stream>>>(x, Ahi, Alo);
  norm_kernel<<<D_SAE / 4, 256, 0, stream>>>(Wdec, g64, g32);
  if (big) {
    wsplit_kernel<<<4096, 256, 0, stream>>>(Wenc, Whi, Wlo);
    hist_gemm<<<256, 256, 0, stream>>>(Whi, Ahi, benc, g32, ghist);
    find_coarse_kernel<<<1, 64, 0, stream>>>(ghist, ctrl, kptr, 16);
    extract_gemm128<<<4096, 256, 0, stream>>>(Whi, Wlo, Ahi, Alo, benc, g32, ctrl, cand_idx, cand_sc, h1);
  } else {
    mfma_gemm<0><<<256, 256, 0, stream>>>(Wenc, Ahi, Alo, benc, g32, ghist, ctrl, nullptr, nullptr);
    find_coarse_kernel<<<1, 64, 0, stream>>>(ghist, ctrl, kptr, 16);
    mfma_gemm<1><<<4096, 256, 0, stream>>>(Wenc, Ahi, Alo, benc, g32, nullptr, ctrl, cand_idx, cand_sc);
    chist_kernel<<<1024, 256, 0, stream>>>(cand_sc, ctrl, h1, 0);
  }
  cfind_kernel<<<1, 64, 0, stream>>>(h1, ctrl, kptr, 0);
  chist_kernel<<<1024, 256, 0, stream>>>(cand_sc, ctrl, h2, 1);
  cfind_kernel<<<1, 64, 0, stream>>>(h2, ctrl, kptr, 1);
  chist_kernel<<<1024, 256, 0, stream>>>(cand_sc, ctrl, h3, 2);
  cfind_kernel<<<1, 64, 0, stream>>>(h3, ctrl, kptr, 2);
  band_kernel<<<1024, 256, 0, stream>>>(cand_idx, cand_sc, g32, ctrl, row_cnt, row_feat, row_act, cand2_idx);
  cand2_score_kernel<<<4096, 256, 0, stream>>>(ctrl, cand2_idx, x, Wdec, benc, g64, cand2_sc);
  cand2_rank_kernel<<<2048, 256, 0, stream>>>(ctrl, cand2_idx, cand2_sc, g64, kptr, row_cnt, row_feat, row_act);
  if (big) {
    // cand_idx/cand_sc are dead now; overwrite with row-major bf16 Wdec
    wdecsplit_kernel<<<D_SAE, 256, 0, stream>>>(Wdec, wdech);
    recon_bf16_kernel<<<BATCH, 256, 0, stream>>>(row_cnt, row_feat, row_act, wdech, bdec, out);
  } else {
    recon_kernel<<<BATCH, 256, 0, stream>>>(row_cnt, row_feat, row_act, Wdec, bdec, out);
  }
}

// Round 18
// 675.964 us; speedup vs baseline: 1.2488x; 1.0114x over previous
//
#include <hip/hip_runtime.h>
#include <math.h>

#define D_MODEL 1024
#define D_SAE   16384
#define BATCH   4096
#define NTOT    (1ull * BATCH * D_SAE)
#define LN_EPS  1e-8
#define EPS_M   3e-4f        // |split-bf16 score - fp64 score| safe band half-width (>=6x margin)
#define ROW_CAP 256
#define CAND_CAP  (4 * 1024 * 1024)
#define CAND2_CAP 65536

using bf16x8 = __attribute__((ext_vector_type(8))) short;
using f32x4  = __attribute__((ext_vector_type(4))) float;

__device__ inline unsigned short f2bf(float f) {   // RNE fp32->bf16
  unsigned u = __float_as_uint(f);
  return (unsigned short)((u + 0x7fffu + ((u >> 16) & 1u)) >> 16);
}
__device__ inline float bf2f(unsigned short h) {
  return __uint_as_float((unsigned)h << 16);
}

// ---------- block (256-thread) reductions ----------
__device__ inline double blockReduceSum256(double v, double* lds) {
#pragma unroll
  for (int off = 32; off > 0; off >>= 1) v += __shfl_down(v, off, 64);
  int lane = threadIdx.x & 63, wid = threadIdx.x >> 6;
  __syncthreads();
  if (lane == 0) lds[wid] = v;
  __syncthreads();
  return lds[0] + lds[1] + lds[2] + lds[3];
}
__device__ inline int blockReduceSumInt256(int v, int* lds) {
#pragma unroll
  for (int off = 32; off > 0; off >>= 1) v += __shfl_down(v, off, 64);
  int lane = threadIdx.x & 63, wid = threadIdx.x >> 6;
  __syncthreads();
  if (lane == 0) lds[wid] = v;
  __syncthreads();
  return lds[0] + lds[1] + lds[2] + lds[3];
}

__device__ inline int wave_append(bool pred, int* counter) {
  unsigned long long m = __ballot(pred);
  int lane = threadIdx.x & 63;
  int pos = -1;
  if (m) {
    int ldr = __ffsll((long long)m) - 1;
    int base = 0;
    if (lane == ldr) base = atomicAdd(counter, __popcll(m));
    base = __shfl(base, ldr, 64);
    if (pred) pos = base + __popcll(m & ((1ull << lane) - 1ull));
  }
  return pos;
}

// ---------- 64-lane parallel descending histogram scan ----------
__device__ inline void hist_scan_desc(const int* __restrict__ hist, int nbins, int need,
                                      int& bsel, int& cumsel) {
  int t = threadIdx.x;          // 0..63
  int chunk = nbins >> 6;
  int topbase = nbins - t * chunk;
  int psum = 0;
  for (int i = 1; i <= chunk; ++i) psum += hist[topbase - i];
  int incl = psum;
#pragma unroll
  for (int off = 1; off < 64; off <<= 1) {
    int v = __shfl_up(incl, off, 64);
    if (t >= off) incl += v;
  }
  int excl = incl - psum;
  bool hit = (excl < need) && (excl + psum >= need);
  unsigned long long m = __ballot(hit);
  int tb = m ? (__ffsll((long long)m) - 1) : 63;
  int exb = __shfl(excl, tb, 64);
  int res_b = 0, res_c = 0;
  if (t == tb) {
    int c = exb;
    int b = nbins - tb * chunk - 1;
    int bend = b - chunk;
    for (; b > 0 && b > bend; --b) {
      int cc = hist[b];
      if (c + cc >= need) break;
      c += cc;
    }
    res_b = b; res_c = c;
  }
  bsel = __shfl(res_b, tb, 64);
  cumsel = __shfl(res_c, tb, 64);
}

// ---------- per-thread fp64 LN chain (256-thr block version, used by cand2) ----------
__device__ inline void ln_row_fp64(const float* __restrict__ row, double* lds, double d[4]) {
  int t = threadIdx.x;
  float4 s4 = *(const float4*)(row + t * 4);
  float4 t4 = *(const float4*)(row + D_MODEL + t * 4);
  double s[4] = {s4.x, s4.y, s4.z, s4.w};
  double tt[4] = {t4.x, t4.y, t4.z, t4.w};
  double ms = blockReduceSum256(s[0] + s[1] + s[2] + s[3], lds) / D_MODEL;
  double mt = blockReduceSum256(tt[0] + tt[1] + tt[2] + tt[3], lds) / D_MODEL;
  double vs = 0, vt = 0;
#pragma unroll
  for (int i = 0; i < 4; i++) { double a = s[i] - ms; vs += a * a; a = tt[i] - mt; vt += a * a; }
  vs = blockReduceSum256(vs, lds) / D_MODEL;
  vt = blockReduceSum256(vt, lds) / D_MODEL;
  double rs = sqrt(vs + LN_EPS), rt = sqrt(vt + LN_EPS);
  double u[4];
#pragma unroll
  for (int i = 0; i < 4; i++) u[i] = (tt[i] - mt) / rt - (s[i] - ms) / rs;
  double mu = blockReduceSum256(u[0] + u[1] + u[2] + u[3], lds) / D_MODEL;
  double vu = 0;
#pragma unroll
  for (int i = 0; i < 4; i++) { double a = u[i] - mu; vu += a * a; }
  vu = blockReduceSum256(vu, lds) / D_MODEL;
  double ru = sqrt(vu + LN_EPS);
#pragma unroll
  for (int i = 0; i < 4; i++) d[i] = (u[i] - mu) / ru;
}

// ---------- LN -> split-bf16 A, wave-per-row (no barriers), tiled layout ----------
__global__ __launch_bounds__(256) void ln_kernel(const float* __restrict__ x,
                                                 short* __restrict__ Ahi, short* __restrict__ Alo) {
  int wv = threadIdx.x >> 6, lane = threadIdx.x & 63;
  int b = (blockIdx.x << 2) | wv;
  const float* row = x + (size_t)b * (2 * D_MODEL);
  float s[16], t[16];
  const float4* s4p = (const float4*)(row + lane * 16);
  const float4* t4p = (const float4*)(row + D_MODEL + lane * 16);
  double sum_s = 0, sum_t = 0;
#pragma unroll
  for (int q = 0; q < 4; ++q) {
    float4 a = s4p[q], c = t4p[q];
    s[q * 4 + 0] = a.x; s[q * 4 + 1] = a.y; s[q * 4 + 2] = a.z; s[q * 4 + 3] = a.w;
    t[q * 4 + 0] = c.x; t[q * 4 + 1] = c.y; t[q * 4 + 2] = c.z; t[q * 4 + 3] = c.w;
  }
#pragma unroll
  for (int i = 0; i < 16; ++i) { sum_s += s[i]; sum_t += t[i]; }
#pragma unroll
  for (int off = 1; off < 64; off <<= 1) {
    sum_s += __shfl_xor(sum_s, off, 64);
    sum_t += __shfl_xor(sum_t, off, 64);
  }
  double ms = sum_s / D_MODEL, mt_ = sum_t / D_MODEL;
  double vs = 0, vt = 0;
#pragma unroll
  for (int i = 0; i < 16; ++i) {
    double a = s[i] - ms; vs += a * a;
    double c = t[i] - mt_; vt += c * c;
  }
#pragma unroll
  for (int off = 1; off < 64; off <<= 1) {
    vs += __shfl_xor(vs, off, 64);
    vt += __shfl_xor(vt, off, 64);
  }
  double rs = sqrt(vs / D_MODEL + LN_EPS), rt = sqrt(vt / D_MODEL + LN_EPS);
  double u[16], su = 0;
#pragma unroll
  for (int i = 0; i < 16; ++i) { u[i] = (t[i] - mt_) / rt - (s[i] - ms) / rs; su += u[i]; }
#pragma unroll
  for (int off = 1; off < 64; off <<= 1) su += __shfl_xor(su, off, 64);
  double mu = su / D_MODEL, vu = 0;
#pragma unroll
  for (int i = 0; i < 16; ++i) { double a = u[i] - mu; vu += a * a; }
#pragma unroll
  for (int off = 1; off < 64; off <<= 1) vu += __shfl_xor(vu, off, 64);
  double ru = sqrt(vu / D_MODEL + LN_EPS);
  int mtb = b >> 7, ml = b & 127;
#pragma unroll
  for (int blk8 = 0; blk8 < 2; ++blk8) {
    short h8[8], l8[8];
#pragma unroll
    for (int e = 0; e < 8; ++e) {
      int i = blk8 * 8 + e;
      double dd = (u[i] - mu) / ru;
      float f = (float)dd;
      unsigned short hh = f2bf(f);
      h8[e] = (short)hh;
      l8[e] = (short)f2bf(f - bf2f(hh));
    }
    int gi = lane * 16 + blk8 * 8;
    int ks = gi >> 5, kc = (gi >> 3) & 3;
    size_t base = ((((size_t)mtb * 32 + ks) * 4 + kc) * 128 + ml) * 8;
    *(float4*)&Ahi[base] = *(float4*)h8;
    *(float4*)&Alo[base] = *(float4*)l8;
  }
}

// ---------- dec_norms in fp64 (wave-per-feature, no block syncs) ----------
__global__ __launch_bounds__(256) void norm_kernel(const float* __restrict__ Wdec,
                                                   double* __restrict__ g64, float* __restrict__ g32) {
  int wv = threadIdx.x >> 6, lane = threadIdx.x & 63;
  int j = (blockIdx.x << 2) | wv;
  const float4* rowp = (const float4*)(Wdec + (size_t)j * D_MODEL);
  double a = 0;
#pragma unroll
  for (int q = 0; q < 4; ++q) {
    float4 w = rowp[lane + q * 64];
    a += (double)w.x * w.x + (double)w.y * w.y + (double)w.z * w.z + (double)w.w * w.w;
  }
#pragma unroll
  for (int off = 32; off > 0; off >>= 1) a += __shfl_down(a, off, 64);
  if (lane == 0) { double g = sqrt(a); g64[j] = g; g32[j] = (float)g; }
}

// ---------- pre-split W_enc fp32 -> tiled bf16 hi/lo [nt][ks][kc][c][e] ----------
__global__ __launch_bounds__(256) void wsplit_kernel(const float* __restrict__ Wenc,
                                                     short* __restrict__ Whi, short* __restrict__ Wlo) {
  __shared__ short sh[4096];
  __shared__ short sl[4096];
  int blk = blockIdx.x;            // 4096 = 128 nt * 32 ks
  int nt = blk >> 5, ks = blk & 31;
  int t = threadIdx.x;
  int r = t >> 3;
  int cg = t & 7;
  int kc = r >> 3, e = r & 7;
  const float* src = Wenc + (size_t)(ks * 32 + r) * D_SAE + nt * 128 + cg;
#pragma unroll
  for (int j = 0; j < 16; ++j) {
    float f = src[j * 8];
    unsigned short hh = f2bf(f);
    short ll = (short)f2bf(f - bf2f(hh));
    int c = j * 8 + cg;
    sh[kc * 1024 + c * 8 + e] = (short)hh;
    sl[kc * 1024 + c * 8 + e] = ll;
  }
  __syncthreads();
  size_t obase = ((size_t)nt * 32 + ks) * 4096;
  *(float4*)&Whi[obase + t * 16]     = *(const float4*)&sh[t * 16];
  *(float4*)&Whi[obase + t * 16 + 8] = *(const float4*)&sh[t * 16 + 8];
  *(float4*)&Wlo[obase + t * 16]     = *(const float4*)&sl[t * 16];
  *(float4*)&Wlo[obase + t * 16 + 8] = *(const float4*)&sl[t * 16 + 8];
}

// ---------- Wdec fp32 -> row-major bf16 (for recon), into dead cand region ----------
__global__ __launch_bounds__(256) void wdecsplit_kernel(const float* __restrict__ Wdec,
                                                        short* __restrict__ wdech) {
  int j = blockIdx.x, t = threadIdx.x;
  float4 w = *(const float4*)(Wdec + (size_t)j * D_MODEL + t * 4);
  short4 h;
  h.x = (short)f2bf(w.x); h.y = (short)f2bf(w.y);
  h.z = (short)f2bf(w.z); h.w = (short)f2bf(w.w);
  *(short4*)&wdech[(size_t)j * D_MODEL + t * 4] = h;
}

// ---------- hi-only 1/16-subsampled hist GEMM: per-wave privatized hist ----------
__global__ __launch_bounds__(256) void hist_gemm(
    const short* __restrict__ Whi, const short* __restrict__ Ahi,
    const float* __restrict__ benc, const float* __restrict__ g32,
    int* __restrict__ ghist) {
  __shared__ short sA[4096];
  __shared__ short sB[4096];
  __shared__ int h[4][2048];
  const int tid = threadIdx.x;
  const int lane = tid & 63;
  const int w = tid >> 6;
  const int wm = (w >> 1) * 64, wn = (w & 1) * 64;
  int lin = blockIdx.x;            // 256 = 2 mt * 128 nt
  int mt = lin >> 7, nt = lin & 127;
  const int col0 = nt * 128;
  for (int i = tid; i < 8192; i += 256) ((int*)h)[i] = 0;
  const size_t atile = (size_t)mt * 131072;
  const size_t btile = (size_t)nt * 131072;
  f32x4 acc[4][4] = {};
  const int kcl = lane >> 4, l15 = lane & 15;

  float4 a0, a1, b0, b1;
  {
    const float4* ah4 = (const float4*)(Ahi + atile);
    const float4* bh4 = (const float4*)(Whi + btile);
    a0 = ah4[tid]; a1 = ah4[tid + 256];
    b0 = bh4[tid]; b1 = bh4[tid + 256];
  }
  for (int ks = 0; ks < 32; ++ks) {
    __syncthreads();
    *(float4*)&sA[(size_t)tid * 8] = a0;
    *(float4*)&sA[(size_t)(tid + 256) * 8] = a1;
    *(float4*)&sB[(size_t)tid * 8] = b0;
    *(float4*)&sB[(size_t)(tid + 256) * 8] = b1;
    __syncthreads();
    if (ks < 31) {
      const float4* ah4 = (const float4*)(Ahi + atile + (ks + 1) * 4096);
      const float4* bh4 = (const float4*)(Whi + btile + (ks + 1) * 4096);
      a0 = ah4[tid]; a1 = ah4[tid + 256];
      b0 = bh4[tid]; b1 = bh4[tid + 256];
    }
    bf16x8 ahf[4];
#pragma unroll
    for (int fm = 0; fm < 4; ++fm)
      ahf[fm] = *(const bf16x8*)&sA[(kcl * 128 + wm + fm * 16 + l15) * 8];
#pragma unroll
    for (int fn = 0; fn < 4; ++fn) {
      bf16x8 bh = *(const bf16x8*)&sB[(kcl * 128 + wn + fn * 16 + l15) * 8];
#pragma unroll
      for (int fm = 0; fm < 4; ++fm)
        acc[fm][fn] = __builtin_amdgcn_mfma_f32_16x16x32_bf16(ahf[fm], bh, acc[fm][fn], 0, 0, 0);
    }
  }
#pragma unroll
  for (int fn = 0; fn < 4; ++fn) {
    int col = col0 + wn + fn * 16 + l15;
    float g = g32[col], be = benc[col];
#pragma unroll
    for (int fm = 0; fm < 4; ++fm) {
#pragma unroll
      for (int r = 0; r < 4; ++r) {
        float z = acc[fm][fn][r] + be;
        float s = z > 0.f ? z * g : 0.f;
        unsigned bits = __float_as_uint(s);
        if (bits) atomicAdd(&h[w][bits >> 21], 1);
      }
    }
  }
  __syncthreads();
  for (int i = tid; i < 2048; i += 256) {
    int v = h[0][i] + h[1][i] + h[2][i] + h[3][i];
    if (v) atomicAdd(&ghist[i], v);
  }
}

// ---------- 128x128 split-bf16 MFMA extract GEMM ----------
// A fragments loaded DIRECT from L2-resident tiled global (no LDS for A).
// B double-buffered in LDS, ONE barrier per K-step. Hist aliased into sB.
// XCD owns 4 mt A-tiles; B streams in nt order. 3 blocks/CU pinned.
__global__ __launch_bounds__(256, 3) void extract_gemm128(
    const short* __restrict__ Whi, const short* __restrict__ Wlo,
    const short* __restrict__ Ahi, const short* __restrict__ Alo,
    const float* __restrict__ benc, const float* __restrict__ g32,
    int* __restrict__ ctrl, int* __restrict__ cand_idx, float* __restrict__ cand_sc,
    int* __restrict__ ghist) {
  __shared__ short sB[2][8192];   // dbuf: hi [4][128][8] | lo at +4096

  const int tid = threadIdx.x;
  const int lane = tid & 63;
  const int w = tid >> 6;
  const int wm = (w >> 1) * 64, wn = (w & 1) * 64;

  // A-resident partition: XCD owns mt in [4*xcd, 4*xcd+4); B streams in nt order.
  int lin = blockIdx.x;
  int xcd = lin & 7, j = lin >> 3;
  int mt = (xcd << 2) | (j & 3);
  int nt = j >> 2;
  const int row0 = mt * 128, col0 = nt * 128;

  const size_t atile = (size_t)mt * 131072;
  const size_t btile = (size_t)nt * 131072;

  f32x4 acc[4][4] = {};
  const int kcl = lane >> 4, l15 = lane & 15;

  // B stage regs (tile ks+1 in flight)
  float4 b0, b1, b2, b3;
  {
    const float4* bh4 = (const float4*)(Whi + btile);
    const float4* bl4 = (const float4*)(Wlo + btile);
    b0 = bh4[tid]; b1 = bh4[tid + 256];
    b2 = bl4[tid]; b3 = bl4[tid + 256];
  }
  *(float4*)&sB[0][(size_t)tid * 8] = b0;
  *(float4*)&sB[0][(size_t)(tid + 256) * 8] = b1;
  *(float4*)&sB[0][(size_t)(512 + tid) * 8] = b2;
  *(float4*)&sB[0][(size_t)(512 + tid + 256) * 8] = b3;
  __syncthreads();
  int cur = 0;

  // per-lane A fragment base offset (within a [4][128][8] K-slab)
  const int afrag = kcl * 1024 + (wm + l15) * 8;   // + fm*128 shorts

  for (int ks = 0; ks < 32; ++ks) {
    if (ks < 31) {             // issue next B tile loads (fly under MFMA)
      const int o = (ks + 1) * 4096;
      const float4* bh4 = (const float4*)(Whi + btile + o);
      const float4* bl4 = (const float4*)(Wlo + btile + o);
      b0 = bh4[tid]; b1 = bh4[tid + 256];
      b2 = bl4[tid]; b3 = bl4[tid + 256];
    }
    // A fragments direct from global (L2-resident slice)
    const short* ah = Ahi + atile + (size_t)ks * 4096 + afrag;
    const short* al = Alo + atile + (size_t)ks * 4096 + afrag;
    bf16x8 ahf[4], alf[4];
#pragma unroll
    for (int fm = 0; fm < 4; ++fm) {
      ahf[fm] = *(const bf16x8*)&ah[fm * 128];
      alf[fm] = *(const bf16x8*)&al[fm * 128];
    }
    const short* tB = sB[cur];
    bf16x8 bh[4], bl[4];
#pragma unroll
    for (int fn = 0; fn < 4; ++fn) {
      int boff = (kcl * 128 + wn + fn * 16 + l15) * 8;
      bh[fn] = *(const bf16x8*)&tB[boff];
      bl[fn] = *(const bf16x8*)&tB[4096 + boff];
    }
#pragma unroll
    for (int fn = 0; fn < 4; ++fn) {
#pragma unroll
      for (int fm = 0; fm < 4; ++fm) {
        acc[fm][fn] = __builtin_amdgcn_mfma_f32_16x16x32_bf16(ahf[fm], bh[fn], acc[fm][fn], 0, 0, 0);
        acc[fm][fn] = __builtin_amdgcn_mfma_f32_16x16x32_bf16(alf[fm], bh[fn], acc[fm][fn], 0, 0, 0);
        acc[fm][fn] = __builtin_amdgcn_mfma_f32_16x16x32_bf16(ahf[fm], bl[fn], acc[fm][fn], 0, 0, 0);
      }
    }
    if (ks < 31) {             // write next tile into the OTHER buffer (disjoint)
      short* nB = sB[cur ^ 1];
      *(float4*)&nB[(size_t)tid * 8] = b0;
      *(float4*)&nB[(size_t)(tid + 256) * 8] = b1;
      *(float4*)&nB[(size_t)(512 + tid) * 8] = b2;
      *(float4*)&nB[(size_t)(512 + tid + 256) * 8] = b3;
    }
    __syncthreads();           // writes to cur^1 visible; reads of cur done
    cur ^= 1;
  }

  // epilogue: alias hist into sB (dead after K-loop). hh[0..2047]=hist,
  // hh[2048]=block count, hh[2049]=global base.
  int* hh = (int*)sB;
  const int l4r = lane >> 4;
  unsigned thrBits = (unsigned)ctrl[1];
  for (int i = tid; i < 2050; i += 256) hh[i] = 0;
  __syncthreads();
  int cnt = 0;
#pragma unroll
  for (int fn = 0; fn < 4; ++fn) {
    int col = col0 + wn + fn * 16 + l15;
    float g = g32[col], be = benc[col];
#pragma unroll
    for (int fm = 0; fm < 4; ++fm) {
#pragma unroll
      for (int r = 0; r < 4; ++r) {
        float z = acc[fm][fn][r] + be;
        float s = z > 0.f ? z * g : 0.f;
        unsigned bits = __float_as_uint(s);
        if (bits >= thrBits) { cnt++; atomicAdd(&hh[bits >> 21], 1); }
      }
    }
  }
  int my = 0;
  if (cnt) my = atomicAdd(&hh[2048], cnt);
  __syncthreads();
  if (tid == 0) hh[2049] = atomicAdd(&ctrl[2], hh[2048]);
  for (int i = tid; i < 2048; i += 256)
    if (hh[i]) atomicAdd(&ghist[i], hh[i]);
  __syncthreads();
  int pos = hh[2049] + my;
#pragma unroll
  for (int fn = 0; fn < 4; ++fn) {
    int col = col0 + wn + fn * 16 + l15;
    float g = g32[col], be = benc[col];
#pragma unroll
    for (int fm = 0; fm < 4; ++fm) {
      int rowb = row0 + wm + fm * 16 + l4r * 4;
#pragma unroll
      for (int r = 0; r < 4; ++r) {
        float z = acc[fm][fn][r] + be;
        float s = z > 0.f ? z * g : 0.f;
        if (__float_as_uint(s) >= thrBits) {
          if (pos < CAND_CAP) { cand_idx[pos] = (rowb + r) * D_SAE + col; cand_sc[pos] = s; }
          pos++;
        }
      }
    }
  }
}

// ---------- fallback 128^2 GEMM (small ws): MODE 0 = hist (1/16), MODE 1 = extract ----------
template <int MODE>
__global__ __launch_bounds__(256) void mfma_gemm(
    const float* __restrict__ Wenc,
    const short* __restrict__ Ahi, const short* __restrict__ Alo,
    const float* __restrict__ benc, const float* __restrict__ g32,
    int* __restrict__ ghist, int* __restrict__ ctrl,
    int* __restrict__ cand_idx, float* __restrict__ cand_sc) {
  __shared__ short sA[8192];
  __shared__ short sB[8192];
  __shared__ int h[(MODE == 0) ? 2048 : 2];
  const int tid = threadIdx.x;
  const int lane = tid & 63;
  const int w = tid >> 6;
  const int wm = (w >> 1) * 64, wn = (w & 1) * 64;
  int lin = blockIdx.x;
  int mt, nt;
  if (MODE == 0) { mt = lin >> 7; nt = lin & 127; }
  else { int xcd = lin & 7, j = lin >> 3; mt = j & 31; nt = (xcd << 4) | (j >> 5); }
  const int row0 = mt * 128, col0 = nt * 128;
  if (MODE == 0) { for (int i = tid; i < 2048; i += 256) h[i] = 0; }
  else if (tid == 0) h[0] = 0;
  const int nl = tid & 127;
  const int half = tid >> 7;
  const float* wbase = Wenc + (size_t)col0 + nl;
  const size_t atile = (size_t)mt * 131072;
  f32x4 acc[4][4] = {};
  const int kcl = lane >> 4, l15 = lane & 15;
  float4 a0, a1, a2, a3;
  float bfv[16];
  {
    const float4* ah4 = (const float4*)(Ahi + atile);
    const float4* al4 = (const float4*)(Alo + atile);
    a0 = ah4[tid]; a1 = ah4[tid + 256];
    a2 = al4[tid]; a3 = al4[tid + 256];
#pragma unroll
    for (int p = 0; p < 4; ++p)
#pragma unroll
      for (int i = 0; i < 4; ++i)
        bfv[p * 4 + i] = wbase[(size_t)(p * 8 + half * 4 + i) * D_SAE];
  }
  for (int ks = 0; ks < 32; ++ks) {
    short hb[16], lb[16];
#pragma unroll
    for (int q = 0; q < 16; ++q) {
      unsigned short hh = f2bf(bfv[q]);
      hb[q] = (short)hh;
      lb[q] = (short)f2bf(bfv[q] - bf2f(hh));
    }
    __syncthreads();
    *(float4*)&sA[(size_t)tid * 8] = a0;
    *(float4*)&sA[(size_t)(tid + 256) * 8] = a1;
    *(float4*)&sA[(size_t)(512 + tid) * 8] = a2;
    *(float4*)&sA[(size_t)(512 + tid + 256) * 8] = a3;
#pragma unroll
    for (int p = 0; p < 4; ++p) {
      int boff = p * 1024 + nl * 8 + half * 4;
      *(short4*)&sB[boff] = make_short4(hb[p * 4], hb[p * 4 + 1], hb[p * 4 + 2], hb[p * 4 + 3]);
      *(short4*)&sB[4096 + boff] = make_short4(lb[p * 4], lb[p * 4 + 1], lb[p * 4 + 2], lb[p * 4 + 3]);
    }
    __syncthreads();
    if (ks < 31) {
      const float4* ah4 = (const float4*)(Ahi + atile + (ks + 1) * 4096);
      const float4* al4 = (const float4*)(Alo + atile + (ks + 1) * 4096);
      a0 = ah4[tid]; a1 = ah4[tid + 256];
      a2 = al4[tid]; a3 = al4[tid + 256];
      const int k0n = (ks + 1) * 32;
#pragma unroll
      for (int p = 0; p < 4; ++p)
#pragma unroll
        for (int i = 0; i < 4; ++i)
          bfv[p * 4 + i] = wbase[(size_t)(k0n + p * 8 + half * 4 + i) * D_SAE];
    }
    bf16x8 ahf[4], alf[4];
#pragma unroll
    for (int fm = 0; fm < 4; ++fm) {
      int off = (kcl * 128 + wm + fm * 16 + l15) * 8;
      ahf[fm] = *(const bf16x8*)&sA[off];
      alf[fm] = *(const bf16x8*)&sA[4096 + off];
    }
#pragma unroll
    for (int fn = 0; fn < 4; ++fn) {
      int boff = (kcl * 128 + wn + fn * 16 + l15) * 8;
      bf16x8 bh = *(const bf16x8*)&sB[boff];
      bf16x8 bl = *(const bf16x8*)&sB[4096 + boff];
#pragma unroll
      for (int fm = 0; fm < 4; ++fm) {
        acc[fm][fn] = __builtin_amdgcn_mfma_f32_16x16x32_bf16(ahf[fm], bh, acc[fm][fn], 0, 0, 0);
        acc[fm][fn] = __builtin_amdgcn_mfma_f32_16x16x32_bf16(alf[fm], bh, acc[fm][fn], 0, 0, 0);
        acc[fm][fn] = __builtin_amdgcn_mfma_f32_16x16x32_bf16(ahf[fm], bl, acc[fm][fn], 0, 0, 0);
      }
    }
  }
  const int l4r = lane >> 4;
  if (MODE == 0) {
#pragma unroll
    for (int fn = 0; fn < 4; ++fn) {
      int col = col0 + wn + fn * 16 + l15;
      float g = g32[col], be = benc[col];
#pragma unroll
      for (int fm = 0; fm < 4; ++fm) {
#pragma unroll
        for (int r = 0; r < 4; ++r) {
          float z = acc[fm][fn][r] + be;
          float s = z > 0.f ? z * g : 0.f;
          unsigned bits = __float_as_uint(s);
          if (bits) atomicAdd(&h[bits >> 21], 1);
        }
      }
    }
    __syncthreads();
    for (int i = tid; i < 2048; i += 256)
      if (h[i]) atomicAdd(&ghist[i], h[i]);
  } else {
    unsigned thrBits = (unsigned)ctrl[1];
    int cnt = 0;
#pragma unroll
    for (int fn = 0; fn < 4; ++fn) {
      int col = col0 + wn + fn * 16 + l15;
      float g = g32[col], be = benc[col];
#pragma unroll
      for (int fm = 0; fm < 4; ++fm) {
#pragma unroll
        for (int r = 0; r < 4; ++r) {
          float z = acc[fm][fn][r] + be;
          float s = z > 0.f ? z * g : 0.f;
          cnt += (__float_as_uint(s) >= thrBits) ? 1 : 0;
        }
      }
    }
    int my = 0;
    if (cnt) my = atomicAdd(&h[0], cnt);
    __syncthreads();
    if (tid == 0) h[1] = atomicAdd(&ctrl[2], h[0]);
    __syncthreads();
    int pos = h[1] + my;
#pragma unroll
    for (int fn = 0; fn < 4; ++fn) {
      int col = col0 + wn + fn * 16 + l15;
      float g = g32[col], be = benc[col];
#pragma unroll
      for (int fm = 0; fm < 4; ++fm) {
        int rowb = row0 + wm + fm * 16 + l4r * 4;
#pragma unroll
        for (int r = 0; r < 4; ++r) {
          float z = acc[fm][fn][r] + be;
          float s = z > 0.f ? z * g : 0.f;
          if (__float_as_uint(s) >= thrBits) {
            if (pos < CAND_CAP) { cand_idx[pos] = (rowb + r) * D_SAE + col; cand_sc[pos] = s; }
            pos++;
          }
        }
      }
    }
  }
}

// ---------- coarse threshold (64-thread parallel scan) ----------
__global__ void find_coarse_kernel(const int* __restrict__ gh, int* ctrl,
                                   const int* __restrict__ kptr, int sub) {
  long long kB = (long long)kptr[0] * BATCH;
  long long needl = (kB + 500000 + sub - 1) / sub;
  long long fl = 720000 / sub;
  if (needl < fl) needl = fl;
  int b, cum;
  hist_scan_desc(gh, 2048, (int)needl, b, cum);
  if (threadIdx.x == 0) {
    long long est_incl = (long long)sub * (cum + gh[b]);
    if (est_incl > 3500000LL && (long long)sub * cum >= kB + 120000LL) b = b + 1;
    ctrl[1] = (int)(((unsigned)b) << 21);
  }
}

// ---------- radix histograms over candidate scores (passes 1,2) ----------
__global__ __launch_bounds__(256) void chist_kernel(const float* __restrict__ cand_sc,
                                                    const int* __restrict__ ctrl,
                                                    int* __restrict__ ghist, int pass) {
  __shared__ int h[2048];
  int nb = (pass == 2) ? 1024 : 2048;
  for (int i = threadIdx.x; i < nb; i += 256) h[i] = 0;
  __syncthreads();
  int n = ctrl[2]; if (n > CAND_CAP) n = CAND_CAP;
  unsigned sel1 = 0, sel22 = 0;
  if (pass == 1) sel1 = (unsigned)ctrl[3];
  if (pass == 2) sel22 = ((unsigned)ctrl[3] << 11) | (unsigned)ctrl[5];
  for (int i = blockIdx.x * 256 + threadIdx.x; i < n; i += gridDim.x * 256) {
    unsigned bits = __float_as_uint(cand_sc[i]);
    if (pass == 0) atomicAdd(&h[bits >> 21], 1);
    else if (pass == 1) { if ((bits >> 21) == sel1) atomicAdd(&h[(bits >> 10) & 0x7FFu], 1); }
    else { if ((bits >> 10) == sel22) atomicAdd(&h[bits & 0x3FFu], 1); }
  }
  __syncthreads();
  for (int i = threadIdx.x; i < nb; i += 256)
    if (h[i]) atomicAdd(&ghist[i], h[i]);
}

// ---------- radix select step (64-thread parallel scan) ----------
__global__ void cfind_kernel(const int* __restrict__ hist, int* ctrl,
                             const int* __restrict__ kptr, int pass) {
  int kB = kptr[0] * BATCH;
  int need, nbins;
  if (pass == 0)      { need = kB;                       nbins = 2048; }
  else if (pass == 1) { need = kB - ctrl[4];             nbins = 2048; }
  else                { need = kB - ctrl[4] - ctrl[6];   nbins = 1024; }
  int b, cum;
  hist_scan_desc(hist, nbins, need, b, cum);
  if (threadIdx.x == 0) {
    if (pass == 0)      { ctrl[3] = b; ctrl[4] = cum; }
    else if (pass == 1) { ctrl[5] = b; ctrl[6] = cum; }
    else {
      unsigned vbits = ((unsigned)ctrl[3] << 21) | ((unsigned)ctrl[5] << 10) | (unsigned)b;
      float V = __uint_as_float(vbits);
      float* cf = (float*)ctrl;
      cf[8] = V; cf[9] = V + EPS_M; cf[10] = V - EPS_M;
    }
  }
}

// ---------- band partition ----------
__global__ __launch_bounds__(256) void band_kernel(const int* __restrict__ cand_idx,
    const float* __restrict__ cand_sc, const float* __restrict__ g32,
    int* ctrl, int* row_cnt, int* row_feat, float* row_act, int* cand2_idx) {
  const float* cf = (const float*)ctrl;
  float hi = cf[9], lo = cf[10];
  int n = ctrl[2]; if (n > CAND_CAP) n = CAND_CAP;
  int lane = threadIdx.x & 63;
  int defc = 0;
  for (int i = blockIdx.x * 256 + threadIdx.x; i < n; i += gridDim.x * 256) {
    float s = cand_sc[i];
    int flat = cand_idx[i];
    if (s > hi) {
      int b = flat >> 14, j = flat & (D_SAE - 1);
      int p = atomicAdd(&row_cnt[b], 1);
      if (p < ROW_CAP) { row_feat[b * ROW_CAP + p] = j; row_act[b * ROW_CAP + p] = s / g32[j]; }
      defc++;
    }
    bool isc = (s <= hi) && (s >= lo);
    int pos = wave_append(isc, &ctrl[12]);
    if (isc && pos >= 0 && pos < CAND2_CAP) cand2_idx[pos] = flat;
  }
#pragma unroll
  for (int off = 32; off > 0; off >>= 1) defc += __shfl_down(defc, off, 64);
  if (lane == 0 && defc) atomicAdd(&ctrl[11], defc);
}

// ---------- fp64 rescore of band candidates ----------
__global__ __launch_bounds__(256) void cand2_score_kernel(const int* __restrict__ ctrl,
    const int* __restrict__ cand2_idx, const float* __restrict__ x,
    const float* __restrict__ Wdec, const float* __restrict__ benc,
    const double* __restrict__ g64, double* __restrict__ cand2_sc) {
  __shared__ double lds[4];
  int n2 = ctrl[12]; if (n2 > CAND2_CAP) n2 = CAND2_CAP;
  int t = threadIdx.x;
  for (int c = blockIdx.x; c < n2; c += gridDim.x) {
    int flat = cand2_idx[c];
    int b = flat >> 14, j = flat & (D_SAE - 1);
    double d[4];
    ln_row_fp64(x + (size_t)b * (2 * D_MODEL), lds, d);
    float4 w4 = *(const float4*)(Wdec + (size_t)j * D_MODEL + t * 4);
    double a = d[0] * (double)w4.x + d[1] * (double)w4.y + d[2] * (double)w4.z + d[3] * (double)w4.w;
    double z = blockReduceSum256(a, lds) + (double)benc[j];
    double sc = z > 0 ? z * g64[j] : 0.0;
    if (t == 0) cand2_sc[c] = sc;
  }
}

// ---------- rank band candidates (fp64, index-stable), accept fill ----------
__global__ __launch_bounds__(256) void cand2_rank_kernel(const int* __restrict__ ctrl,
    const int* __restrict__ cand2_idx, const double* __restrict__ cand2_sc,
    const double* __restrict__ g64, const int* __restrict__ kptr,
    int* row_cnt, int* row_feat, float* row_act) {
  __shared__ int lds[4];
  int n2 = ctrl[12]; if (n2 > CAND2_CAP) n2 = CAND2_CAP;
  int kB = kptr[0] * BATCH;
  int fill = kB - ctrl[11];
  int t = threadIdx.x;
  for (int c = blockIdx.x; c < n2; c += gridDim.x) {
    double sc = cand2_sc[c];
    int fc = cand2_idx[c];
    int cnt = 0;
    for (int y = t; y < n2; y += 256) {
      double sy = cand2_sc[y];
      if (sy > sc || (sy == sc && cand2_idx[y] < fc)) cnt++;
    }
    cnt = blockReduceSumInt256(cnt, lds);
    if (t == 0 && cnt < fill) {
      int b = fc >> 14, j = fc & (D_SAE - 1);
      int p = atomicAdd(&row_cnt[b], 1);
      if (p < ROW_CAP) { row_feat[b * ROW_CAP + p] = j; row_act[b * ROW_CAP + p] = (float)(sc / g64[j]); }
    }
  }
}

// ---------- sparse recon, bf16-hi Wdec (big path) ----------
__global__ __launch_bounds__(256) void recon_bf16_kernel(const int* __restrict__ row_cnt,
    const int* __restrict__ row_feat, const float* __restrict__ row_act,
    const short* __restrict__ wdech, const float* __restrict__ bdec, float* __restrict__ out) {
  int b = blockIdx.x, t = threadIdx.x;
  float4 acc0 = *(const float4*)&bdec[t * 4];
  float4 acc1 = make_float4(0.f, 0.f, 0.f, 0.f);
  int n = row_cnt[b]; if (n > ROW_CAP) n = ROW_CAP;
  const int* rf = row_feat + (size_t)b * ROW_CAP;
  const float* ra = row_act + (size_t)b * ROW_CAP;
  int p = 0;
  for (; p + 2 <= n; p += 2) {
    int j0 = rf[p], j1 = rf[p + 1];
    float v0 = ra[p], v1 = ra[p + 1];
    short4 h0 = *(const short4*)&wdech[(size_t)j0 * D_MODEL + t * 4];
    short4 h1 = *(const short4*)&wdech[(size_t)j1 * D_MODEL + t * 4];
    acc0.x += v0 * bf2f((unsigned short)h0.x); acc0.y += v0 * bf2f((unsigned short)h0.y);
    acc0.z += v0 * bf2f((unsigned short)h0.z); acc0.w += v0 * bf2f((unsigned short)h0.w);
    acc1.x += v1 * bf2f((unsigned short)h1.x); acc1.y += v1 * bf2f((unsigned short)h1.y);
    acc1.z += v1 * bf2f((unsigned short)h1.z); acc1.w += v1 * bf2f((unsigned short)h1.w);
  }
  if (p < n) {
    int j0 = rf[p]; float v0 = ra[p];
    short4 h0 = *(const short4*)&wdech[(size_t)j0 * D_MODEL + t * 4];
    acc0.x += v0 * bf2f((unsigned short)h0.x); acc0.y += v0 * bf2f((unsigned short)h0.y);
    acc0.z += v0 * bf2f((unsigned short)h0.z); acc0.w += v0 * bf2f((unsigned short)h0.w);
  }
  acc0.x += acc1.x; acc0.y += acc1.y; acc0.z += acc1.z; acc0.w += acc1.w;
  *(float4*)(out + (size_t)b * D_MODEL + t * 4) = acc0;
}

// ---------- sparse recon fp32 (fallback path) ----------
__global__ __launch_bounds__(256) void recon_kernel(const int* __restrict__ row_cnt,
    const int* __restrict__ row_feat, const float* __restrict__ row_act,
    const float* __restrict__ Wdec, const float* __restrict__ bdec, float* __restrict__ out) {
  int b = blockIdx.x, t = threadIdx.x;
  float4 acc0 = *(const float4*)&bdec[t * 4];
  float4 acc1 = make_float4(0.f, 0.f, 0.f, 0.f);
  int n = row_cnt[b]; if (n > ROW_CAP) n = ROW_CAP;
  const int* rf = row_feat + (size_t)b * ROW_CAP;
  const float* ra = row_act + (size_t)b * ROW_CAP;
  int p = 0;
  for (; p + 2 <= n; p += 2) {
    int j0 = rf[p], j1 = rf[p + 1];
    float v0 = ra[p], v1 = ra[p + 1];
    float4 w0 = *(const float4*)(Wdec + (size_t)j0 * D_MODEL + t * 4);
    float4 w1 = *(const float4*)(Wdec + (size_t)j1 * D_MODEL + t * 4);
    acc0.x += v0 * w0.x; acc0.y += v0 * w0.y; acc0.z += v0 * w0.z; acc0.w += v0 * w0.w;
    acc1.x += v1 * w1.x; acc1.y += v1 * w1.y; acc1.z += v1 * w1.z; acc1.w += v1 * w1.w;
  }
  if (p < n) {
    int j0 = rf[p]; float v0 = ra[p];
    float4 w0 = *(const float4*)(Wdec + (size_t)j0 * D_MODEL + t * 4);
    acc0.x += v0 * w0.x; acc0.y += v0 * w0.y; acc0.z += v0 * w0.z; acc0.w += v0 * w0.w;
  }
  acc0.x += acc1.x; acc0.y += acc1.y; acc0.z += acc1.z; acc0.w += acc1.w;
  *(float4*)(out + (size_t)b * D_MODEL + t * 4) = acc0;
}

extern "C" void kernel_launch(void* const* d_in, const int* in_sizes, int n_in,
                              void* d_out, int out_size, void* d_ws, size_t ws_size,
                              hipStream_t stream) {
  const float* x    = (const float*)d_in[0];
  const float* Wenc = (const float*)d_in[1];
  const float* benc = (const float*)d_in[2];
  const float* Wdec = (const float*)d_in[3];
  const float* bdec = (const float*)d_in[4];
  const int*   kptr = (const int*)d_in[5];
  float* out = (float*)d_out;

  char* ws = (char*)d_ws;
  size_t off = 0;
  short*  Ahi       = (short*)(ws + off);  off += (size_t)BATCH * D_MODEL * 2;
  short*  Alo       = (short*)(ws + off);  off += (size_t)BATCH * D_MODEL * 2;
  int*    cand_idx  = (int*)(ws + off);    off += (size_t)CAND_CAP * 4;
  float*  cand_sc   = (float*)(ws + off);  off += (size_t)CAND_CAP * 4;
  int*    row_feat  = (int*)(ws + off);    off += (size_t)BATCH * ROW_CAP * 4;
  float*  row_act   = (float*)(ws + off);  off += (size_t)BATCH * ROW_CAP * 4;
  int*    cand2_idx = (int*)(ws + off);    off += (size_t)CAND2_CAP * 4;
  double* cand2_sc  = (double*)(ws + off); off += (size_t)CAND2_CAP * 8;
  double* g64       = (double*)(ws + off); off += (size_t)D_SAE * 8;
  float*  g32       = (float*)(ws + off);  off += (size_t)D_SAE * 4;
  char*   zbase     = ws + off;
  int* ghist   = (int*)(zbase);
  int* h1      = (int*)(zbase + 8192);
  int* h2      = (int*)(zbase + 16384);
  int* h3      = (int*)(zbase + 24576);
  int* ctrl    = (int*)(zbase + 28672);
  int* row_cnt = (int*)(zbase + 28928);
  size_t zbytes = 28928 + (size_t)BATCH * 4;
  size_t small_need = off + zbytes;
  if (small_need > ws_size) return;  // ~60 MB floor

  size_t big_off = (small_need + 255) & ~(size_t)255;
  short* Whi = (short*)(ws + big_off);
  short* Wlo = Whi + (size_t)D_MODEL * D_SAE;
  size_t big_need = big_off + (size_t)D_MODEL * D_SAE * 4;
  const bool big = (big_need <= ws_size);   // round-6..17-proven to fit

  // bf16 Wdec for recon aliases the (dead-after-band) cand_idx+cand_sc region.
  short* wdech = (short*)cand_idx;

  hipMemsetAsync(zbase, 0, zbytes, stream);

  ln_kernel<<<BATCH / 4, 256, 0, stream>>>(x, Ahi, Alo);
  norm_kernel<<<D_SAE / 4, 256, 0, stream>>>(Wdec, g64, g32);
  if (big) {
    wsplit_kernel<<<4096, 256, 0, stream>>>(Wenc, Whi, Wlo);
    hist_gemm<<<256, 256, 0, stream>>>(Whi, Ahi, benc, g32, ghist);
    find_coarse_kernel<<<1, 64, 0, stream>>>(ghist, ctrl, kptr, 16);
    extract_gemm128<<<4096, 256, 0, stream>>>(Whi, Wlo, Ahi, Alo, benc, g32, ctrl, cand_idx, cand_sc, h1);
  } else {
    mfma_gemm<0><<<256, 256, 0, stream>>>(Wenc, Ahi, Alo, benc, g32, ghist, ctrl, nullptr, nullptr);
    find_coarse_kernel<<<1, 64, 0, stream>>>(ghist, ctrl, kptr, 16);
    mfma_gemm<1><<<4096, 256, 0, stream>>>(Wenc, Ahi, Alo, benc, g32, nullptr, ctrl, cand_idx, cand_sc);
    chist_kernel<<<1024, 256, 0, stream>>>(cand_sc, ctrl, h1, 0);
  }
  cfind_kernel<<<1, 64, 0, stream>>>(h1, ctrl, kptr, 0);
  chist_kernel<<<1024, 256, 0, stream>>>(cand_sc, ctrl, h2, 1);
  cfind_kernel<<<1, 64, 0, stream>>>(h2, ctrl, kptr, 1);
  chist_kernel<<<1024, 256, 0, stream>>>(cand_sc, ctrl, h3, 2);
  cfind_kernel<<<1, 64, 0, stream>>>(h3, ctrl, kptr, 2);
  band_kernel<<<1024, 256, 0, stream>>>(cand_idx, cand_sc, g32, ctrl, row_cnt, row_feat, row_act, cand2_idx);
  cand2_score_kernel<<<4096, 256, 0, stream>>>(ctrl, cand2_idx, x, Wdec, benc, g64, cand2_sc);
  cand2_rank_kernel<<<2048, 256, 0, stream>>>(ctrl, cand2_idx, cand2_sc, g64, kptr, row_cnt, row_feat, row_act);
  if (big) {
    wdecsplit_kernel<<<D_SAE, 256, 0, stream>>>(Wdec, wdech);
    recon_bf16_kernel<<<BATCH, 256, 0, stream>>>(row_cnt, row_feat, row_act, wdech, bdec, out);
  } else {
    recon_kernel<<<BATCH, 256, 0, stream>>>(row_cnt, row_feat, row_act, Wdec, bdec, out);
  }
}

// Round 19
// 664.785 us; speedup vs baseline: 1.2698x; 1.0168x over previous
//
#include <hip/hip_runtime.h>
#include <math.h>

#define D_MODEL 1024
#define D_SAE   16384
#define BATCH   4096
#define NTOT    (1ull * BATCH * D_SAE)
#define LN_EPS  1e-8
#define EPS_M   3e-4f        // |split-bf16 score - fp64 score| safe band half-width (>=6x margin)
#define ROW_CAP 256
#define CAND_CAP  (4 * 1024 * 1024)
#define CAND2_CAP 65536

using bf16x8 = __attribute__((ext_vector_type(8))) short;
using f32x4  = __attribute__((ext_vector_type(4))) float;

__device__ inline unsigned short f2bf(float f) {   // RNE fp32->bf16
  unsigned u = __float_as_uint(f);
  return (unsigned short)((u + 0x7fffu + ((u >> 16) & 1u)) >> 16);
}
__device__ inline float bf2f(unsigned short h) {
  return __uint_as_float((unsigned)h << 16);
}

// bank-conflict swizzle for sB (short-index space, 16B rows):
// injects row bits 3-5 XOR 6-8 into bank bits; bijective involution; 16B-align kept.
__device__ inline int swzB(int si) {
  int g = ((si >> 6) & 7) ^ ((si >> 9) & 7);
  return si ^ (g << 3);
}

// ---------- block (256-thread) reductions ----------
__device__ inline double blockReduceSum256(double v, double* lds) {
#pragma unroll
  for (int off = 32; off > 0; off >>= 1) v += __shfl_down(v, off, 64);
  int lane = threadIdx.x & 63, wid = threadIdx.x >> 6;
  __syncthreads();
  if (lane == 0) lds[wid] = v;
  __syncthreads();
  return lds[0] + lds[1] + lds[2] + lds[3];
}
__device__ inline int blockReduceSumInt256(int v, int* lds) {
#pragma unroll
  for (int off = 32; off > 0; off >>= 1) v += __shfl_down(v, off, 64);
  int lane = threadIdx.x & 63, wid = threadIdx.x >> 6;
  __syncthreads();
  if (lane == 0) lds[wid] = v;
  __syncthreads();
  return lds[0] + lds[1] + lds[2] + lds[3];
}

__device__ inline int wave_append(bool pred, int* counter) {
  unsigned long long m = __ballot(pred);
  int lane = threadIdx.x & 63;
  int pos = -1;
  if (m) {
    int ldr = __ffsll((long long)m) - 1;
    int base = 0;
    if (lane == ldr) base = atomicAdd(counter, __popcll(m));
    base = __shfl(base, ldr, 64);
    if (pred) pos = base + __popcll(m & ((1ull << lane) - 1ull));
  }
  return pos;
}

// ---------- 64-lane parallel descending histogram scan ----------
__device__ inline void hist_scan_desc(const int* __restrict__ hist, int nbins, int need,
                                      int& bsel, int& cumsel) {
  int t = threadIdx.x;          // 0..63
  int chunk = nbins >> 6;
  int topbase = nbins - t * chunk;
  int psum = 0;
  for (int i = 1; i <= chunk; ++i) psum += hist[topbase - i];
  int incl = psum;
#pragma unroll
  for (int off = 1; off < 64; off <<= 1) {
    int v = __shfl_up(incl, off, 64);
    if (t >= off) incl += v;
  }
  int excl = incl - psum;
  bool hit = (excl < need) && (excl + psum >= need);
  unsigned long long m = __ballot(hit);
  int tb = m ? (__ffsll((long long)m) - 1) : 63;
  int exb = __shfl(excl, tb, 64);
  int res_b = 0, res_c = 0;
  if (t == tb) {
    int c = exb;
    int b = nbins - tb * chunk - 1;
    int bend = b - chunk;
    for (; b > 0 && b > bend; --b) {
      int cc = hist[b];
      if (c + cc >= need) break;
      c += cc;
    }
    res_b = b; res_c = c;
  }
  bsel = __shfl(res_b, tb, 64);
  cumsel = __shfl(res_c, tb, 64);
}

// ---------- per-thread fp64 LN chain (256-thr block version, used by cand2) ----------
__device__ inline void ln_row_fp64(const float* __restrict__ row, double* lds, double d[4]) {
  int t = threadIdx.x;
  float4 s4 = *(const float4*)(row + t * 4);
  float4 t4 = *(const float4*)(row + D_MODEL + t * 4);
  double s[4] = {s4.x, s4.y, s4.z, s4.w};
  double tt[4] = {t4.x, t4.y, t4.z, t4.w};
  double ms = blockReduceSum256(s[0] + s[1] + s[2] + s[3], lds) / D_MODEL;
  double mt = blockReduceSum256(tt[0] + tt[1] + tt[2] + tt[3], lds) / D_MODEL;
  double vs = 0, vt = 0;
#pragma unroll
  for (int i = 0; i < 4; i++) { double a = s[i] - ms; vs += a * a; a = tt[i] - mt; vt += a * a; }
  vs = blockReduceSum256(vs, lds) / D_MODEL;
  vt = blockReduceSum256(vt, lds) / D_MODEL;
  double rs = sqrt(vs + LN_EPS), rt = sqrt(vt + LN_EPS);
  double u[4];
#pragma unroll
  for (int i = 0; i < 4; i++) u[i] = (tt[i] - mt) / rt - (s[i] - ms) / rs;
  double mu = blockReduceSum256(u[0] + u[1] + u[2] + u[3], lds) / D_MODEL;
  double vu = 0;
#pragma unroll
  for (int i = 0; i < 4; i++) { double a = u[i] - mu; vu += a * a; }
  vu = blockReduceSum256(vu, lds) / D_MODEL;
  double ru = sqrt(vu + LN_EPS);
#pragma unroll
  for (int i = 0; i < 4; i++) d[i] = (u[i] - mu) / ru;
}

// ---------- LN -> split-bf16 A, wave-per-row (no barriers), tiled layout ----------
__global__ __launch_bounds__(256) void ln_kernel(const float* __restrict__ x,
                                                 short* __restrict__ Ahi, short* __restrict__ Alo) {
  int wv = threadIdx.x >> 6, lane = threadIdx.x & 63;
  int b = (blockIdx.x << 2) | wv;
  const float* row = x + (size_t)b * (2 * D_MODEL);
  float s[16], t[16];
  const float4* s4p = (const float4*)(row + lane * 16);
  const float4* t4p = (const float4*)(row + D_MODEL + lane * 16);
  double sum_s = 0, sum_t = 0;
#pragma unroll
  for (int q = 0; q < 4; ++q) {
    float4 a = s4p[q], c = t4p[q];
    s[q * 4 + 0] = a.x; s[q * 4 + 1] = a.y; s[q * 4 + 2] = a.z; s[q * 4 + 3] = a.w;
    t[q * 4 + 0] = c.x; t[q * 4 + 1] = c.y; t[q * 4 + 2] = c.z; t[q * 4 + 3] = c.w;
  }
#pragma unroll
  for (int i = 0; i < 16; ++i) { sum_s += s[i]; sum_t += t[i]; }
#pragma unroll
  for (int off = 1; off < 64; off <<= 1) {
    sum_s += __shfl_xor(sum_s, off, 64);
    sum_t += __shfl_xor(sum_t, off, 64);
  }
  double ms = sum_s / D_MODEL, mt_ = sum_t / D_MODEL;
  double vs = 0, vt = 0;
#pragma unroll
  for (int i = 0; i < 16; ++i) {
    double a = s[i] - ms; vs += a * a;
    double c = t[i] - mt_; vt += c * c;
  }
#pragma unroll
  for (int off = 1; off < 64; off <<= 1) {
    vs += __shfl_xor(vs, off, 64);
    vt += __shfl_xor(vt, off, 64);
  }
  double rs = sqrt(vs / D_MODEL + LN_EPS), rt = sqrt(vt / D_MODEL + LN_EPS);
  double u[16], su = 0;
#pragma unroll
  for (int i = 0; i < 16; ++i) { u[i] = (t[i] - mt_) / rt - (s[i] - ms) / rs; su += u[i]; }
#pragma unroll
  for (int off = 1; off < 64; off <<= 1) su += __shfl_xor(su, off, 64);
  double mu = su / D_MODEL, vu = 0;
#pragma unroll
  for (int i = 0; i < 16; ++i) { double a = u[i] - mu; vu += a * a; }
#pragma unroll
  for (int off = 1; off < 64; off <<= 1) vu += __shfl_xor(vu, off, 64);
  double ru = sqrt(vu / D_MODEL + LN_EPS);
  int mtb = b >> 7, ml = b & 127;
#pragma unroll
  for (int blk8 = 0; blk8 < 2; ++blk8) {
    short h8[8], l8[8];
#pragma unroll
    for (int e = 0; e < 8; ++e) {
      int i = blk8 * 8 + e;
      double dd = (u[i] - mu) / ru;
      float f = (float)dd;
      unsigned short hh = f2bf(f);
      h8[e] = (short)hh;
      l8[e] = (short)f2bf(f - bf2f(hh));
    }
    int gi = lane * 16 + blk8 * 8;
    int ks = gi >> 5, kc = (gi >> 3) & 3;
    size_t base = ((((size_t)mtb * 32 + ks) * 4 + kc) * 128 + ml) * 8;
    *(float4*)&Ahi[base] = *(float4*)h8;
    *(float4*)&Alo[base] = *(float4*)l8;
  }
}

// ---------- dec_norms in fp64 (wave-per-feature, no block syncs) ----------
__global__ __launch_bounds__(256) void norm_kernel(const float* __restrict__ Wdec,
                                                   double* __restrict__ g64, float* __restrict__ g32) {
  int wv = threadIdx.x >> 6, lane = threadIdx.x & 63;
  int j = (blockIdx.x << 2) | wv;
  const float4* rowp = (const float4*)(Wdec + (size_t)j * D_MODEL);
  double a = 0;
#pragma unroll
  for (int q = 0; q < 4; ++q) {
    float4 w = rowp[lane + q * 64];
    a += (double)w.x * w.x + (double)w.y * w.y + (double)w.z * w.z + (double)w.w * w.w;
  }
#pragma unroll
  for (int off = 32; off > 0; off >>= 1) a += __shfl_down(a, off, 64);
  if (lane == 0) { double g = sqrt(a); g64[j] = g; g32[j] = (float)g; }
}

// ---------- pre-split W_enc fp32 -> tiled bf16 hi/lo [nt][ks][kc][c][e] ----------
__global__ __launch_bounds__(256) void wsplit_kernel(const float* __restrict__ Wenc,
                                                     short* __restrict__ Whi, short* __restrict__ Wlo) {
  __shared__ short sh[4096];
  __shared__ short sl[4096];
  int blk = blockIdx.x;            // 4096 = 128 nt * 32 ks
  int nt = blk >> 5, ks = blk & 31;
  int t = threadIdx.x;
  int r = t >> 3;
  int cg = t & 7;
  int kc = r >> 3, e = r & 7;
  const float* src = Wenc + (size_t)(ks * 32 + r) * D_SAE + nt * 128 + cg;
#pragma unroll
  for (int j = 0; j < 16; ++j) {
    float f = src[j * 8];
    unsigned short hh = f2bf(f);
    short ll = (short)f2bf(f - bf2f(hh));
    int c = j * 8 + cg;
    sh[kc * 1024 + c * 8 + e] = (short)hh;
    sl[kc * 1024 + c * 8 + e] = ll;
  }
  __syncthreads();
  size_t obase = ((size_t)nt * 32 + ks) * 4096;
  *(float4*)&Whi[obase + t * 16]     = *(const float4*)&sh[t * 16];
  *(float4*)&Whi[obase + t * 16 + 8] = *(const float4*)&sh[t * 16 + 8];
  *(float4*)&Wlo[obase + t * 16]     = *(const float4*)&sl[t * 16];
  *(float4*)&Wlo[obase + t * 16 + 8] = *(const float4*)&sl[t * 16 + 8];
}

// ---------- Wdec fp32 -> row-major bf16 (for recon), into dead cand region ----------
__global__ __launch_bounds__(256) void wdecsplit_kernel(const float* __restrict__ Wdec,
                                                        short* __restrict__ wdech) {
  int j = blockIdx.x, t = threadIdx.x;
  float4 w = *(const float4*)(Wdec + (size_t)j * D_MODEL + t * 4);
  short4 h;
  h.x = (short)f2bf(w.x); h.y = (short)f2bf(w.y);
  h.z = (short)f2bf(w.z); h.w = (short)f2bf(w.w);
  *(short4*)&wdech[(size_t)j * D_MODEL + t * 4] = h;
}

// ---------- hi-only 1/16-subsampled hist GEMM: per-wave privatized hist ----------
__global__ __launch_bounds__(256) void hist_gemm(
    const short* __restrict__ Whi, const short* __restrict__ Ahi,
    const float* __restrict__ benc, const float* __restrict__ g32,
    int* __restrict__ ghist) {
  __shared__ short sA[4096];
  __shared__ short sB[4096];
  __shared__ int h[4][2048];
  const int tid = threadIdx.x;
  const int lane = tid & 63;
  const int w = tid >> 6;
  const int wm = (w >> 1) * 64, wn = (w & 1) * 64;
  int lin = blockIdx.x;            // 256 = 2 mt * 128 nt
  int mt = lin >> 7, nt = lin & 127;
  const int col0 = nt * 128;
  for (int i = tid; i < 8192; i += 256) ((int*)h)[i] = 0;
  const size_t atile = (size_t)mt * 131072;
  const size_t btile = (size_t)nt * 131072;
  f32x4 acc[4][4] = {};
  const int kcl = lane >> 4, l15 = lane & 15;

  float4 a0, a1, b0, b1;
  {
    const float4* ah4 = (const float4*)(Ahi + atile);
    const float4* bh4 = (const float4*)(Whi + btile);
    a0 = ah4[tid]; a1 = ah4[tid + 256];
    b0 = bh4[tid]; b1 = bh4[tid + 256];
  }
  for (int ks = 0; ks < 32; ++ks) {
    __syncthreads();
    *(float4*)&sA[(size_t)tid * 8] = a0;
    *(float4*)&sA[(size_t)(tid + 256) * 8] = a1;
    *(float4*)&sB[(size_t)tid * 8] = b0;
    *(float4*)&sB[(size_t)(tid + 256) * 8] = b1;
    __syncthreads();
    if (ks < 31) {
      const float4* ah4 = (const float4*)(Ahi + atile + (ks + 1) * 4096);
      const float4* bh4 = (const float4*)(Whi + btile + (ks + 1) * 4096);
      a0 = ah4[tid]; a1 = ah4[tid + 256];
      b0 = bh4[tid]; b1 = bh4[tid + 256];
    }
    bf16x8 ahf[4];
#pragma unroll
    for (int fm = 0; fm < 4; ++fm)
      ahf[fm] = *(const bf16x8*)&sA[(kcl * 128 + wm + fm * 16 + l15) * 8];
#pragma unroll
    for (int fn = 0; fn < 4; ++fn) {
      bf16x8 bh = *(const bf16x8*)&sB[(kcl * 128 + wn + fn * 16 + l15) * 8];
#pragma unroll
      for (int fm = 0; fm < 4; ++fm)
        acc[fm][fn] = __builtin_amdgcn_mfma_f32_16x16x32_bf16(ahf[fm], bh, acc[fm][fn], 0, 0, 0);
    }
  }
#pragma unroll
  for (int fn = 0; fn < 4; ++fn) {
    int col = col0 + wn + fn * 16 + l15;
    float g = g32[col], be = benc[col];
#pragma unroll
    for (int fm = 0; fm < 4; ++fm) {
#pragma unroll
      for (int r = 0; r < 4; ++r) {
        float z = acc[fm][fn][r] + be;
        float s = z > 0.f ? z * g : 0.f;
        unsigned bits = __float_as_uint(s);
        if (bits) atomicAdd(&h[w][bits >> 21], 1);
      }
    }
  }
  __syncthreads();
  for (int i = tid; i < 2048; i += 256) {
    int v = h[0][i] + h[1][i] + h[2][i] + h[3][i];
    if (v) atomicAdd(&ghist[i], v);
  }
}

// ---------- 128x128 split-bf16 MFMA extract GEMM ----------
// A fragments direct from L2-resident tiled global; B double-buffered in LDS with
// XOR bank-swizzle (write+read both swizzled -> conflict-free). One barrier/K-step.
__global__ __launch_bounds__(256, 3) void extract_gemm128(
    const short* __restrict__ Whi, const short* __restrict__ Wlo,
    const short* __restrict__ Ahi, const short* __restrict__ Alo,
    const float* __restrict__ benc, const float* __restrict__ g32,
    int* __restrict__ ctrl, int* __restrict__ cand_idx, float* __restrict__ cand_sc,
    int* __restrict__ ghist) {
  __shared__ short sB[2][8192];   // dbuf: hi [4][128][8] | lo at +4096 (swizzled)

  const int tid = threadIdx.x;
  const int lane = tid & 63;
  const int w = tid >> 6;
  const int wm = (w >> 1) * 64, wn = (w & 1) * 64;

  // A-resident partition: XCD owns mt in [4*xcd, 4*xcd+4); B streams in nt order.
  int lin = blockIdx.x;
  int xcd = lin & 7, j = lin >> 3;
  int mt = (xcd << 2) | (j & 3);
  int nt = j >> 2;
  const int row0 = mt * 128, col0 = nt * 128;

  const size_t atile = (size_t)mt * 131072;
  const size_t btile = (size_t)nt * 131072;

  f32x4 acc[4][4] = {};
  const int kcl = lane >> 4, l15 = lane & 15;

  // swizzled write slots (fixed per thread)
  const int wsi0 = swzB(tid * 8);
  const int wsi1 = swzB((tid + 256) * 8);
  const int wsi2 = swzB(4096 + tid * 8);
  const int wsi3 = swzB(4096 + (tid + 256) * 8);

  // B stage regs (tile ks+1 in flight)
  float4 b0, b1, b2, b3;
  {
    const float4* bh4 = (const float4*)(Whi + btile);
    const float4* bl4 = (const float4*)(Wlo + btile);
    b0 = bh4[tid]; b1 = bh4[tid + 256];
    b2 = bl4[tid]; b3 = bl4[tid + 256];
  }
  *(float4*)&sB[0][wsi0] = b0;
  *(float4*)&sB[0][wsi1] = b1;
  *(float4*)&sB[0][wsi2] = b2;
  *(float4*)&sB[0][wsi3] = b3;
  __syncthreads();
  int cur = 0;

  // per-lane A fragment base offset (within a [4][128][8] K-slab)
  const int afrag = kcl * 1024 + (wm + l15) * 8;   // + fm*128 shorts

  // swizzled read slots (fixed per thread)
  int rsh[4], rsl[4];
#pragma unroll
  for (int fn = 0; fn < 4; ++fn) {
    int si = (kcl * 128 + wn + fn * 16 + l15) * 8;
    rsh[fn] = swzB(si);
    rsl[fn] = swzB(4096 + si);
  }

  for (int ks = 0; ks < 32; ++ks) {
    if (ks < 31) {             // issue next B tile loads (fly under MFMA)
      const int o = (ks + 1) * 4096;
      const float4* bh4 = (const float4*)(Whi + btile + o);
      const float4* bl4 = (const float4*)(Wlo + btile + o);
      b0 = bh4[tid]; b1 = bh4[tid + 256];
      b2 = bl4[tid]; b3 = bl4[tid + 256];
    }
    // A fragments direct from global (L2-resident slice)
    const short* ah = Ahi + atile + (size_t)ks * 4096 + afrag;
    const short* al = Alo + atile + (size_t)ks * 4096 + afrag;
    bf16x8 ahf[4], alf[4];
#pragma unroll
    for (int fm = 0; fm < 4; ++fm) {
      ahf[fm] = *(const bf16x8*)&ah[fm * 128];
      alf[fm] = *(const bf16x8*)&al[fm * 128];
    }
    const short* tB = sB[cur];
    bf16x8 bh[4], bl[4];
#pragma unroll
    for (int fn = 0; fn < 4; ++fn) {
      bh[fn] = *(const bf16x8*)&tB[rsh[fn]];
      bl[fn] = *(const bf16x8*)&tB[rsl[fn]];
    }
#pragma unroll
    for (int fn = 0; fn < 4; ++fn) {
#pragma unroll
      for (int fm = 0; fm < 4; ++fm) {
        acc[fm][fn] = __builtin_amdgcn_mfma_f32_16x16x32_bf16(ahf[fm], bh[fn], acc[fm][fn], 0, 0, 0);
        acc[fm][fn] = __builtin_amdgcn_mfma_f32_16x16x32_bf16(alf[fm], bh[fn], acc[fm][fn], 0, 0, 0);
        acc[fm][fn] = __builtin_amdgcn_mfma_f32_16x16x32_bf16(ahf[fm], bl[fn], acc[fm][fn], 0, 0, 0);
      }
    }
    if (ks < 31) {             // write next tile into the OTHER buffer (disjoint)
      short* nB = sB[cur ^ 1];
      *(float4*)&nB[wsi0] = b0;
      *(float4*)&nB[wsi1] = b1;
      *(float4*)&nB[wsi2] = b2;
      *(float4*)&nB[wsi3] = b3;
    }
    __syncthreads();           // writes to cur^1 visible; reads of cur done
    cur ^= 1;
  }

  // epilogue: alias hist into sB (dead after K-loop). hh[0..2047]=hist,
  // hh[2048]=block count, hh[2049]=global base.
  int* hh = (int*)sB;
  const int l4r = lane >> 4;
  unsigned thrBits = (unsigned)ctrl[1];
  for (int i = tid; i < 2050; i += 256) hh[i] = 0;
  __syncthreads();
  int cnt = 0;
#pragma unroll
  for (int fn = 0; fn < 4; ++fn) {
    int col = col0 + wn + fn * 16 + l15;
    float g = g32[col], be = benc[col];
#pragma unroll
    for (int fm = 0; fm < 4; ++fm) {
#pragma unroll
      for (int r = 0; r < 4; ++r) {
        float z = acc[fm][fn][r] + be;
        float s = z > 0.f ? z * g : 0.f;
        unsigned bits = __float_as_uint(s);
        if (bits >= thrBits) { cnt++; atomicAdd(&hh[bits >> 21], 1); }
      }
    }
  }
  int my = 0;
  if (cnt) my = atomicAdd(&hh[2048], cnt);
  __syncthreads();
  if (tid == 0) hh[2049] = atomicAdd(&ctrl[2], hh[2048]);
  for (int i = tid; i < 2048; i += 256)
    if (hh[i]) atomicAdd(&ghist[i], hh[i]);
  __syncthreads();
  int pos = hh[2049] + my;
#pragma unroll
  for (int fn = 0; fn < 4; ++fn) {
    int col = col0 + wn + fn * 16 + l15;
    float g = g32[col], be = benc[col];
#pragma unroll
    for (int fm = 0; fm < 4; ++fm) {
      int rowb = row0 + wm + fm * 16 + l4r * 4;
#pragma unroll
      for (int r = 0; r < 4; ++r) {
        float z = acc[fm][fn][r] + be;
        float s = z > 0.f ? z * g : 0.f;
        if (__float_as_uint(s) >= thrBits) {
          if (pos < CAND_CAP) { cand_idx[pos] = (rowb + r) * D_SAE + col; cand_sc[pos] = s; }
          pos++;
        }
      }
    }
  }
}

// ---------- fallback 128^2 GEMM (small ws): MODE 0 = hist (1/16), MODE 1 = extract ----------
template <int MODE>
__global__ __launch_bounds__(256) void mfma_gemm(
    const float* __restrict__ Wenc,
    const short* __restrict__ Ahi, const short* __restrict__ Alo,
    const float* __restrict__ benc, const float* __restrict__ g32,
    int* __restrict__ ghist, int* __restrict__ ctrl,
    int* __restrict__ cand_idx, float* __restrict__ cand_sc) {
  __shared__ short sA[8192];
  __shared__ short sB[8192];
  __shared__ int h[(MODE == 0) ? 2048 : 2];
  const int tid = threadIdx.x;
  const int lane = tid & 63;
  const int w = tid >> 6;
  const int wm = (w >> 1) * 64, wn = (w & 1) * 64;
  int lin = blockIdx.x;
  int mt, nt;
  if (MODE == 0) { mt = lin >> 7; nt = lin & 127; }
  else { int xcd = lin & 7, j = lin >> 3; mt = j & 31; nt = (xcd << 4) | (j >> 5); }
  const int row0 = mt * 128, col0 = nt * 128;
  if (MODE == 0) { for (int i = tid; i < 2048; i += 256) h[i] = 0; }
  else if (tid == 0) h[0] = 0;
  const int nl = tid & 127;
  const int half = tid >> 7;
  const float* wbase = Wenc + (size_t)col0 + nl;
  const size_t atile = (size_t)mt * 131072;
  f32x4 acc[4][4] = {};
  const int kcl = lane >> 4, l15 = lane & 15;
  float4 a0, a1, a2, a3;
  float bfv[16];
  {
    const float4* ah4 = (const float4*)(Ahi + atile);
    const float4* al4 = (const float4*)(Alo + atile);
    a0 = ah4[tid]; a1 = ah4[tid + 256];
    a2 = al4[tid]; a3 = al4[tid + 256];
#pragma unroll
    for (int p = 0; p < 4; ++p)
#pragma unroll
      for (int i = 0; i < 4; ++i)
        bfv[p * 4 + i] = wbase[(size_t)(p * 8 + half * 4 + i) * D_SAE];
  }
  for (int ks = 0; ks < 32; ++ks) {
    short hb[16], lb[16];
#pragma unroll
    for (int q = 0; q < 16; ++q) {
      unsigned short hh = f2bf(bfv[q]);
      hb[q] = (short)hh;
      lb[q] = (short)f2bf(bfv[q] - bf2f(hh));
    }
    __syncthreads();
    *(float4*)&sA[(size_t)tid * 8] = a0;
    *(float4*)&sA[(size_t)(tid + 256) * 8] = a1;
    *(float4*)&sA[(size_t)(512 + tid) * 8] = a2;
    *(float4*)&sA[(size_t)(512 + tid + 256) * 8] = a3;
#pragma unroll
    for (int p = 0; p < 4; ++p) {
      int boff = p * 1024 + nl * 8 + half * 4;
      *(short4*)&sB[boff] = make_short4(hb[p * 4], hb[p * 4 + 1], hb[p * 4 + 2], hb[p * 4 + 3]);
      *(short4*)&sB[4096 + boff] = make_short4(lb[p * 4], lb[p * 4 + 1], lb[p * 4 + 2], lb[p * 4 + 3]);
    }
    __syncthreads();
    if (ks < 31) {
      const float4* ah4 = (const float4*)(Ahi + atile + (ks + 1) * 4096);
      const float4* al4 = (const float4*)(Alo + atile + (ks + 1) * 4096);
      a0 = ah4[tid]; a1 = ah4[tid + 256];
      a2 = al4[tid]; a3 = al4[tid + 256];
      const int k0n = (ks + 1) * 32;
#pragma unroll
      for (int p = 0; p < 4; ++p)
#pragma unroll
        for (int i = 0; i < 4; ++i)
          bfv[p * 4 + i] = wbase[(size_t)(k0n + p * 8 + half * 4 + i) * D_SAE];
    }
    bf16x8 ahf[4], alf[4];
#pragma unroll
    for (int fm = 0; fm < 4; ++fm) {
      int off = (kcl * 128 + wm + fm * 16 + l15) * 8;
      ahf[fm] = *(const bf16x8*)&sA[off];
      alf[fm] = *(const bf16x8*)&sA[4096 + off];
    }
#pragma unroll
    for (int fn = 0; fn < 4; ++fn) {
      int boff = (kcl * 128 + wn + fn * 16 + l15) * 8;
      bf16x8 bh = *(const bf16x8*)&sB[boff];
      bf16x8 bl = *(const bf16x8*)&sB[4096 + boff];
#pragma unroll
      for (int fm = 0; fm < 4; ++fm) {
        acc[fm][fn] = __builtin_amdgcn_mfma_f32_16x16x32_bf16(ahf[fm], bh, acc[fm][fn], 0, 0, 0);
        acc[fm][fn] = __builtin_amdgcn_mfma_f32_16x16x32_bf16(alf[fm], bh, acc[fm][fn], 0, 0, 0);
        acc[fm][fn] = __builtin_amdgcn_mfma_f32_16x16x32_bf16(ahf[fm], bl, acc[fm][fn], 0, 0, 0);
      }
    }
  }
  const int l4r = lane >> 4;
  if (MODE == 0) {
#pragma unroll
    for (int fn = 0; fn < 4; ++fn) {
      int col = col0 + wn + fn * 16 + l15;
      float g = g32[col], be = benc[col];
#pragma unroll
      for (int fm = 0; fm < 4; ++fm) {
#pragma unroll
        for (int r = 0; r < 4; ++r) {
          float z = acc[fm][fn][r] + be;
          float s = z > 0.f ? z * g : 0.f;
          unsigned bits = __float_as_uint(s);
          if (bits) atomicAdd(&h[bits >> 21], 1);
        }
      }
    }
    __syncthreads();
    for (int i = tid; i < 2048; i += 256)
      if (h[i]) atomicAdd(&ghist[i], h[i]);
  } else {
    unsigned thrBits = (unsigned)ctrl[1];
    int cnt = 0;
#pragma unroll
    for (int fn = 0; fn < 4; ++fn) {
      int col = col0 + wn + fn * 16 + l15;
      float g = g32[col], be = benc[col];
#pragma unroll
      for (int fm = 0; fm < 4; ++fm) {
#pragma unroll
        for (int r = 0; r < 4; ++r) {
          float z = acc[fm][fn][r] + be;
          float s = z > 0.f ? z * g : 0.f;
          cnt += (__float_as_uint(s) >= thrBits) ? 1 : 0;
        }
      }
    }
    int my = 0;
    if (cnt) my = atomicAdd(&h[0], cnt);
    __syncthreads();
    if (tid == 0) h[1] = atomicAdd(&ctrl[2], h[0]);
    __syncthreads();
    int pos = h[1] + my;
#pragma unroll
    for (int fn = 0; fn < 4; ++fn) {
      int col = col0 + wn + fn * 16 + l15;
      float g = g32[col], be = benc[col];
#pragma unroll
      for (int fm = 0; fm < 4; ++fm) {
        int rowb = row0 + wm + fm * 16 + l4r * 4;
#pragma unroll
        for (int r = 0; r < 4; ++r) {
          float z = acc[fm][fn][r] + be;
          float s = z > 0.f ? z * g : 0.f;
          if (__float_as_uint(s) >= thrBits) {
            if (pos < CAND_CAP) { cand_idx[pos] = (rowb + r) * D_SAE + col; cand_sc[pos] = s; }
            pos++;
          }
        }
      }
    }
  }
}

// ---------- coarse threshold (64-thread parallel scan) ----------
__global__ void find_coarse_kernel(const int* __restrict__ gh, int* ctrl,
                                   const int* __restrict__ kptr, int sub) {
  long long kB = (long long)kptr[0] * BATCH;
  long long needl = (kB + 500000 + sub - 1) / sub;
  long long fl = 720000 / sub;
  if (needl < fl) needl = fl;
  int b, cum;
  hist_scan_desc(gh, 2048, (int)needl, b, cum);
  if (threadIdx.x == 0) {
    long long est_incl = (long long)sub * (cum + gh[b]);
    if (est_incl > 3500000LL && (long long)sub * cum >= kB + 120000LL) b = b + 1;
    ctrl[1] = (int)(((unsigned)b) << 21);
  }
}

// ---------- radix histograms over candidate scores (passes 1,2) ----------
__global__ __launch_bounds__(256) void chist_kernel(const float* __restrict__ cand_sc,
                                                    const int* __restrict__ ctrl,
                                                    int* __restrict__ ghist, int pass) {
  __shared__ int h[2048];
  int nb = (pass == 2) ? 1024 : 2048;
  for (int i = threadIdx.x; i < nb; i += 256) h[i] = 0;
  __syncthreads();
  int n = ctrl[2]; if (n > CAND_CAP) n = CAND_CAP;
  unsigned sel1 = 0, sel22 = 0;
  if (pass == 1) sel1 = (unsigned)ctrl[3];
  if (pass == 2) sel22 = ((unsigned)ctrl[3] << 11) | (unsigned)ctrl[5];
  for (int i = blockIdx.x * 256 + threadIdx.x; i < n; i += gridDim.x * 256) {
    unsigned bits = __float_as_uint(cand_sc[i]);
    if (pass == 0) atomicAdd(&h[bits >> 21], 1);
    else if (pass == 1) { if ((bits >> 21) == sel1) atomicAdd(&h[(bits >> 10) & 0x7FFu], 1); }
    else { if ((bits >> 10) == sel22) atomicAdd(&h[bits & 0x3FFu], 1); }
  }
  __syncthreads();
  for (int i = threadIdx.x; i < nb; i += 256)
    if (h[i]) atomicAdd(&ghist[i], h[i]);
}

// ---------- radix select step (64-thread parallel scan) ----------
__global__ void cfind_kernel(const int* __restrict__ hist, int* ctrl,
                             const int* __restrict__ kptr, int pass) {
  int kB = kptr[0] * BATCH;
  int need, nbins;
  if (pass == 0)      { need = kB;                       nbins = 2048; }
  else if (pass == 1) { need = kB - ctrl[4];             nbins = 2048; }
  else                { need = kB - ctrl[4] - ctrl[6];   nbins = 1024; }
  int b, cum;
  hist_scan_desc(hist, nbins, need, b, cum);
  if (threadIdx.x == 0) {
    if (pass == 0)      { ctrl[3] = b; ctrl[4] = cum; }
    else if (pass == 1) { ctrl[5] = b; ctrl[6] = cum; }
    else {
      unsigned vbits = ((unsigned)ctrl[3] << 21) | ((unsigned)ctrl[5] << 10) | (unsigned)b;
      float V = __uint_as_float(vbits);
      float* cf = (float*)ctrl;
      cf[8] = V; cf[9] = V + EPS_M; cf[10] = V - EPS_M;
    }
  }
}

// ---------- band partition ----------
__global__ __launch_bounds__(256) void band_kernel(const int* __restrict__ cand_idx,
    const float* __restrict__ cand_sc, const float* __restrict__ g32,
    int* ctrl, int* row_cnt, int* row_feat, float* row_act, int* cand2_idx) {
  const float* cf = (const float*)ctrl;
  float hi = cf[9], lo = cf[10];
  int n = ctrl[2]; if (n > CAND_CAP) n = CAND_CAP;
  int lane = threadIdx.x & 63;
  int defc = 0;
  for (int i = blockIdx.x * 256 + threadIdx.x; i < n; i += gridDim.x * 256) {
    float s = cand_sc[i];
    int flat = cand_idx[i];
    if (s > hi) {
      int b = flat >> 14, j = flat & (D_SAE - 1);
      int p = atomicAdd(&row_cnt[b], 1);
      if (p < ROW_CAP) { row_feat[b * ROW_CAP + p] = j; row_act[b * ROW_CAP + p] = s / g32[j]; }
      defc++;
    }
    bool isc = (s <= hi) && (s >= lo);
    int pos = wave_append(isc, &ctrl[12]);
    if (isc && pos >= 0 && pos < CAND2_CAP) cand2_idx[pos] = flat;
  }
#pragma unroll
  for (int off = 32; off > 0; off >>= 1) defc += __shfl_down(defc, off, 64);
  if (lane == 0 && defc) atomicAdd(&ctrl[11], defc);
}

// ---------- fp64 rescore of band candidates ----------
__global__ __launch_bounds__(256) void cand2_score_kernel(const int* __restrict__ ctrl,
    const int* __restrict__ cand2_idx, const float* __restrict__ x,
    const float* __restrict__ Wdec, const float* __restrict__ benc,
    const double* __restrict__ g64, double* __restrict__ cand2_sc) {
  __shared__ double lds[4];
  int n2 = ctrl[12]; if (n2 > CAND2_CAP) n2 = CAND2_CAP;
  int t = threadIdx.x;
  for (int c = blockIdx.x; c < n2; c += gridDim.x) {
    int flat = cand2_idx[c];
    int b = flat >> 14, j = flat & (D_SAE - 1);
    double d[4];
    ln_row_fp64(x + (size_t)b * (2 * D_MODEL), lds, d);
    float4 w4 = *(const float4*)(Wdec + (size_t)j * D_MODEL + t * 4);
    double a = d[0] * (double)w4.x + d[1] * (double)w4.y + d[2] * (double)w4.z + d[3] * (double)w4.w;
    double z = blockReduceSum256(a, lds) + (double)benc[j];
    double sc = z > 0 ? z * g64[j] : 0.0;
    if (t == 0) cand2_sc[c] = sc;
  }
}

// ---------- rank band candidates (fp64, index-stable), accept fill ----------
__global__ __launch_bounds__(256) void cand2_rank_kernel(const int* __restrict__ ctrl,
    const int* __restrict__ cand2_idx, const double* __restrict__ cand2_sc,
    const double* __restrict__ g64, const int* __restrict__ kptr,
    int* row_cnt, int* row_feat, float* row_act) {
  __shared__ int lds[4];
  int n2 = ctrl[12]; if (n2 > CAND2_CAP) n2 = CAND2_CAP;
  int kB = kptr[0] * BATCH;
  int fill = kB - ctrl[11];
  int t = threadIdx.x;
  for (int c = blockIdx.x; c < n2; c += gridDim.x) {
    double sc = cand2_sc[c];
    int fc = cand2_idx[c];
    int cnt = 0;
    for (int y = t; y < n2; y += 256) {
      double sy = cand2_sc[y];
      if (sy > sc || (sy == sc && cand2_idx[y] < fc)) cnt++;
    }
    cnt = blockReduceSumInt256(cnt, lds);
    if (t == 0 && cnt < fill) {
      int b = fc >> 14, j = fc & (D_SAE - 1);
      int p = atomicAdd(&row_cnt[b], 1);
      if (p < ROW_CAP) { row_feat[b * ROW_CAP + p] = j; row_act[b * ROW_CAP + p] = (float)(sc / g64[j]); }
    }
  }
}

// ---------- sparse recon, bf16-hi Wdec, 4-way ILP (big path) ----------
__global__ __launch_bounds__(256) void recon_bf16_kernel(const int* __restrict__ row_cnt,
    const int* __restrict__ row_feat, const float* __restrict__ row_act,
    const short* __restrict__ wdech, const float* __restrict__ bdec, float* __restrict__ out) {
  int b = blockIdx.x, t = threadIdx.x;
  float4 acc0 = *(const float4*)&bdec[t * 4];
  float4 acc1 = make_float4(0.f, 0.f, 0.f, 0.f);
  float4 acc2 = make_float4(0.f, 0.f, 0.f, 0.f);
  float4 acc3 = make_float4(0.f, 0.f, 0.f, 0.f);
  int n = row_cnt[b]; if (n > ROW_CAP) n = ROW_CAP;
  const int* rf = row_feat + (size_t)b * ROW_CAP;
  const float* ra = row_act + (size_t)b * ROW_CAP;
  int p = 0;
  for (; p + 4 <= n; p += 4) {
    int j0 = rf[p], j1 = rf[p + 1], j2 = rf[p + 2], j3 = rf[p + 3];
    float v0 = ra[p], v1 = ra[p + 1], v2 = ra[p + 2], v3 = ra[p + 3];
    short4 h0 = *(const short4*)&wdech[(size_t)j0 * D_MODEL + t * 4];
    short4 h1 = *(const short4*)&wdech[(size_t)j1 * D_MODEL + t * 4];
    short4 h2 = *(const short4*)&wdech[(size_t)j2 * D_MODEL + t * 4];
    short4 h3 = *(const short4*)&wdech[(size_t)j3 * D_MODEL + t * 4];
    acc0.x += v0 * bf2f((unsigned short)h0.x); acc0.y += v0 * bf2f((unsigned short)h0.y);
    acc0.z += v0 * bf2f((unsigned short)h0.z); acc0.w += v0 * bf2f((unsigned short)h0.w);
    acc1.x += v1 * bf2f((unsigned short)h1.x); acc1.y += v1 * bf2f((unsigned short)h1.y);
    acc1.z += v1 * bf2f((unsigned short)h1.z); acc1.w += v1 * bf2f((unsigned short)h1.w);
    acc2.x += v2 * bf2f((unsigned short)h2.x); acc2.y += v2 * bf2f((unsigned short)h2.y);
    acc2.z += v2 * bf2f((unsigned short)h2.z); acc2.w += v2 * bf2f((unsigned short)h2.w);
    acc3.x += v3 * bf2f((unsigned short)h3.x); acc3.y += v3 * bf2f((unsigned short)h3.y);
    acc3.z += v3 * bf2f((unsigned short)h3.z); acc3.w += v3 * bf2f((unsigned short)h3.w);
  }
  for (; p < n; ++p) {
    int j0 = rf[p]; float v0 = ra[p];
    short4 h0 = *(const short4*)&wdech[(size_t)j0 * D_MODEL + t * 4];
    acc0.x += v0 * bf2f((unsigned short)h0.x); acc0.y += v0 * bf2f((unsigned short)h0.y);
    acc0.z += v0 * bf2f((unsigned short)h0.z); acc0.w += v0 * bf2f((unsigned short)h0.w);
  }
  acc0.x += acc1.x + acc2.x + acc3.x;
  acc0.y += acc1.y + acc2.y + acc3.y;
  acc0.z += acc1.z + acc2.z + acc3.z;
  acc0.w += acc1.w + acc2.w + acc3.w;
  *(float4*)(out + (size_t)b * D_MODEL + t * 4) = acc0;
}

// ---------- sparse recon fp32 (fallback path) ----------
__global__ __launch_bounds__(256) void recon_kernel(const int* __restrict__ row_cnt,
    const int* __restrict__ row_feat, const float* __restrict__ row_act,
    const float* __restrict__ Wdec, const float* __restrict__ bdec, float* __restrict__ out) {
  int b = blockIdx.x, t = threadIdx.x;
  float4 acc0 = *(const float4*)&bdec[t * 4];
  float4 acc1 = make_float4(0.f, 0.f, 0.f, 0.f);
  int n = row_cnt[b]; if (n > ROW_CAP) n = ROW_CAP;
  const int* rf = row_feat + (size_t)b * ROW_CAP;
  const float* ra = row_act + (size_t)b * ROW_CAP;
  int p = 0;
  for (; p + 2 <= n; p += 2) {
    int j0 = rf[p], j1 = rf[p + 1];
    float v0 = ra[p], v1 = ra[p + 1];
    float4 w0 = *(const float4*)(Wdec + (size_t)j0 * D_MODEL + t * 4);
    float4 w1 = *(const float4*)(Wdec + (size_t)j1 * D_MODEL + t * 4);
    acc0.x += v0 * w0.x; acc0.y += v0 * w0.y; acc0.z += v0 * w0.z; acc0.w += v0 * w0.w;
    acc1.x += v1 * w1.x; acc1.y += v1 * w1.y; acc1.z += v1 * w1.z; acc1.w += v1 * w1.w;
  }
  if (p < n) {
    int j0 = rf[p]; float v0 = ra[p];
    float4 w0 = *(const float4*)(Wdec + (size_t)j0 * D_MODEL + t * 4);
    acc0.x += v0 * w0.x; acc0.y += v0 * w0.y; acc0.z += v0 * w0.z; acc0.w += v0 * w0.w;
  }
  acc0.x += acc1.x; acc0.y += acc1.y; acc0.z += acc1.z; acc0.w += acc1.w;
  *(float4*)(out + (size_t)b * D_MODEL + t * 4) = acc0;
}

extern "C" void kernel_launch(void* const* d_in, const int* in_sizes, int n_in,
                              void* d_out, int out_size, void* d_ws, size_t ws_size,
                              hipStream_t stream) {
  const float* x    = (const float*)d_in[0];
  const float* Wenc = (const float*)d_in[1];
  const float* benc = (const float*)d_in[2];
  const float* Wdec = (const float*)d_in[3];
  const float* bdec = (const float*)d_in[4];
  const int*   kptr = (const int*)d_in[5];
  float* out = (float*)d_out;

  char* ws = (char*)d_ws;
  size_t off = 0;
  short*  Ahi       = (short*)(ws + off);  off += (size_t)BATCH * D_MODEL * 2;
  short*  Alo       = (short*)(ws + off);  off += (size_t)BATCH * D_MODEL * 2;
  int*    cand_idx  = (int*)(ws + off);    off += (size_t)CAND_CAP * 4;
  float*  cand_sc   = (float*)(ws + off);  off += (size_t)CAND_CAP * 4;
  int*    row_feat  = (int*)(ws + off);    off += (size_t)BATCH * ROW_CAP * 4;
  float*  row_act   = (float*)(ws + off);  off += (size_t)BATCH * ROW_CAP * 4;
  int*    cand2_idx = (int*)(ws + off);    off += (size_t)CAND2_CAP * 4;
  double* cand2_sc  = (double*)(ws + off); off += (size_t)CAND2_CAP * 8;
  double* g64       = (double*)(ws + off); off += (size_t)D_SAE * 8;
  float*  g32       = (float*)(ws + off);  off += (size_t)D_SAE * 4;
  char*   zbase     = ws + off;
  int* ghist   = (int*)(zbase);
  int* h1      = (int*)(zbase + 8192);
  int* h2      = (int*)(zbase + 16384);
  int* h3      = (int*)(zbase + 24576);
  int* ctrl    = (int*)(zbase + 28672);
  int* row_cnt = (int*)(zbase + 28928);
  size_t zbytes = 28928 + (size_t)BATCH * 4;
  size_t small_need = off + zbytes;
  if (small_need > ws_size) return;  // ~60 MB floor

  size_t big_off = (small_need + 255) & ~(size_t)255;
  short* Whi = (short*)(ws + big_off);
  short* Wlo = Whi + (size_t)D_MODEL * D_SAE;
  size_t big_need = big_off + (size_t)D_MODEL * D_SAE * 4;
  const bool big = (big_need <= ws_size);   // round-6..18-proven to fit

  // bf16 Wdec for recon aliases the (dead-after-band) cand_idx+cand_sc region.
  short* wdech = (short*)cand_idx;

  hipMemsetAsync(zbase, 0, zbytes, stream);

  ln_kernel<<<BATCH / 4, 256, 0, stream>>>(x, Ahi, Alo);
  norm_kernel<<<D_SAE / 4, 256, 0, stream>>>(Wdec, g64, g32);
  if (big) {
    wsplit_kernel<<<4096, 256, 0, stream>>>(Wenc, Whi, Wlo);
    hist_gemm<<<256, 256, 0, stream>>>(Whi, Ahi, benc, g32, ghist);
    find_coarse_kernel<<<1, 64, 0, stream>>>(ghist, ctrl, kptr, 16);
    extract_gemm128<<<4096, 256, 0, stream>>>(Whi, Wlo, Ahi, Alo, benc, g32, ctrl, cand_idx, cand_sc, h1);
  } else {
    mfma_gemm<0><<<256, 256, 0, stream>>>(Wenc, Ahi, Alo, benc, g32, ghist, ctrl, nullptr, nullptr);
    find_coarse_kernel<<<1, 64, 0, stream>>>(ghist, ctrl, kptr, 16);
    mfma_gemm<1><<<4096, 256, 0, stream>>>(Wenc, Ahi, Alo, benc, g32, nullptr, ctrl, cand_idx, cand_sc);
    chist_kernel<<<1024, 256, 0, stream>>>(cand_sc, ctrl, h1, 0);
  }
  cfind_kernel<<<1, 64, 0, stream>>>(h1, ctrl, kptr, 0);
  chist_kernel<<<1024, 256, 0, stream>>>(cand_sc, ctrl, h2, 1);
  cfind_kernel<<<1, 64, 0, stream>>>(h2, ctrl, kptr, 1);
  chist_kernel<<<1024, 256, 0, stream>>>(cand_sc, ctrl, h3, 2);
  cfind_kernel<<<1, 64, 0, stream>>>(h3, ctrl, kptr, 2);
  band_kernel<<<1024, 256, 0, stream>>>(cand_idx, cand_sc, g32, ctrl, row_cnt, row_feat, row_act, cand2_idx);
  cand2_score_kernel<<<4096, 256, 0, stream>>>(ctrl, cand2_idx, x, Wdec, benc, g64, cand2_sc);
  cand2_rank_kernel<<<2048, 256, 0, stream>>>(ctrl, cand2_idx, cand2_sc, g64, kptr, row_cnt, row_feat, row_act);
  if (big) {
    wdecsplit_kernel<<<D_SAE, 256, 0, stream>>>(Wdec, wdech);
    recon_bf16_kernel<<<BATCH, 256, 0, stream>>>(row_cnt, row_feat, row_act, wdech, bdec, out);
  } else {
    recon_kernel<<<BATCH, 256, 0, stream>>>(row_cnt, row_feat, row_act, Wdec, bdec, out);
  }
}